// Round 1
// baseline (743.374 us; speedup 1.0000x reference)
//
#include <hip/hip_runtime.h>

// ---------------------------------------------------------------------------
// LavaNetwork, bit-exact 4-plane i8 MFMA GEMM (mfma_i32_16x16x64_i8).
//   w ~ k*2^-31 (k = rint(w*2^31), residual <= 2^-32), 4 balanced base-256
//   digits -> exact i8 planes, exact i32 sums, exact i64 Horner + f64 bias.
// Round-10 structure:
//   - wave tile 64t x 32m (acc 128 VGPR) -> 2 blocks/CU via launch_bounds(256,2)
//     32 MFMA per 8 ds_read_b128 per k64-iter (2x arithmetic intensity of r9)
//   - grid reordered to dim3(t, b, m): blocks sharing an act tile differ by
//     gridDim.x*gridDim.y = 128 in dispatch id == 0 mod 8 -> same XCD -> act
//     tile fetched from HBM once per group instead of once per XCD
//   - acts DIRECT to VGPR from [b][kt][t][64] layout (register double-buffer);
//     LDS holds only weights (16 KB, GLDS double-buffered, shared by 4 waves)
//   - weights keep the proven chunk swizzle c^((m>>1)&3) for conflict-free
//     ds_read_b128
//   - lif1_t: register double-buffered window prefetch
//   - lif_lds<32> with 256 blocks (1 block/CU)
// Fallback: round-3 proven f16 path if ws too small.
// ---------------------------------------------------------------------------

typedef int i32x4 __attribute__((ext_vector_type(4)));
typedef _Float16 f16x8 __attribute__((ext_vector_type(8)));
typedef _Float16 f16x4 __attribute__((ext_vector_type(4)));
typedef float f32x4 __attribute__((ext_vector_type(4)));

#define GLDS(g, l) __builtin_amdgcn_global_load_lds( \
    (const __attribute__((address_space(1))) void*)(g), \
    (__attribute__((address_space(3))) void*)(l), 16, 0, 0)

#define INV231 4.656612873077392578125e-10   // 2^-31

// ======================= prep =======================

// w (M,K) f32 -> wp [K/64][4][M][64] i8 digit planes; 16-B chunk c of row m
// stored at c ^ ((m>>1)&3)  (round-6/8-proven conflict-free for ds_read_b128).
__global__ __launch_bounds__(256) void prep_w8(const float* __restrict__ A,
                                               signed char* __restrict__ wp,
                                               int M, int K)
{
    long gt = (long)blockIdx.x * 256 + threadIdx.x;
    int kq4 = K >> 2;
    int m = (int)(gt / kq4), kq = (int)(gt % kq4);
    int k0 = kq * 4;
    int kt = k0 >> 6, kin = k0 & 63;
    int cw = ((kin >> 4) ^ (m >> 1)) & 3;
    float4 w = *(const float4*)&A[(long)m * K + k0];
    float wv[4] = {w.x, w.y, w.z, w.w};
    int pack[4] = {0, 0, 0, 0};
#pragma unroll
    for (int e = 0; e < 4; e++) {
        long k64 = (long)rint((double)wv[e] * 2147483648.0);  // * 2^31
#pragma unroll
        for (int j = 0; j < 3; j++) {
            long r = ((k64 + 128) & 255) - 128;   // balanced digit [-128,127]
            pack[j] |= ((int)r & 255) << (e * 8);
            k64 = (k64 - r) >> 8;
        }
        pack[3] |= ((int)k64 & 255) << (e * 8);
    }
#pragma unroll
    for (int p = 0; p < 4; p++)
        *(int*)&wp[(((long)kt * 4 + p) * M + m) * 64 + cw * 16 + (kin & 15)] = pack[p];
}

// x [b][512][1024] f32 -> x8t [b][8][1024][64] i8 (k-tile-major, plain layout
// for direct coalesced frag loads; no swizzle).
__global__ __launch_bounds__(256) void prep_x8(const float* __restrict__ x,
                                               unsigned char* __restrict__ xt)
{
    __shared__ float xs[64][68];
    const int b = blockIdx.z, i0 = blockIdx.y * 64, t0 = blockIdx.x * 64;
    const float* xb = x + ((long)b * 512 + i0) * 1024 + t0;
#pragma unroll
    for (int p = 0; p < 4; p++) {
        int f = threadIdx.x + p * 256;
        int i = f >> 4, t4 = (f & 15) * 4;
        *(float4*)&xs[i][t4] = *(const float4*)&xb[(long)i * 1024 + t4];
    }
    __syncthreads();
    int tt = threadIdx.x >> 2, c = threadIdx.x & 3;
    unsigned char bytes[16];
#pragma unroll
    for (int j = 0; j < 16; j++)
        bytes[j] = (unsigned char)xs[c * 16 + j][tt];
    *(uint4*)&xt[(((long)b * 8 + (i0 >> 6)) * 1024 + t0 + tt) * 64 + c * 16] =
        *(uint4*)bytes;
}

// ======================= GEMM (both orientations) =======================
// TRANS: D[t][M]  (acts A, weights B) -> cur1t for coalesced LIF
// !TRANS: D[M][t] (weights A, acts B) -> cur2 directly
// Block: 32m x 256t, 4 waves each own a 64-t slice (all share the 32-m LDS
// weight tile). Wave tile 64t x 32m, 32 MFMA / (2 glb-lds + 8 lds-read +
// 4 glb-act) per k64.
// Grid is dim3(t-blocks, b, m-blocks): all m-blocks of one act tile land on
// the same XCD (dispatch id stride gridDim.x*gridDim.y == 128 == 0 mod 8).
template <bool TRANS>
__global__ __launch_bounds__(256, 2) void gemm_i8(
    const signed char* __restrict__ wp,     // [K/64][4][M][64] swizzled
    const unsigned char* __restrict__ act,  // [b][K/64][1024][64] plain
    const float* __restrict__ bias,         // (M)
    float* __restrict__ C,
    int M, int K)
{
    __shared__ signed char Ws[2][4][32][64];   // 16 KB

    const int b = blockIdx.y;
    const int m0 = blockIdx.z * 32, t0 = blockIdx.x * 256;
    const int tid = threadIdx.x, lane = tid & 63, wave = tid >> 6;
    const int wt = t0 + wave * 64;            // wave's global t base
    const int lm = lane & 15, lq = lane >> 4;
    const int fro = ((lq ^ (lm >> 1)) & 3) * 16;   // swizzled LDS read offset
    const int gl_t = lane >> 2, gl_c = (lane & 3) * 16;
    const int niter = K >> 6;

    const unsigned char* ab = act + (long)b * niter * 1024 * 64;
    // slab r for this wave: r in {wave, wave+4}: p = r>>1, s = r&1
    const int p0 = wave >> 1, s0 = wave & 1;          // slab r = wave
    const int p1 = (wave + 4) >> 1, s1 = wave & 1;    // slab r = wave+4

    // acc[plane][q]: TRANS q = tf*2+mf, !TRANS q = mf*4+tf  (all static idx)
    i32x4 acc[4][8];
#pragma unroll
    for (int p = 0; p < 4; p++)
#pragma unroll
        for (int q = 0; q < 8; q++) acc[p][q] = (i32x4)0;

    // stage weights iter 0 into buf 0
    {
        const signed char* g0 = wp + (((long)p0) * M + m0 + s0 * 16 + gl_t) * 64 + gl_c;
        const signed char* g1 = wp + (((long)p1) * M + m0 + s1 * 16 + gl_t) * 64 + gl_c;
        GLDS(g0, &Ws[0][p0][s0 * 16][0]);
        GLDS(g1, &Ws[0][p1][s1 * 16][0]);
    }
    // acts iter 0 into registers (4 t-frags of 16B/lane)
    i32x4 a[4], an[4];
#pragma unroll
    for (int f = 0; f < 4; f++)
        a[f] = *(const i32x4*)&ab[((long)(wt + f * 16 + lm)) * 64 + lq * 16];
    __syncthreads();

    for (int it = 0; it < niter; it++) {
        const int buf = it & 1;
        const int nx = (it + 1 < niter) ? it + 1 : it;
        // prefetch weights it+1 -> buf^1 (GLDS) and acts it+1 -> registers;
        // both are drained by the end-of-iter barrier's vmcnt(0) anyway.
        if (it + 1 < niter) {
            const long kb = (long)(it + 1) * 4;
            const signed char* g0 =
                wp + ((kb + p0) * M + m0 + s0 * 16 + gl_t) * 64 + gl_c;
            const signed char* g1 =
                wp + ((kb + p1) * M + m0 + s1 * 16 + gl_t) * 64 + gl_c;
            GLDS(g0, &Ws[buf ^ 1][p0][s0 * 16][0]);
            GLDS(g1, &Ws[buf ^ 1][p1][s1 * 16][0]);
        }
#pragma unroll
        for (int f = 0; f < 4; f++)
            an[f] = *(const i32x4*)&ab[((long)nx * 1024 + wt + f * 16 + lm) * 64 + lq * 16];

#pragma unroll
        for (int p = 0; p < 4; p++) {
            i32x4 w0 = *(const i32x4*)&Ws[buf][p][lm][fro];
            i32x4 w1 = *(const i32x4*)&Ws[buf][p][16 + lm][fro];
            if (TRANS) {
#pragma unroll
                for (int f = 0; f < 4; f++) {
                    acc[p][f * 2 + 0] = __builtin_amdgcn_mfma_i32_16x16x64_i8(
                        a[f], w0, acc[p][f * 2 + 0], 0, 0, 0);
                    acc[p][f * 2 + 1] = __builtin_amdgcn_mfma_i32_16x16x64_i8(
                        a[f], w1, acc[p][f * 2 + 1], 0, 0, 0);
                }
            } else {
#pragma unroll
                for (int f = 0; f < 4; f++) {
                    acc[p][0 + f] = __builtin_amdgcn_mfma_i32_16x16x64_i8(
                        w0, a[f], acc[p][0 + f], 0, 0, 0);
                    acc[p][4 + f] = __builtin_amdgcn_mfma_i32_16x16x64_i8(
                        w1, a[f], acc[p][4 + f], 0, 0, 0);
                }
            }
        }
        __syncthreads();
#pragma unroll
        for (int f = 0; f < 4; f++) a[f] = an[f];
    }

    if (TRANS) {
        // D[t][m]: acc[p][tf*2+mf]; col = m (lane lm), row = t (lq*4 + r)
        double bv[2];
        bv[0] = (double)bias[m0 + lm];
        bv[1] = (double)bias[m0 + 16 + lm];
        float* Cb = C + (long)b * 1024 * M;
#pragma unroll
        for (int tf = 0; tf < 4; tf++)
#pragma unroll
            for (int r = 0; r < 4; r++) {
                const int trow = wt + tf * 16 + lq * 4 + r;
#pragma unroll
                for (int mf = 0; mf < 2; mf++) {
                    long T = acc[3][tf * 2 + mf][r];
                    T = T * 256 + acc[2][tf * 2 + mf][r];
                    T = T * 256 + acc[1][tf * 2 + mf][r];
                    T = T * 256 + acc[0][tf * 2 + mf][r];
                    Cb[(long)trow * M + m0 + mf * 16 + lm] =
                        (float)((double)T * INV231 + bv[mf]);
                }
            }
    } else {
        // D[m][t]: acc[p][mf*4+tf]; col = t (lane lm), row = m (lq*4 + r)
        float* Cb = C + (long)b * M * 1024;
#pragma unroll
        for (int mf = 0; mf < 2; mf++)
#pragma unroll
            for (int r = 0; r < 4; r++) {
                const int mrow = m0 + mf * 16 + lq * 4 + r;
                const double bv = (double)bias[mrow];
#pragma unroll
                for (int tf = 0; tf < 4; tf++) {
                    long T = acc[3][mf * 4 + tf][r];
                    T = T * 256 + acc[2][mf * 4 + tf][r];
                    T = T * 256 + acc[1][mf * 4 + tf][r];
                    T = T * 256 + acc[0][mf * 4 + tf][r];
                    Cb[(long)mrow * 1024 + wt + tf * 16 + lm] =
                        (float)((double)T * INV231 + bv);
                }
            }
    }
}

// ======================= LIF =======================

// Coalesced thread-per-row scan over cur1t [b][1024][2048]; emits i8 spikes
// [b][32][1024][64] (k-tile-major, plain) + 1024-bit masks.
// Register double-buffer: prefetch window tw+1 while scanning tw.
__global__ __launch_bounds__(256) void lif1_t(
    const float* __restrict__ ct,
    unsigned char* __restrict__ spk8,
    unsigned* __restrict__ mask_ws)
{
    const int b = blockIdx.y;
    const int m = blockIdx.x * 256 + threadIdx.x;
    const float* src = ct + (long)b * 1024 * 2048 + m;
    unsigned char* spb = spk8 + (((long)b * 32 + (m >> 6)) * 1024) * 64 + (m & 63);
    unsigned* mw = mask_ws + (long)b * 32 * 2048 + m;
    double v = 0.0;
    float c0[32], c1[32];
#pragma unroll
    for (int j = 0; j < 32; j++)
        c0[j] = src[(long)j * 2048];
    for (int tw = 0; tw < 32; tw += 2) {
        // prefetch window tw+1 (independent of the scan below)
#pragma unroll
        for (int j = 0; j < 32; j++)
            c1[j] = src[(long)((tw + 1) * 32 + j) * 2048];
        unsigned mword = 0;
#pragma unroll
        for (int j = 0; j < 32; j++) {
            v = 0.95 * v + (double)c0[j];
            bool s = v >= 1.0;
            mword |= (s ? 1u : 0u) << j;
            if (s) v = 0.0;
            spb[(long)(tw * 32 + j) * 64] = s ? 1 : 0;
        }
        mw[(long)tw * 2048] = mword;
        // prefetch window tw+2
        if (tw + 2 < 32) {
#pragma unroll
            for (int j = 0; j < 32; j++)
                c0[j] = src[(long)((tw + 2) * 32 + j) * 2048];
        }
        mword = 0;
#pragma unroll
        for (int j = 0; j < 32; j++) {
            v = 0.95 * v + (double)c1[j];
            bool s = v >= 1.0;
            mword |= (s ? 1u : 0u) << j;
            if (s) v = 0.0;
            spb[(long)((tw + 1) * 32 + j) * 64] = s ? 1 : 0;
        }
        mw[(long)(tw + 1) * 2048] = mword;
    }
}

// masks [b][32][2048] -> f32 spikes [b][2048][1024]
__global__ __launch_bounds__(256) void expand_spk(
    const unsigned* __restrict__ mask_ws,
    float* __restrict__ spk1)
{
    __shared__ unsigned msk[8][32];
    const long rowbase = (long)blockIdx.x * 8;
    const int b = (int)(rowbase >> 11), m0 = (int)(rowbase & 2047);
    const int tid = threadIdx.x;
    {
        int w = tid >> 3, r = tid & 7;
        msk[r][w] = mask_ws[((long)b * 32 + w) * 2048 + m0 + r];
    }
    __syncthreads();
    const int r = tid >> 5, l5 = tid & 31;
    float* dst = spk1 + (rowbase + r) * 1024;
    const int sh = (l5 & 7) * 4;
#pragma unroll
    for (int j = 0; j < 8; j++) {
        const int t = l5 * 4 + j * 128;
        const unsigned w = msk[r][(l5 >> 3) + j * 4];
        float4 o;
        o.x = ((w >> sh) & 1u) ? 1.f : 0.f;
        o.y = ((w >> (sh + 1)) & 1u) ? 1.f : 0.f;
        o.z = ((w >> (sh + 2)) & 1u) ? 1.f : 0.f;
        o.w = ((w >> (sh + 3)) & 1u) ? 1.f : 0.f;
        *(float4*)&dst[t] = o;
    }
}

// LDS-chunked LIF for layer 2 (proven round 4); RPB=32 -> 256 blocks (1/CU)
template <int RPB>
__global__ __launch_bounds__(256) void lif_lds(float* __restrict__ cur)
{
    __shared__ float cs[RPB][36];
    const long rowbase = (long)blockIdx.x * RPB;
    float* base = cur + rowbase * 1024;
    const int tid = threadIdx.x;
    double v = 0.0;
    const int NV = RPB * 32 / 4;
    for (int tc = 0; tc < 1024; tc += 32) {
        for (int f = tid; f < NV; f += 256) {
            int row = f >> 3, t4 = (f & 7) * 4;
            *(float4*)&cs[row][t4] = *(const float4*)&base[(long)row * 1024 + tc + t4];
        }
        __syncthreads();
        if (tid < RPB) {
#pragma unroll
            for (int j = 0; j < 32; j++) {
                v = 0.95 * v + (double)cs[tid][j];
                bool s = v >= 1.0;
                cs[tid][j] = s ? 1.f : 0.f;
                if (s) v = 0.0;
            }
        }
        __syncthreads();
        for (int f = tid; f < NV; f += 256) {
            int row = f >> 3, t4 = (f & 7) * 4;
            *(float4*)&base[(long)row * 1024 + tc + t4] = *(float4*)&cs[row][t4];
        }
        __syncthreads();
    }
}

// ======================= fallback (round 3, proven) =======================

__device__ inline void split3(float w, _Float16& q0, _Float16& q1, _Float16& q2) {
    float p0 = rintf(w * 4096.f) * 2.44140625e-4f;
    float r1 = w - p0;
    float p1s = rintf(r1 * 8388608.f) * 2.44140625e-4f;
    float r2 = r1 - p1s * 4.8828125e-4f;
    float p2s = rintf(r2 * 1.7179869184e10f) * 1.220703125e-4f;
    q0 = (_Float16)p0; q1 = (_Float16)p1s; q2 = (_Float16)p2s;
}

__global__ __launch_bounds__(256) void gemm_f16x3_kernel(
    const float* __restrict__ A, const float* __restrict__ Bmat,
    const float* __restrict__ bias, float* __restrict__ C,
    int M, int N, int K, long sB, long sC)
{
    __shared__ _Float16 As[3][128][40];
    __shared__ _Float16 Bsh[128][40];
    const int batch = blockIdx.z;
    const float* Bp = Bmat + (long)batch * sB;
    float* Cp = C + (long)batch * sC;
    const int m0 = blockIdx.y * 128, n0 = blockIdx.x * 128;
    const int tid = threadIdx.x, lane = tid & 63, wave = tid >> 6;
    const int wrow = (wave >> 1) * 64, wcol = (wave & 1) * 64;
    const int lm = lane & 15, lq = lane >> 4;
    const int a_mo = tid >> 3, a_kc = (tid & 7) * 4;
    const int b_kq = tid >> 5, b_nq = tid & 31;

    f32x4 acc[3][4][4];
#pragma unroll
    for (int p = 0; p < 3; p++)
#pragma unroll
        for (int i = 0; i < 4; i++)
#pragma unroll
            for (int j = 0; j < 4; j++) acc[p][i][j] = (f32x4)0.f;

    for (int k0 = 0; k0 < K; k0 += 32) {
#pragma unroll
        for (int i = 0; i < 4; i++) {
            const int m = i * 32 + a_mo;
            float4 w = *(const float4*)&A[(long)(m0 + m) * K + k0 + a_kc];
            _Float16 a0[4], a1[4], a2[4];
            split3(w.x, a0[0], a1[0], a2[0]);
            split3(w.y, a0[1], a1[1], a2[1]);
            split3(w.z, a0[2], a1[2], a2[2]);
            split3(w.w, a0[3], a1[3], a2[3]);
            *(f16x4*)&As[0][m][a_kc] = (f16x4){a0[0], a0[1], a0[2], a0[3]};
            *(f16x4*)&As[1][m][a_kc] = (f16x4){a1[0], a1[1], a1[2], a1[3]};
            *(f16x4*)&As[2][m][a_kc] = (f16x4){a2[0], a2[1], a2[2], a2[3]};
        }
        {
            float4 r0 = *(const float4*)&Bp[(long)(k0 + b_kq * 4 + 0) * N + n0 + b_nq * 4];
            float4 r1 = *(const float4*)&Bp[(long)(k0 + b_kq * 4 + 1) * N + n0 + b_nq * 4];
            float4 r2 = *(const float4*)&Bp[(long)(k0 + b_kq * 4 + 2) * N + n0 + b_nq * 4];
            float4 r3 = *(const float4*)&Bp[(long)(k0 + b_kq * 4 + 3) * N + n0 + b_nq * 4];
            *(f16x4*)&Bsh[b_nq * 4 + 0][b_kq * 4] =
                (f16x4){(_Float16)r0.x, (_Float16)r1.x, (_Float16)r2.x, (_Float16)r3.x};
            *(f16x4*)&Bsh[b_nq * 4 + 1][b_kq * 4] =
                (f16x4){(_Float16)r0.y, (_Float16)r1.y, (_Float16)r2.y, (_Float16)r3.y};
            *(f16x4*)&Bsh[b_nq * 4 + 2][b_kq * 4] =
                (f16x4){(_Float16)r0.z, (_Float16)r1.z, (_Float16)r2.z, (_Float16)r3.z};
            *(f16x4*)&Bsh[b_nq * 4 + 3][b_kq * 4] =
                (f16x4){(_Float16)r0.w, (_Float16)r1.w, (_Float16)r2.w, (_Float16)r3.w};
        }
        __syncthreads();
        f16x8 bf[4];
#pragma unroll
        for (int j = 0; j < 4; j++)
            bf[j] = *(const f16x8*)&Bsh[wcol + j * 16 + lm][lq * 8];
#pragma unroll
        for (int p = 0; p < 3; p++) {
            f16x8 af[4];
#pragma unroll
            for (int i = 0; i < 4; i++)
                af[i] = *(const f16x8*)&As[p][wrow + i * 16 + lm][lq * 8];
#pragma unroll
            for (int i = 0; i < 4; i++)
#pragma unroll
                for (int j = 0; j < 4; j++)
                    acc[p][i][j] = __builtin_amdgcn_mfma_f32_16x16x32_f16(
                        af[i], bf[j], acc[p][i][j], 0, 0, 0);
        }
        __syncthreads();
    }
#pragma unroll
    for (int i = 0; i < 4; i++)
#pragma unroll
        for (int r = 0; r < 4; r++) {
            const int row = m0 + wrow + i * 16 + lq * 4 + r;
            const double bv = (double)bias[row];
#pragma unroll
            for (int j = 0; j < 4; j++) {
                double s = (double)acc[0][i][j][r]
                         + (double)acc[1][i][j][r] * 4.8828125e-4
                         + (double)acc[2][i][j][r] * 4.76837158203125e-7 + bv;
                Cp[(long)row * N + n0 + wcol + j * 16 + lm] = (float)s;
            }
        }
}

__global__ __launch_bounds__(256) void lif_rows(float* __restrict__ data,
                                                long nrows, int T)
{
    long r = (long)blockIdx.x * blockDim.x + threadIdx.x;
    if (r >= nrows) return;
    float* p = data + r * (long)T;
    double v = 0.0;
    for (int t = 0; t < T; t += 4) {
        float4 c = *(float4*)(p + t);
        float4 s;
        v = 0.95 * v + (double)c.x; s.x = (v >= 1.0) ? 1.f : 0.f; if (v >= 1.0) v = 0.0;
        v = 0.95 * v + (double)c.y; s.y = (v >= 1.0) ? 1.f : 0.f; if (v >= 1.0) v = 0.0;
        v = 0.95 * v + (double)c.z; s.z = (v >= 1.0) ? 1.f : 0.f; if (v >= 1.0) v = 0.0;
        v = 0.95 * v + (double)c.w; s.w = (v >= 1.0) ? 1.f : 0.f; if (v >= 1.0) v = 0.0;
        *(float4*)(p + t) = s;
    }
}

// ======================= launch =======================

extern "C" void kernel_launch(void* const* d_in, const int* in_sizes, int n_in,
                              void* d_out, int out_size, void* d_ws, size_t ws_size,
                              hipStream_t stream)
{
    const float* x  = (const float*)d_in[0];  // (32, 512, 1024)
    const float* w1 = (const float*)d_in[1];  // (2048, 512)
    const float* b1 = (const float*)d_in[2];  // (2048)
    const float* w2 = (const float*)d_in[3];  // (256, 2048)
    const float* b2 = (const float*)d_in[4];  // (256)

    float* out  = (float*)d_out;
    float* spk1 = out;                              // (32, 2048, 1024)
    float* spk2 = out + (long)32 * 2048 * 1024;     // (32, 256, 1024)

    const size_t WP1 = 4194304;        // [8][4][2048][64] i8
    const size_t WP2 = 2097152;        // [32][4][256][64] i8
    const size_t X8T = 16777216;       // [32][8][1024][64] i8
    const size_t SPK = 67108864;       // [32][32][1024][64] i8
    const size_t MSK = 8388608;        // [32][32][2048] u32
    const size_t NEED = WP1 + WP2 + X8T + SPK + MSK;

    if (ws_size >= NEED) {
        char* ws = (char*)d_ws;
        signed char* wp1 = (signed char*)ws;
        signed char* wp2 = (signed char*)(ws + WP1);
        unsigned char* x8t = (unsigned char*)(ws + WP1 + WP2);
        unsigned char* spk8 = (unsigned char*)(ws + WP1 + WP2 + X8T);
        unsigned* mask_ws = (unsigned*)(ws + WP1 + WP2 + X8T + SPK);

        prep_w8<<<1024, 256, 0, stream>>>(w1, wp1, 2048, 512);
        prep_w8<<<512, 256, 0, stream>>>(w2, wp2, 256, 2048);
        prep_x8<<<dim3(16, 8, 32), 256, 0, stream>>>(x, x8t);

        // layer 1: cur1t [b][t][2048] -> coalesced LIF -> spikes
        // grid (t=4, b=32, m=64): same-act blocks land on one XCD
        gemm_i8<true><<<dim3(4, 32, 64), 256, 0, stream>>>(
            wp1, x8t, b1, spk1, 2048, 512);
        lif1_t<<<dim3(8, 32), 256, 0, stream>>>(spk1, spk8, mask_ws);
        expand_spk<<<8192, 256, 0, stream>>>(mask_ws, spk1);

        // layer 2: cur2 [b][256][1024] direct -> in-place LIF
        gemm_i8<false><<<dim3(4, 32, 8), 256, 0, stream>>>(
            wp2, spk8, b2, spk2, 256, 2048);
        lif_lds<32><<<256, 256, 0, stream>>>(spk2);
    } else {
        gemm_f16x3_kernel<<<dim3(8, 16, 32), 256, 0, stream>>>(
            w1, x, b1, spk1, 2048, 1024, 512, (long)512 * 1024, (long)2048 * 1024);
        lif_rows<<<(65536 + 255) / 256, 256, 0, stream>>>(spk1, 65536, 1024);
        gemm_f16x3_kernel<<<dim3(8, 2, 32), 256, 0, stream>>>(
            w2, spk1, b2, spk2, 256, 1024, 2048, (long)2048 * 1024, (long)256 * 1024);
        lif_rows<<<(8192 + 255) / 256, 256, 0, stream>>>(spk2, 8192, 1024);
    }
}

// Round 2
// 684.146 us; speedup vs baseline: 1.0866x; 1.0866x over previous
//
#include <hip/hip_runtime.h>

// ---------------------------------------------------------------------------
// LavaNetwork, bit-exact 4-plane i8 MFMA GEMM (mfma_i32_16x16x64_i8).
//   w ~ k*2^-31 (k = rint(w*2^31), residual <= 2^-32), 4 balanced base-256
//   digits -> exact i8 planes, exact i32 sums, exact i64 Horner + f64 bias.
// Round-11 structure:
//   - whole-chunk weight staging: CHUNK=8 k-tiles (64 KB LDS) staged at once,
//     then a BARRIER-FREE inner loop of CHUNK iters (4 act-loads + 8 ds_read
//     + 32 MFMA each). Layer 1 (K=512): one stage, ZERO barriers in k-loop.
//     Layer 2 (K=2048): 4 chunks, 2 barriers per chunk boundary (8 total vs
//     32 vmcnt(0) drains in round-10 -> the round-10 regression's root cause).
//   - wave tile 64t x 32m (acc 128 VGPR), 2 blocks/CU via launch_bounds(256,2)
//   - acts DIRECT to VGPR from [b][kt][t][64] layout, register double-buffer
//     with compile-time parity index
//   - grid dim3(t, b, m): same-act blocks land on one XCD (id stride % 8 == 0)
//   - weights keep the proven chunk swizzle c^((m>>1)&3) for conflict-free
//     ds_read_b128
// Fallback: round-3 proven f16 path if ws too small.
// ---------------------------------------------------------------------------

typedef int i32x4 __attribute__((ext_vector_type(4)));
typedef _Float16 f16x8 __attribute__((ext_vector_type(8)));
typedef _Float16 f16x4 __attribute__((ext_vector_type(4)));
typedef float f32x4 __attribute__((ext_vector_type(4)));

#define GLDS(g, l) __builtin_amdgcn_global_load_lds( \
    (const __attribute__((address_space(1))) void*)(g), \
    (__attribute__((address_space(3))) void*)(l), 16, 0, 0)

#define INV231 4.656612873077392578125e-10   // 2^-31

// ======================= prep =======================

// w (M,K) f32 -> wp [K/64][4][M][64] i8 digit planes; 16-B chunk c of row m
// stored at c ^ ((m>>1)&3)  (round-6/8-proven conflict-free for ds_read_b128).
__global__ __launch_bounds__(256) void prep_w8(const float* __restrict__ A,
                                               signed char* __restrict__ wp,
                                               int M, int K)
{
    long gt = (long)blockIdx.x * 256 + threadIdx.x;
    int kq4 = K >> 2;
    int m = (int)(gt / kq4), kq = (int)(gt % kq4);
    int k0 = kq * 4;
    int kt = k0 >> 6, kin = k0 & 63;
    int cw = ((kin >> 4) ^ (m >> 1)) & 3;
    float4 w = *(const float4*)&A[(long)m * K + k0];
    float wv[4] = {w.x, w.y, w.z, w.w};
    int pack[4] = {0, 0, 0, 0};
#pragma unroll
    for (int e = 0; e < 4; e++) {
        long k64 = (long)rint((double)wv[e] * 2147483648.0);  // * 2^31
#pragma unroll
        for (int j = 0; j < 3; j++) {
            long r = ((k64 + 128) & 255) - 128;   // balanced digit [-128,127]
            pack[j] |= ((int)r & 255) << (e * 8);
            k64 = (k64 - r) >> 8;
        }
        pack[3] |= ((int)k64 & 255) << (e * 8);
    }
#pragma unroll
    for (int p = 0; p < 4; p++)
        *(int*)&wp[(((long)kt * 4 + p) * M + m) * 64 + cw * 16 + (kin & 15)] = pack[p];
}

// x [b][512][1024] f32 -> x8t [b][8][1024][64] i8 (k-tile-major, plain layout
// for direct coalesced frag loads; no swizzle).
__global__ __launch_bounds__(256) void prep_x8(const float* __restrict__ x,
                                               unsigned char* __restrict__ xt)
{
    __shared__ float xs[64][68];
    const int b = blockIdx.z, i0 = blockIdx.y * 64, t0 = blockIdx.x * 64;
    const float* xb = x + ((long)b * 512 + i0) * 1024 + t0;
#pragma unroll
    for (int p = 0; p < 4; p++) {
        int f = threadIdx.x + p * 256;
        int i = f >> 4, t4 = (f & 15) * 4;
        *(float4*)&xs[i][t4] = *(const float4*)&xb[(long)i * 1024 + t4];
    }
    __syncthreads();
    int tt = threadIdx.x >> 2, c = threadIdx.x & 3;
    unsigned char bytes[16];
#pragma unroll
    for (int j = 0; j < 16; j++)
        bytes[j] = (unsigned char)xs[c * 16 + j][tt];
    *(uint4*)&xt[(((long)b * 8 + (i0 >> 6)) * 1024 + t0 + tt) * 64 + c * 16] =
        *(uint4*)bytes;
}

// ======================= GEMM (both orientations) =======================
// TRANS: D[t][M]  (acts A, weights B) -> cur1t for coalesced LIF
// !TRANS: D[M][t] (weights A, acts B) -> cur2 directly
// Block: 32m x 256t, 4 waves each own a 64-t slice (all share the 32-m LDS
// weight chunk). Wave tile 64t x 32m.
// CHUNK k-tiles of weights ([CHUNK][4][32][64] = CHUNK*8 KB) staged per phase;
// inner CHUNK-iteration loop has NO barriers (acts are register-double-
// buffered from global; compiler emits fine-grained vmcnt/lgkmcnt).
template <bool TRANS, int NITER, int CHUNK>
__global__ __launch_bounds__(256, 2) void gemm_i8(
    const signed char* __restrict__ wp,     // [K/64][4][M][64] swizzled
    const unsigned char* __restrict__ act,  // [b][K/64][1024][64] plain
    const float* __restrict__ bias,         // (M)
    float* __restrict__ C,
    int M)
{
    constexpr int NCHUNK = NITER / CHUNK;
    __shared__ signed char Ws[CHUNK][4][32][64];   // CHUNK * 8 KB

    const int b = blockIdx.y;
    const int m0 = blockIdx.z * 32, t0 = blockIdx.x * 256;
    const int tid = threadIdx.x, lane = tid & 63, wave = tid >> 6;
    const int wt = t0 + wave * 64;            // wave's global t base
    const int lm = lane & 15, lq = lane >> 4;
    const int fro = ((lq ^ (lm >> 1)) & 3) * 16;   // swizzled LDS read offset
    const int gl_row = lane >> 2, gl_col = (lane & 3) * 16;

    const unsigned char* ab = act + (long)b * NITER * 1024 * 64;

    // stage chunk cc: wave w loads plane p=w for all kt (2 GLDS per slab)
    auto stage = [&](int cc) {
#pragma unroll
        for (int j = 0; j < CHUNK; ++j) {
            const int r = wave + 4 * j;          // slab id
            const int kt = r >> 2, p = r & 3;
            const long kg = ((long)(cc * CHUNK + kt) * 4 + p);
            const signed char* g = wp + (kg * M + m0 + gl_row) * 64 + gl_col;
            GLDS(g, &Ws[kt][p][0][0]);
            GLDS(g + 16 * 64, &Ws[kt][p][16][0]);
        }
    };

    // acc[plane][q]: TRANS q = tf*2+mf, !TRANS q = mf*4+tf  (all static idx)
    i32x4 acc[4][8];
#pragma unroll
    for (int p = 0; p < 4; p++)
#pragma unroll
        for (int q = 0; q < 8; q++) acc[p][q] = (i32x4)0;

    stage(0);
    // acts iter 0 into registers (4 t-frags of 16B/lane), dbuf parity 0
    i32x4 areg[2][4];
#pragma unroll
    for (int f = 0; f < 4; f++)
        areg[0][f] = *(const i32x4*)&ab[((long)(wt + f * 16 + lm)) * 64 + lq * 16];
    __syncthreads();

    for (int c = 0; c < NCHUNK; ++c) {
#pragma unroll
        for (int kk = 0; kk < CHUNK; ++kk) {
            // prefetch acts for iter it+1 into the other parity slot
            {
                const int itv = c * CHUNK + kk;
                const long nx = (itv + 1 < NITER) ? itv + 1 : itv;
#pragma unroll
                for (int f = 0; f < 4; f++)
                    areg[(kk + 1) & 1][f] = *(const i32x4*)
                        &ab[(nx * 1024 + wt + f * 16 + lm) * 64 + lq * 16];
            }
#pragma unroll
            for (int p = 0; p < 4; p++) {
                i32x4 w0 = *(const i32x4*)&Ws[kk][p][lm][fro];
                i32x4 w1 = *(const i32x4*)&Ws[kk][p][16 + lm][fro];
                if (TRANS) {
#pragma unroll
                    for (int f = 0; f < 4; f++) {
                        acc[p][f * 2 + 0] = __builtin_amdgcn_mfma_i32_16x16x64_i8(
                            areg[kk & 1][f], w0, acc[p][f * 2 + 0], 0, 0, 0);
                        acc[p][f * 2 + 1] = __builtin_amdgcn_mfma_i32_16x16x64_i8(
                            areg[kk & 1][f], w1, acc[p][f * 2 + 1], 0, 0, 0);
                    }
                } else {
#pragma unroll
                    for (int f = 0; f < 4; f++) {
                        acc[p][0 + f] = __builtin_amdgcn_mfma_i32_16x16x64_i8(
                            w0, areg[kk & 1][f], acc[p][0 + f], 0, 0, 0);
                        acc[p][4 + f] = __builtin_amdgcn_mfma_i32_16x16x64_i8(
                            w1, areg[kk & 1][f], acc[p][4 + f], 0, 0, 0);
                    }
                }
            }
        }
        if (c + 1 < NCHUNK) {
            __syncthreads();      // all waves done reading chunk c
            stage(c + 1);
            __syncthreads();      // chunk c+1 resident (vmcnt drained)
        }
    }

    if (TRANS) {
        // D[t][m]: acc[p][tf*2+mf]; col = m (lane lm), row = t (lq*4 + r)
        double bv[2];
        bv[0] = (double)bias[m0 + lm];
        bv[1] = (double)bias[m0 + 16 + lm];
        float* Cb = C + (long)b * 1024 * M;
#pragma unroll
        for (int tf = 0; tf < 4; tf++)
#pragma unroll
            for (int r = 0; r < 4; r++) {
                const int trow = wt + tf * 16 + lq * 4 + r;
#pragma unroll
                for (int mf = 0; mf < 2; mf++) {
                    long T = acc[3][tf * 2 + mf][r];
                    T = T * 256 + acc[2][tf * 2 + mf][r];
                    T = T * 256 + acc[1][tf * 2 + mf][r];
                    T = T * 256 + acc[0][tf * 2 + mf][r];
                    Cb[(long)trow * M + m0 + mf * 16 + lm] =
                        (float)((double)T * INV231 + bv[mf]);
                }
            }
    } else {
        // D[m][t]: acc[p][mf*4+tf]; col = t (lane lm), row = m (lq*4 + r)
        float* Cb = C + (long)b * M * 1024;
#pragma unroll
        for (int mf = 0; mf < 2; mf++)
#pragma unroll
            for (int r = 0; r < 4; r++) {
                const int mrow = m0 + mf * 16 + lq * 4 + r;
                const double bv = (double)bias[mrow];
#pragma unroll
                for (int tf = 0; tf < 4; tf++) {
                    long T = acc[3][mf * 4 + tf][r];
                    T = T * 256 + acc[2][mf * 4 + tf][r];
                    T = T * 256 + acc[1][mf * 4 + tf][r];
                    T = T * 256 + acc[0][mf * 4 + tf][r];
                    Cb[(long)mrow * 1024 + wt + tf * 16 + lm] =
                        (float)((double)T * INV231 + bv);
                }
            }
    }
}

// ======================= LIF =======================

// Coalesced thread-per-row scan over cur1t [b][1024][2048]; emits i8 spikes
// [b][32][1024][64] (k-tile-major, plain) + 1024-bit masks.
// Register double-buffer: prefetch window tw+1 while scanning tw.
__global__ __launch_bounds__(256) void lif1_t(
    const float* __restrict__ ct,
    unsigned char* __restrict__ spk8,
    unsigned* __restrict__ mask_ws)
{
    const int b = blockIdx.y;
    const int m = blockIdx.x * 256 + threadIdx.x;
    const float* src = ct + (long)b * 1024 * 2048 + m;
    unsigned char* spb = spk8 + (((long)b * 32 + (m >> 6)) * 1024) * 64 + (m & 63);
    unsigned* mw = mask_ws + (long)b * 32 * 2048 + m;
    double v = 0.0;
    float c0[32], c1[32];
#pragma unroll
    for (int j = 0; j < 32; j++)
        c0[j] = src[(long)j * 2048];
    for (int tw = 0; tw < 32; tw += 2) {
        // prefetch window tw+1 (independent of the scan below)
#pragma unroll
        for (int j = 0; j < 32; j++)
            c1[j] = src[(long)((tw + 1) * 32 + j) * 2048];
        unsigned mword = 0;
#pragma unroll
        for (int j = 0; j < 32; j++) {
            v = 0.95 * v + (double)c0[j];
            bool s = v >= 1.0;
            mword |= (s ? 1u : 0u) << j;
            if (s) v = 0.0;
            spb[(long)(tw * 32 + j) * 64] = s ? 1 : 0;
        }
        mw[(long)tw * 2048] = mword;
        // prefetch window tw+2
        if (tw + 2 < 32) {
#pragma unroll
            for (int j = 0; j < 32; j++)
                c0[j] = src[(long)((tw + 2) * 32 + j) * 2048];
        }
        mword = 0;
#pragma unroll
        for (int j = 0; j < 32; j++) {
            v = 0.95 * v + (double)c1[j];
            bool s = v >= 1.0;
            mword |= (s ? 1u : 0u) << j;
            if (s) v = 0.0;
            spb[(long)((tw + 1) * 32 + j) * 64] = s ? 1 : 0;
        }
        mw[(long)(tw + 1) * 2048] = mword;
    }
}

// masks [b][32][2048] -> f32 spikes [b][2048][1024]
__global__ __launch_bounds__(256) void expand_spk(
    const unsigned* __restrict__ mask_ws,
    float* __restrict__ spk1)
{
    __shared__ unsigned msk[8][32];
    const long rowbase = (long)blockIdx.x * 8;
    const int b = (int)(rowbase >> 11), m0 = (int)(rowbase & 2047);
    const int tid = threadIdx.x;
    {
        int w = tid >> 3, r = tid & 7;
        msk[r][w] = mask_ws[((long)b * 32 + w) * 2048 + m0 + r];
    }
    __syncthreads();
    const int r = tid >> 5, l5 = tid & 31;
    float* dst = spk1 + (rowbase + r) * 1024;
    const int sh = (l5 & 7) * 4;
#pragma unroll
    for (int j = 0; j < 8; j++) {
        const int t = l5 * 4 + j * 128;
        const unsigned w = msk[r][(l5 >> 3) + j * 4];
        float4 o;
        o.x = ((w >> sh) & 1u) ? 1.f : 0.f;
        o.y = ((w >> (sh + 1)) & 1u) ? 1.f : 0.f;
        o.z = ((w >> (sh + 2)) & 1u) ? 1.f : 0.f;
        o.w = ((w >> (sh + 3)) & 1u) ? 1.f : 0.f;
        *(float4*)&dst[t] = o;
    }
}

// LDS-chunked LIF for layer 2 (proven round 4); RPB=32 -> 256 blocks (1/CU)
template <int RPB>
__global__ __launch_bounds__(256) void lif_lds(float* __restrict__ cur)
{
    __shared__ float cs[RPB][36];
    const long rowbase = (long)blockIdx.x * RPB;
    float* base = cur + rowbase * 1024;
    const int tid = threadIdx.x;
    double v = 0.0;
    const int NV = RPB * 32 / 4;
    for (int tc = 0; tc < 1024; tc += 32) {
        for (int f = tid; f < NV; f += 256) {
            int row = f >> 3, t4 = (f & 7) * 4;
            *(float4*)&cs[row][t4] = *(const float4*)&base[(long)row * 1024 + tc + t4];
        }
        __syncthreads();
        if (tid < RPB) {
#pragma unroll
            for (int j = 0; j < 32; j++) {
                v = 0.95 * v + (double)cs[tid][j];
                bool s = v >= 1.0;
                cs[tid][j] = s ? 1.f : 0.f;
                if (s) v = 0.0;
            }
        }
        __syncthreads();
        for (int f = tid; f < NV; f += 256) {
            int row = f >> 3, t4 = (f & 7) * 4;
            *(float4*)&base[(long)row * 1024 + tc + t4] = *(float4*)&cs[row][t4];
        }
        __syncthreads();
    }
}

// ======================= fallback (round 3, proven) =======================

__device__ inline void split3(float w, _Float16& q0, _Float16& q1, _Float16& q2) {
    float p0 = rintf(w * 4096.f) * 2.44140625e-4f;
    float r1 = w - p0;
    float p1s = rintf(r1 * 8388608.f) * 2.44140625e-4f;
    float r2 = r1 - p1s * 4.8828125e-4f;
    float p2s = rintf(r2 * 1.7179869184e10f) * 1.220703125e-4f;
    q0 = (_Float16)p0; q1 = (_Float16)p1s; q2 = (_Float16)p2s;
}

__global__ __launch_bounds__(256) void gemm_f16x3_kernel(
    const float* __restrict__ A, const float* __restrict__ Bmat,
    const float* __restrict__ bias, float* __restrict__ C,
    int M, int N, int K, long sB, long sC)
{
    __shared__ _Float16 As[3][128][40];
    __shared__ _Float16 Bsh[128][40];
    const int batch = blockIdx.z;
    const float* Bp = Bmat + (long)batch * sB;
    float* Cp = C + (long)batch * sC;
    const int m0 = blockIdx.y * 128, n0 = blockIdx.x * 128;
    const int tid = threadIdx.x, lane = tid & 63, wave = tid >> 6;
    const int wrow = (wave >> 1) * 64, wcol = (wave & 1) * 64;
    const int lm = lane & 15, lq = lane >> 4;
    const int a_mo = tid >> 3, a_kc = (tid & 7) * 4;
    const int b_kq = tid >> 5, b_nq = tid & 31;

    f32x4 acc[3][4][4];
#pragma unroll
    for (int p = 0; p < 3; p++)
#pragma unroll
        for (int i = 0; i < 4; i++)
#pragma unroll
            for (int j = 0; j < 4; j++) acc[p][i][j] = (f32x4)0.f;

    for (int k0 = 0; k0 < K; k0 += 32) {
#pragma unroll
        for (int i = 0; i < 4; i++) {
            const int m = i * 32 + a_mo;
            float4 w = *(const float4*)&A[(long)(m0 + m) * K + k0 + a_kc];
            _Float16 a0[4], a1[4], a2[4];
            split3(w.x, a0[0], a1[0], a2[0]);
            split3(w.y, a0[1], a1[1], a2[1]);
            split3(w.z, a0[2], a1[2], a2[2]);
            split3(w.w, a0[3], a1[3], a2[3]);
            *(f16x4*)&As[0][m][a_kc] = (f16x4){a0[0], a0[1], a0[2], a0[3]};
            *(f16x4*)&As[1][m][a_kc] = (f16x4){a1[0], a1[1], a1[2], a1[3]};
            *(f16x4*)&As[2][m][a_kc] = (f16x4){a2[0], a2[1], a2[2], a2[3]};
        }
        {
            float4 r0 = *(const float4*)&Bp[(long)(k0 + b_kq * 4 + 0) * N + n0 + b_nq * 4];
            float4 r1 = *(const float4*)&Bp[(long)(k0 + b_kq * 4 + 1) * N + n0 + b_nq * 4];
            float4 r2 = *(const float4*)&Bp[(long)(k0 + b_kq * 4 + 2) * N + n0 + b_nq * 4];
            float4 r3 = *(const float4*)&Bp[(long)(k0 + b_kq * 4 + 3) * N + n0 + b_nq * 4];
            *(f16x4*)&Bsh[b_nq * 4 + 0][b_kq * 4] =
                (f16x4){(_Float16)r0.x, (_Float16)r1.x, (_Float16)r2.x, (_Float16)r3.x};
            *(f16x4*)&Bsh[b_nq * 4 + 1][b_kq * 4] =
                (f16x4){(_Float16)r0.y, (_Float16)r1.y, (_Float16)r2.y, (_Float16)r3.y};
            *(f16x4*)&Bsh[b_nq * 4 + 2][b_kq * 4] =
                (f16x4){(_Float16)r0.z, (_Float16)r1.z, (_Float16)r2.z, (_Float16)r3.z};
            *(f16x4*)&Bsh[b_nq * 4 + 3][b_kq * 4] =
                (f16x4){(_Float16)r0.w, (_Float16)r1.w, (_Float16)r2.w, (_Float16)r3.w};
        }
        __syncthreads();
        f16x8 bf[4];
#pragma unroll
        for (int j = 0; j < 4; j++)
            bf[j] = *(const f16x8*)&Bsh[wcol + j * 16 + lm][lq * 8];
#pragma unroll
        for (int p = 0; p < 3; p++) {
            f16x8 af[4];
#pragma unroll
            for (int i = 0; i < 4; i++)
                af[i] = *(const f16x8*)&As[p][wrow + i * 16 + lm][lq * 8];
#pragma unroll
            for (int i = 0; i < 4; i++)
#pragma unroll
                for (int j = 0; j < 4; j++)
                    acc[p][i][j] = __builtin_amdgcn_mfma_f32_16x16x32_f16(
                        af[i], bf[j], acc[p][i][j], 0, 0, 0);
        }
        __syncthreads();
    }
#pragma unroll
    for (int i = 0; i < 4; i++)
#pragma unroll
        for (int r = 0; r < 4; r++) {
            const int row = m0 + wrow + i * 16 + lq * 4 + r;
            const double bv = (double)bias[row];
#pragma unroll
            for (int j = 0; j < 4; j++) {
                double s = (double)acc[0][i][j][r]
                         + (double)acc[1][i][j][r] * 4.8828125e-4
                         + (double)acc[2][i][j][r] * 4.76837158203125e-7 + bv;
                Cp[(long)row * N + n0 + wcol + j * 16 + lm] = (float)s;
            }
        }
}

__global__ __launch_bounds__(256) void lif_rows(float* __restrict__ data,
                                                long nrows, int T)
{
    long r = (long)blockIdx.x * blockDim.x + threadIdx.x;
    if (r >= nrows) return;
    float* p = data + r * (long)T;
    double v = 0.0;
    for (int t = 0; t < T; t += 4) {
        float4 c = *(float4*)(p + t);
        float4 s;
        v = 0.95 * v + (double)c.x; s.x = (v >= 1.0) ? 1.f : 0.f; if (v >= 1.0) v = 0.0;
        v = 0.95 * v + (double)c.y; s.y = (v >= 1.0) ? 1.f : 0.f; if (v >= 1.0) v = 0.0;
        v = 0.95 * v + (double)c.z; s.z = (v >= 1.0) ? 1.f : 0.f; if (v >= 1.0) v = 0.0;
        v = 0.95 * v + (double)c.w; s.w = (v >= 1.0) ? 1.f : 0.f; if (v >= 1.0) v = 0.0;
        *(float4*)(p + t) = s;
    }
}

// ======================= launch =======================

extern "C" void kernel_launch(void* const* d_in, const int* in_sizes, int n_in,
                              void* d_out, int out_size, void* d_ws, size_t ws_size,
                              hipStream_t stream)
{
    const float* x  = (const float*)d_in[0];  // (32, 512, 1024)
    const float* w1 = (const float*)d_in[1];  // (2048, 512)
    const float* b1 = (const float*)d_in[2];  // (2048)
    const float* w2 = (const float*)d_in[3];  // (256, 2048)
    const float* b2 = (const float*)d_in[4];  // (256)

    float* out  = (float*)d_out;
    float* spk1 = out;                              // (32, 2048, 1024)
    float* spk2 = out + (long)32 * 2048 * 1024;     // (32, 256, 1024)

    const size_t WP1 = 4194304;        // [8][4][2048][64] i8
    const size_t WP2 = 2097152;        // [32][4][256][64] i8
    const size_t X8T = 16777216;       // [32][8][1024][64] i8
    const size_t SPK = 67108864;       // [32][32][1024][64] i8
    const size_t MSK = 8388608;        // [32][32][2048] u32
    const size_t NEED = WP1 + WP2 + X8T + SPK + MSK;

    if (ws_size >= NEED) {
        char* ws = (char*)d_ws;
        signed char* wp1 = (signed char*)ws;
        signed char* wp2 = (signed char*)(ws + WP1);
        unsigned char* x8t = (unsigned char*)(ws + WP1 + WP2);
        unsigned char* spk8 = (unsigned char*)(ws + WP1 + WP2 + X8T);
        unsigned* mask_ws = (unsigned*)(ws + WP1 + WP2 + X8T + SPK);

        prep_w8<<<1024, 256, 0, stream>>>(w1, wp1, 2048, 512);
        prep_w8<<<512, 256, 0, stream>>>(w2, wp2, 256, 2048);
        prep_x8<<<dim3(16, 8, 32), 256, 0, stream>>>(x, x8t);

        // layer 1: cur1t [b][t][2048] -> coalesced LIF -> spikes
        // K=512 -> NITER=8, CHUNK=8: whole weight slab staged once, k-loop
        // has ZERO barriers. grid (t=4, b=32, m=64): same-act blocks on 1 XCD
        gemm_i8<true, 8, 8><<<dim3(4, 32, 64), 256, 0, stream>>>(
            wp1, x8t, b1, spk1, 2048);
        lif1_t<<<dim3(8, 32), 256, 0, stream>>>(spk1, spk8, mask_ws);
        expand_spk<<<8192, 256, 0, stream>>>(mask_ws, spk1);

        // layer 2: cur2 [b][256][1024] direct -> in-place LIF
        // K=2048 -> NITER=32, CHUNK=8: 4 chunks, 2 barriers per boundary
        gemm_i8<false, 32, 8><<<dim3(4, 32, 8), 256, 0, stream>>>(
            wp2, spk8, b2, spk2, 256);
        lif_lds<32><<<256, 256, 0, stream>>>(spk2);
    } else {
        gemm_f16x3_kernel<<<dim3(8, 16, 32), 256, 0, stream>>>(
            w1, x, b1, spk1, 2048, 1024, 512, (long)512 * 1024, (long)2048 * 1024);
        lif_rows<<<(65536 + 255) / 256, 256, 0, stream>>>(spk1, 65536, 1024);
        gemm_f16x3_kernel<<<dim3(8, 2, 32), 256, 0, stream>>>(
            w2, spk1, b2, spk2, 256, 1024, 2048, (long)2048 * 1024, (long)256 * 1024);
        lif_rows<<<(8192 + 255) / 256, 256, 0, stream>>>(spk2, 8192, 1024);
    }
}

// Round 3
// 677.430 us; speedup vs baseline: 1.0973x; 1.0099x over previous
//
#include <hip/hip_runtime.h>

// ---------------------------------------------------------------------------
// LavaNetwork, bit-exact 4-plane i8 MFMA GEMM (mfma_i32_16x16x64_i8).
//   w ~ k*2^-31 (k = rint(w*2^31), residual <= 2^-32), 4 balanced base-256
//   digits -> exact i8 planes, exact i32 sums, exact i64 Horner + f64 bias.
// Round-12 structure:
//   - FUSED gemm1+LIF (gemm_lif1): block = (b, 32m) x all 1024 t; K=512
//     weights resident in LDS (64 KB) for the whole kernel; 4 t-passes of
//     256; currents staged in LDS cs[2][256][33] (f32, double-buffered);
//     a dedicated 5th wave (320-thread block) scans LIF of pass p-1 while
//     waves 0-3 run the GEMM of pass p. Emits ONLY 1024-bit masks (8 MB)
//     -- eliminates the 256 MB cur1t write + 256 MB read + lif1_t kernel.
//   - expand_spk8: masks -> i8 spikes [b][32][1024][64] for gemm2 (64 MB).
//   - expand_spk:  masks -> f32 spk1 (unchanged).
//   - layer 2 unchanged (round-11 proven): chunked barrier-light gemm_i8 +
//     lif_lds<32>.
//   - LIF recurrence identical arithmetic: u = 0.95*u + c; on spike u = c
//     next step (== 0.95*0 + c exactly), f64 state, f32 inputs.
// Fallback: round-3 proven f16 path if ws too small.
// ---------------------------------------------------------------------------

typedef int i32x4 __attribute__((ext_vector_type(4)));
typedef _Float16 f16x8 __attribute__((ext_vector_type(8)));
typedef _Float16 f16x4 __attribute__((ext_vector_type(4)));
typedef float f32x4 __attribute__((ext_vector_type(4)));

#define GLDS(g, l) __builtin_amdgcn_global_load_lds( \
    (const __attribute__((address_space(1))) void*)(g), \
    (__attribute__((address_space(3))) void*)(l), 16, 0, 0)

#define INV231 4.656612873077392578125e-10   // 2^-31

// ======================= prep =======================

// w (M,K) f32 -> wp [K/64][4][M][64] i8 digit planes; 16-B chunk c of row m
// stored at c ^ ((m>>1)&3)  (round-6/8-proven conflict-free for ds_read_b128).
__global__ __launch_bounds__(256) void prep_w8(const float* __restrict__ A,
                                               signed char* __restrict__ wp,
                                               int M, int K)
{
    long gt = (long)blockIdx.x * 256 + threadIdx.x;
    int kq4 = K >> 2;
    int m = (int)(gt / kq4), kq = (int)(gt % kq4);
    int k0 = kq * 4;
    int kt = k0 >> 6, kin = k0 & 63;
    int cw = ((kin >> 4) ^ (m >> 1)) & 3;
    float4 w = *(const float4*)&A[(long)m * K + k0];
    float wv[4] = {w.x, w.y, w.z, w.w};
    int pack[4] = {0, 0, 0, 0};
#pragma unroll
    for (int e = 0; e < 4; e++) {
        long k64 = (long)rint((double)wv[e] * 2147483648.0);  // * 2^31
#pragma unroll
        for (int j = 0; j < 3; j++) {
            long r = ((k64 + 128) & 255) - 128;   // balanced digit [-128,127]
            pack[j] |= ((int)r & 255) << (e * 8);
            k64 = (k64 - r) >> 8;
        }
        pack[3] |= ((int)k64 & 255) << (e * 8);
    }
#pragma unroll
    for (int p = 0; p < 4; p++)
        *(int*)&wp[(((long)kt * 4 + p) * M + m) * 64 + cw * 16 + (kin & 15)] = pack[p];
}

// x [b][512][1024] f32 -> x8t [b][8][1024][64] i8 (k-tile-major, plain layout
// for direct coalesced frag loads; no swizzle).
__global__ __launch_bounds__(256) void prep_x8(const float* __restrict__ x,
                                               unsigned char* __restrict__ xt)
{
    __shared__ float xs[64][68];
    const int b = blockIdx.z, i0 = blockIdx.y * 64, t0 = blockIdx.x * 64;
    const float* xb = x + ((long)b * 512 + i0) * 1024 + t0;
#pragma unroll
    for (int p = 0; p < 4; p++) {
        int f = threadIdx.x + p * 256;
        int i = f >> 4, t4 = (f & 15) * 4;
        *(float4*)&xs[i][t4] = *(const float4*)&xb[(long)i * 1024 + t4];
    }
    __syncthreads();
    int tt = threadIdx.x >> 2, c = threadIdx.x & 3;
    unsigned char bytes[16];
#pragma unroll
    for (int j = 0; j < 16; j++)
        bytes[j] = (unsigned char)xs[c * 16 + j][tt];
    *(uint4*)&xt[(((long)b * 8 + (i0 >> 6)) * 1024 + t0 + tt) * 64 + c * 16] =
        *(uint4*)bytes;
}

// ======================= fused layer-1 GEMM + LIF =======================
// Block = (b, m-tile 32) x ALL 1024 t.  320 threads: waves 0-3 GEMM
// (wave tile 64t x 32m, proven), wave 4 = LIF scanner.
// LDS: Ws[8][4][32][64] = 64 KB (whole K=512 slab, staged once) +
//      cs[2][256][33] f32 = 66 KB current staging (double-buffered).
// 4 t-passes of 256: pass p GEMM -> cs[p&1]; wave 4 scans cs[(p-1)&1]
// concurrently (separate LDS buffers; one barrier per pass).
// Output: 1024-bit spike masks only.
// Grid dim3(32 b, 64 mb): dispatch id % 8 == b % 8 -> same-b blocks share
// one XCD's L2 for the act slab.
__global__ __launch_bounds__(320) void gemm_lif1(
    const signed char* __restrict__ wp,     // [8][4][2048][64] swizzled
    const unsigned char* __restrict__ act,  // [b][8][1024][64] plain
    const float* __restrict__ bias,         // (2048)
    unsigned* __restrict__ mask_ws)         // [b][32][2048]
{
    __shared__ signed char Ws[8][4][32][64];   // 64 KB
    __shared__ float cs[2][256][33];           // 66 KB

    const int b = blockIdx.x, m0 = blockIdx.y * 32;
    const int tid = threadIdx.x, lane = tid & 63, wave = tid >> 6;
    const int lm = lane & 15, lq = lane >> 4;
    const int fro = ((lq ^ (lm >> 1)) & 3) * 16;   // swizzled LDS read offset
    const unsigned char* ab = act + (long)b * 8 * 1024 * 64;

    i32x4 areg[2][4];
    double bv0 = 0.0, bv1 = 0.0;

    if (wave < 4) {
        // stage the whole weight slab (32 slabs x 2 GLDS / 4 waves)
        const int gl_row = lane >> 2, gl_col = (lane & 3) * 16;
#pragma unroll
        for (int j = 0; j < 8; ++j) {
            const int r = wave + 4 * j;          // slab id 0..31
            const int kt = r >> 2, p = r & 3;
            const signed char* g = wp + ((long)r * 2048 + m0 + gl_row) * 64 + gl_col;
            GLDS(g, &Ws[kt][p][0][0]);
            GLDS(g + 16 * 64, &Ws[kt][p][16][0]);
        }
        bv0 = (double)bias[m0 + lm];
        bv1 = (double)bias[m0 + 16 + lm];
        // acts (pass 0, kt 0) into parity slot 0
#pragma unroll
        for (int f = 0; f < 4; f++)
            areg[0][f] = *(const i32x4*)
                &ab[((long)(wave * 64 + f * 16 + lm)) * 64 + lq * 16];
    }
    __syncthreads();

    // LIF state (wave 4, lanes < 32: col m0+lane)
    double u = 0.0;
    bool sprev = false;

    for (int p = 0; p < 5; ++p) {
        if (wave < 4 && p < 4) {
            i32x4 acc[4][8];
#pragma unroll
            for (int pp = 0; pp < 4; pp++)
#pragma unroll
                for (int q = 0; q < 8; q++) acc[pp][q] = (i32x4)0;

#pragma unroll
            for (int kk = 0; kk < 8; ++kk) {
                // prefetch next virtual iter (pn, kn) -> other parity slot
                {
                    int pn = p, kn = kk + 1;
                    if (kn == 8) { kn = 0; pn = p + 1; if (pn > 3) { pn = 3; kn = 7; } }
                    const long tt = (long)pn * 256 + wave * 64 + lm;
#pragma unroll
                    for (int f = 0; f < 4; f++)
                        areg[(kk + 1) & 1][f] = *(const i32x4*)
                            &ab[((long)kn * 1024 + tt + f * 16) * 64 + lq * 16];
                }
#pragma unroll
                for (int pp = 0; pp < 4; pp++) {
                    i32x4 w0 = *(const i32x4*)&Ws[kk][pp][lm][fro];
                    i32x4 w1 = *(const i32x4*)&Ws[kk][pp][16 + lm][fro];
#pragma unroll
                    for (int f = 0; f < 4; f++) {
                        acc[pp][f * 2 + 0] = __builtin_amdgcn_mfma_i32_16x16x64_i8(
                            areg[kk & 1][f], w0, acc[pp][f * 2 + 0], 0, 0, 0);
                        acc[pp][f * 2 + 1] = __builtin_amdgcn_mfma_i32_16x16x64_i8(
                            areg[kk & 1][f], w1, acc[pp][f * 2 + 1], 0, 0, 0);
                    }
                }
            }
            // Horner -> exact f32 current -> cs[p&1]
            const int tb = wave * 64;
#pragma unroll
            for (int tf = 0; tf < 4; tf++)
#pragma unroll
                for (int r = 0; r < 4; r++) {
                    const int tl = tb + tf * 16 + lq * 4 + r;
#pragma unroll
                    for (int mf = 0; mf < 2; mf++) {
                        long T = acc[3][tf * 2 + mf][r];
                        T = T * 256 + acc[2][tf * 2 + mf][r];
                        T = T * 256 + acc[1][tf * 2 + mf][r];
                        T = T * 256 + acc[0][tf * 2 + mf][r];
                        cs[p & 1][tl][mf * 16 + lm] =
                            (float)((double)T * INV231 + (mf ? bv1 : bv0));
                    }
                }
        }
        if (wave == 4 && p >= 1 && lane < 32) {
            const int pp = p - 1, buf = pp & 1;
#pragma unroll 1
            for (int g = 0; g < 8; ++g) {
                unsigned mword = 0;
#pragma unroll
                for (int j = 0; j < 32; ++j) {
                    double c = (double)cs[buf][g * 32 + j][lane];
                    double a = 0.95 * u + c;
                    u = sprev ? c : a;        // spike last step -> v was 0
                    bool s = (u >= 1.0);
                    mword |= (s ? 1u : 0u) << j;
                    sprev = s;
                }
                mask_ws[((long)b * 32 + pp * 8 + g) * 2048 + m0 + lane] = mword;
            }
        }
        __syncthreads();
    }
}

// ======================= mask expanders =======================

// masks [b][32][2048] -> i8 spikes spk8 [b][32 kt][1024 t][64 m]
__global__ __launch_bounds__(256) void expand_spk8(
    const unsigned* __restrict__ mask_ws,
    unsigned char* __restrict__ spk8)
{
    __shared__ unsigned msk[64][33];
    const int b = blockIdx.x, kt = blockIdx.y;
    const int tid = threadIdx.x;
#pragma unroll
    for (int i = 0; i < 8; ++i) {
        int idx = tid + i * 256;            // 0..2047
        int tw = idx >> 6, m = idx & 63;
        msk[m][tw] = mask_ws[((long)b * 32 + tw) * 2048 + kt * 64 + m];
    }
    __syncthreads();
    unsigned char* dst = spk8 + ((long)b * 32 + kt) * 1024 * 64;
#pragma unroll
    for (int i = 0; i < 16; ++i) {
        int off = tid + i * 256;            // 16-B chunk index 0..4095
        int t = off >> 2, mq = off & 3;
        int tw = t >> 5, sh = t & 31;
        unsigned w0 = 0, w1 = 0, w2 = 0, w3 = 0;
#pragma unroll
        for (int j = 0; j < 4; ++j) {
            w0 |= ((msk[mq * 16 + j][tw] >> sh) & 1u) << (8 * j);
            w1 |= ((msk[mq * 16 + 4 + j][tw] >> sh) & 1u) << (8 * j);
            w2 |= ((msk[mq * 16 + 8 + j][tw] >> sh) & 1u) << (8 * j);
            w3 |= ((msk[mq * 16 + 12 + j][tw] >> sh) & 1u) << (8 * j);
        }
        *(uint4*)&dst[(long)off * 16] = (uint4){w0, w1, w2, w3};
    }
}

// masks [b][32][2048] -> f32 spikes [b][2048][1024]
__global__ __launch_bounds__(256) void expand_spk(
    const unsigned* __restrict__ mask_ws,
    float* __restrict__ spk1)
{
    __shared__ unsigned msk[8][32];
    const long rowbase = (long)blockIdx.x * 8;
    const int b = (int)(rowbase >> 11), m0 = (int)(rowbase & 2047);
    const int tid = threadIdx.x;
    {
        int w = tid >> 3, r = tid & 7;
        msk[r][w] = mask_ws[((long)b * 32 + w) * 2048 + m0 + r];
    }
    __syncthreads();
    const int r = tid >> 5, l5 = tid & 31;
    float* dst = spk1 + (rowbase + r) * 1024;
    const int sh = (l5 & 7) * 4;
#pragma unroll
    for (int j = 0; j < 8; j++) {
        const int t = l5 * 4 + j * 128;
        const unsigned w = msk[r][(l5 >> 3) + j * 4];
        float4 o;
        o.x = ((w >> sh) & 1u) ? 1.f : 0.f;
        o.y = ((w >> (sh + 1)) & 1u) ? 1.f : 0.f;
        o.z = ((w >> (sh + 2)) & 1u) ? 1.f : 0.f;
        o.w = ((w >> (sh + 3)) & 1u) ? 1.f : 0.f;
        *(float4*)&dst[t] = o;
    }
}

// ======================= layer-2 GEMM (round-11 proven) =======================
// !TRANS: D[M][t] (weights A, acts B) -> cur2 directly.
// CHUNK k-tiles staged per phase; inner loop barrier-free.
template <bool TRANS, int NITER, int CHUNK>
__global__ __launch_bounds__(256, 2) void gemm_i8(
    const signed char* __restrict__ wp,     // [K/64][4][M][64] swizzled
    const unsigned char* __restrict__ act,  // [b][K/64][1024][64] plain
    const float* __restrict__ bias,         // (M)
    float* __restrict__ C,
    int M)
{
    constexpr int NCHUNK = NITER / CHUNK;
    __shared__ signed char Ws[CHUNK][4][32][64];   // CHUNK * 8 KB

    const int b = blockIdx.y;
    const int m0 = blockIdx.z * 32, t0 = blockIdx.x * 256;
    const int tid = threadIdx.x, lane = tid & 63, wave = tid >> 6;
    const int wt = t0 + wave * 64;            // wave's global t base
    const int lm = lane & 15, lq = lane >> 4;
    const int fro = ((lq ^ (lm >> 1)) & 3) * 16;   // swizzled LDS read offset
    const int gl_row = lane >> 2, gl_col = (lane & 3) * 16;

    const unsigned char* ab = act + (long)b * NITER * 1024 * 64;

    auto stage = [&](int cc) {
#pragma unroll
        for (int j = 0; j < CHUNK; ++j) {
            const int r = wave + 4 * j;          // slab id
            const int kt = r >> 2, p = r & 3;
            const long kg = ((long)(cc * CHUNK + kt) * 4 + p);
            const signed char* g = wp + (kg * M + m0 + gl_row) * 64 + gl_col;
            GLDS(g, &Ws[kt][p][0][0]);
            GLDS(g + 16 * 64, &Ws[kt][p][16][0]);
        }
    };

    i32x4 acc[4][8];
#pragma unroll
    for (int p = 0; p < 4; p++)
#pragma unroll
        for (int q = 0; q < 8; q++) acc[p][q] = (i32x4)0;

    stage(0);
    i32x4 areg[2][4];
#pragma unroll
    for (int f = 0; f < 4; f++)
        areg[0][f] = *(const i32x4*)&ab[((long)(wt + f * 16 + lm)) * 64 + lq * 16];
    __syncthreads();

    for (int c = 0; c < NCHUNK; ++c) {
#pragma unroll
        for (int kk = 0; kk < CHUNK; ++kk) {
            {
                const int itv = c * CHUNK + kk;
                const long nx = (itv + 1 < NITER) ? itv + 1 : itv;
#pragma unroll
                for (int f = 0; f < 4; f++)
                    areg[(kk + 1) & 1][f] = *(const i32x4*)
                        &ab[(nx * 1024 + wt + f * 16 + lm) * 64 + lq * 16];
            }
#pragma unroll
            for (int p = 0; p < 4; p++) {
                i32x4 w0 = *(const i32x4*)&Ws[kk][p][lm][fro];
                i32x4 w1 = *(const i32x4*)&Ws[kk][p][16 + lm][fro];
                if (TRANS) {
#pragma unroll
                    for (int f = 0; f < 4; f++) {
                        acc[p][f * 2 + 0] = __builtin_amdgcn_mfma_i32_16x16x64_i8(
                            areg[kk & 1][f], w0, acc[p][f * 2 + 0], 0, 0, 0);
                        acc[p][f * 2 + 1] = __builtin_amdgcn_mfma_i32_16x16x64_i8(
                            areg[kk & 1][f], w1, acc[p][f * 2 + 1], 0, 0, 0);
                    }
                } else {
#pragma unroll
                    for (int f = 0; f < 4; f++) {
                        acc[p][0 + f] = __builtin_amdgcn_mfma_i32_16x16x64_i8(
                            w0, areg[kk & 1][f], acc[p][0 + f], 0, 0, 0);
                        acc[p][4 + f] = __builtin_amdgcn_mfma_i32_16x16x64_i8(
                            w1, areg[kk & 1][f], acc[p][4 + f], 0, 0, 0);
                    }
                }
            }
        }
        if (c + 1 < NCHUNK) {
            __syncthreads();
            stage(c + 1);
            __syncthreads();
        }
    }

    if (TRANS) {
        double bv[2];
        bv[0] = (double)bias[m0 + lm];
        bv[1] = (double)bias[m0 + 16 + lm];
        float* Cb = C + (long)b * 1024 * M;
#pragma unroll
        for (int tf = 0; tf < 4; tf++)
#pragma unroll
            for (int r = 0; r < 4; r++) {
                const int trow = wt + tf * 16 + lq * 4 + r;
#pragma unroll
                for (int mf = 0; mf < 2; mf++) {
                    long T = acc[3][tf * 2 + mf][r];
                    T = T * 256 + acc[2][tf * 2 + mf][r];
                    T = T * 256 + acc[1][tf * 2 + mf][r];
                    T = T * 256 + acc[0][tf * 2 + mf][r];
                    Cb[(long)trow * M + m0 + mf * 16 + lm] =
                        (float)((double)T * INV231 + bv[mf]);
                }
            }
    } else {
        float* Cb = C + (long)b * M * 1024;
#pragma unroll
        for (int mf = 0; mf < 2; mf++)
#pragma unroll
            for (int r = 0; r < 4; r++) {
                const int mrow = m0 + mf * 16 + lq * 4 + r;
                const double bv = (double)bias[mrow];
#pragma unroll
                for (int tf = 0; tf < 4; tf++) {
                    long T = acc[3][mf * 4 + tf][r];
                    T = T * 256 + acc[2][mf * 4 + tf][r];
                    T = T * 256 + acc[1][mf * 4 + tf][r];
                    T = T * 256 + acc[0][mf * 4 + tf][r];
                    Cb[(long)mrow * 1024 + wt + tf * 16 + lm] =
                        (float)((double)T * INV231 + bv);
                }
            }
    }
}

// LDS-chunked LIF for layer 2 (proven round 4); RPB=32 -> 256 blocks (1/CU)
template <int RPB>
__global__ __launch_bounds__(256) void lif_lds(float* __restrict__ cur)
{
    __shared__ float cs[RPB][36];
    const long rowbase = (long)blockIdx.x * RPB;
    float* base = cur + rowbase * 1024;
    const int tid = threadIdx.x;
    double v = 0.0;
    const int NV = RPB * 32 / 4;
    for (int tc = 0; tc < 1024; tc += 32) {
        for (int f = tid; f < NV; f += 256) {
            int row = f >> 3, t4 = (f & 7) * 4;
            *(float4*)&cs[row][t4] = *(const float4*)&base[(long)row * 1024 + tc + t4];
        }
        __syncthreads();
        if (tid < RPB) {
#pragma unroll
            for (int j = 0; j < 32; j++) {
                v = 0.95 * v + (double)cs[tid][j];
                bool s = v >= 1.0;
                cs[tid][j] = s ? 1.f : 0.f;
                if (s) v = 0.0;
            }
        }
        __syncthreads();
        for (int f = tid; f < NV; f += 256) {
            int row = f >> 3, t4 = (f & 7) * 4;
            *(float4*)&base[(long)row * 1024 + tc + t4] = *(float4*)&cs[row][t4];
        }
        __syncthreads();
    }
}

// ======================= fallback (round 3, proven) =======================

__device__ inline void split3(float w, _Float16& q0, _Float16& q1, _Float16& q2) {
    float p0 = rintf(w * 4096.f) * 2.44140625e-4f;
    float r1 = w - p0;
    float p1s = rintf(r1 * 8388608.f) * 2.44140625e-4f;
    float r2 = r1 - p1s * 4.8828125e-4f;
    float p2s = rintf(r2 * 1.7179869184e10f) * 1.220703125e-4f;
    q0 = (_Float16)p0; q1 = (_Float16)p1s; q2 = (_Float16)p2s;
}

__global__ __launch_bounds__(256) void gemm_f16x3_kernel(
    const float* __restrict__ A, const float* __restrict__ Bmat,
    const float* __restrict__ bias, float* __restrict__ C,
    int M, int N, int K, long sB, long sC)
{
    __shared__ _Float16 As[3][128][40];
    __shared__ _Float16 Bsh[128][40];
    const int batch = blockIdx.z;
    const float* Bp = Bmat + (long)batch * sB;
    float* Cp = C + (long)batch * sC;
    const int m0 = blockIdx.y * 128, n0 = blockIdx.x * 128;
    const int tid = threadIdx.x, lane = tid & 63, wave = tid >> 6;
    const int wrow = (wave >> 1) * 64, wcol = (wave & 1) * 64;
    const int lm = lane & 15, lq = lane >> 4;
    const int a_mo = tid >> 3, a_kc = (tid & 7) * 4;
    const int b_kq = tid >> 5, b_nq = tid & 31;

    f32x4 acc[3][4][4];
#pragma unroll
    for (int p = 0; p < 3; p++)
#pragma unroll
        for (int i = 0; i < 4; i++)
#pragma unroll
            for (int j = 0; j < 4; j++) acc[p][i][j] = (f32x4)0.f;

    for (int k0 = 0; k0 < K; k0 += 32) {
#pragma unroll
        for (int i = 0; i < 4; i++) {
            const int m = i * 32 + a_mo;
            float4 w = *(const float4*)&A[(long)(m0 + m) * K + k0 + a_kc];
            _Float16 a0[4], a1[4], a2[4];
            split3(w.x, a0[0], a1[0], a2[0]);
            split3(w.y, a0[1], a1[1], a2[1]);
            split3(w.z, a0[2], a1[2], a2[2]);
            split3(w.w, a0[3], a1[3], a2[3]);
            *(f16x4*)&As[0][m][a_kc] = (f16x4){a0[0], a0[1], a0[2], a0[3]};
            *(f16x4*)&As[1][m][a_kc] = (f16x4){a1[0], a1[1], a1[2], a1[3]};
            *(f16x4*)&As[2][m][a_kc] = (f16x4){a2[0], a2[1], a2[2], a2[3]};
        }
        {
            float4 r0 = *(const float4*)&Bp[(long)(k0 + b_kq * 4 + 0) * N + n0 + b_nq * 4];
            float4 r1 = *(const float4*)&Bp[(long)(k0 + b_kq * 4 + 1) * N + n0 + b_nq * 4];
            float4 r2 = *(const float4*)&Bp[(long)(k0 + b_kq * 4 + 2) * N + n0 + b_nq * 4];
            float4 r3 = *(const float4*)&Bp[(long)(k0 + b_kq * 4 + 3) * N + n0 + b_nq * 4];
            *(f16x4*)&Bsh[b_nq * 4 + 0][b_kq * 4] =
                (f16x4){(_Float16)r0.x, (_Float16)r1.x, (_Float16)r2.x, (_Float16)r3.x};
            *(f16x4*)&Bsh[b_nq * 4 + 1][b_kq * 4] =
                (f16x4){(_Float16)r0.y, (_Float16)r1.y, (_Float16)r2.y, (_Float16)r3.y};
            *(f16x4*)&Bsh[b_nq * 4 + 2][b_kq * 4] =
                (f16x4){(_Float16)r0.z, (_Float16)r1.z, (_Float16)r2.z, (_Float16)r3.z};
            *(f16x4*)&Bsh[b_nq * 4 + 3][b_kq * 4] =
                (f16x4){(_Float16)r0.w, (_Float16)r1.w, (_Float16)r2.w, (_Float16)r3.w};
        }
        __syncthreads();
        f16x8 bf[4];
#pragma unroll
        for (int j = 0; j < 4; j++)
            bf[j] = *(const f16x8*)&Bsh[wcol + j * 16 + lm][lq * 8];
#pragma unroll
        for (int p = 0; p < 3; p++) {
            f16x8 af[4];
#pragma unroll
            for (int i = 0; i < 4; i++)
                af[i] = *(const f16x8*)&As[p][wrow + i * 16 + lm][lq * 8];
#pragma unroll
            for (int i = 0; i < 4; i++)
#pragma unroll
                for (int j = 0; j < 4; j++)
                    acc[p][i][j] = __builtin_amdgcn_mfma_f32_16x16x32_f16(
                        af[i], bf[j], acc[p][i][j], 0, 0, 0);
        }
        __syncthreads();
    }
#pragma unroll
    for (int i = 0; i < 4; i++)
#pragma unroll
        for (int r = 0; r < 4; r++) {
            const int row = m0 + wrow + i * 16 + lq * 4 + r;
            const double bv = (double)bias[row];
#pragma unroll
            for (int j = 0; j < 4; j++) {
                double s = (double)acc[0][i][j][r]
                         + (double)acc[1][i][j][r] * 4.8828125e-4
                         + (double)acc[2][i][j][r] * 4.76837158203125e-7 + bv;
                Cp[(long)row * N + n0 + wcol + j * 16 + lm] = (float)s;
            }
        }
}

__global__ __launch_bounds__(256) void lif_rows(float* __restrict__ data,
                                                long nrows, int T)
{
    long r = (long)blockIdx.x * blockDim.x + threadIdx.x;
    if (r >= nrows) return;
    float* p = data + r * (long)T;
    double v = 0.0;
    for (int t = 0; t < T; t += 4) {
        float4 c = *(float4*)(p + t);
        float4 s;
        v = 0.95 * v + (double)c.x; s.x = (v >= 1.0) ? 1.f : 0.f; if (v >= 1.0) v = 0.0;
        v = 0.95 * v + (double)c.y; s.y = (v >= 1.0) ? 1.f : 0.f; if (v >= 1.0) v = 0.0;
        v = 0.95 * v + (double)c.z; s.z = (v >= 1.0) ? 1.f : 0.f; if (v >= 1.0) v = 0.0;
        v = 0.95 * v + (double)c.w; s.w = (v >= 1.0) ? 1.f : 0.f; if (v >= 1.0) v = 0.0;
        *(float4*)(p + t) = s;
    }
}

// ======================= launch =======================

extern "C" void kernel_launch(void* const* d_in, const int* in_sizes, int n_in,
                              void* d_out, int out_size, void* d_ws, size_t ws_size,
                              hipStream_t stream)
{
    const float* x  = (const float*)d_in[0];  // (32, 512, 1024)
    const float* w1 = (const float*)d_in[1];  // (2048, 512)
    const float* b1 = (const float*)d_in[2];  // (2048)
    const float* w2 = (const float*)d_in[3];  // (256, 2048)
    const float* b2 = (const float*)d_in[4];  // (256)

    float* out  = (float*)d_out;
    float* spk1 = out;                              // (32, 2048, 1024)
    float* spk2 = out + (long)32 * 2048 * 1024;     // (32, 256, 1024)

    const size_t WP1 = 4194304;        // [8][4][2048][64] i8
    const size_t WP2 = 2097152;        // [32][4][256][64] i8
    const size_t X8T = 16777216;       // [32][8][1024][64] i8
    const size_t SPK = 67108864;       // [32][32][1024][64] i8
    const size_t MSK = 8388608;        // [32][32][2048] u32
    const size_t NEED = WP1 + WP2 + X8T + SPK + MSK;

    if (ws_size >= NEED) {
        char* ws = (char*)d_ws;
        signed char* wp1 = (signed char*)ws;
        signed char* wp2 = (signed char*)(ws + WP1);
        unsigned char* x8t = (unsigned char*)(ws + WP1 + WP2);
        unsigned char* spk8 = (unsigned char*)(ws + WP1 + WP2 + X8T);
        unsigned* mask_ws = (unsigned*)(ws + WP1 + WP2 + X8T + SPK);

        prep_w8<<<1024, 256, 0, stream>>>(w1, wp1, 2048, 512);
        prep_w8<<<512, 256, 0, stream>>>(w2, wp2, 256, 2048);
        prep_x8<<<dim3(16, 8, 32), 256, 0, stream>>>(x, x8t);

        // layer 1: fused GEMM+LIF -> masks only (no 256 MB cur round-trip)
        gemm_lif1<<<dim3(32, 64), 320, 0, stream>>>(wp1, x8t, b1, mask_ws);
        expand_spk8<<<dim3(32, 32), 256, 0, stream>>>(mask_ws, spk8);

        // layer 2: cur2 [b][256][1024] direct -> in-place LIF
        gemm_i8<false, 32, 8><<<dim3(4, 32, 8), 256, 0, stream>>>(
            wp2, spk8, b2, spk2, 256);
        lif_lds<32><<<256, 256, 0, stream>>>(spk2);

        // f32 spike expansion for layer-1 output
        expand_spk<<<8192, 256, 0, stream>>>(mask_ws, spk1);
    } else {
        gemm_f16x3_kernel<<<dim3(8, 16, 32), 256, 0, stream>>>(
            w1, x, b1, spk1, 2048, 1024, 512, (long)512 * 1024, (long)2048 * 1024);
        lif_rows<<<(65536 + 255) / 256, 256, 0, stream>>>(spk1, 65536, 1024);
        gemm_f16x3_kernel<<<dim3(8, 2, 32), 256, 0, stream>>>(
            w2, spk1, b2, spk2, 256, 1024, 2048, (long)2048 * 1024, (long)256 * 1024);
        lif_rows<<<(8192 + 255) / 256, 256, 0, stream>>>(spk2, 8192, 1024);
    }
}

// Round 4
// 658.871 us; speedup vs baseline: 1.1283x; 1.0282x over previous
//
#include <hip/hip_runtime.h>

// ---------------------------------------------------------------------------
// LavaNetwork, bit-exact 4-plane i8 MFMA GEMM (mfma_i32_16x16x64_i8).
//   w ~ k*2^-31 (k = rint(w*2^31), residual <= 2^-32), 4 balanced base-256
//   digits -> exact i8 planes, exact i32 sums, exact i64 Horner + f64 bias.
// Round-13 structure:
//   - FUSED gemm1+LIF (gemm_lif1), re-tiled for occupancy: m-tile 16,
//     192 threads (2 GEMM waves 64t x 16m + 1 LIF wave), LDS 49 KB
//     (Ws[8][4][16][64]=32K whole-K resident + cs[2][128][17]=17.4K)
//     -> 3 blocks/CU (was 1 at 130 KB). One block's serial LIF chain now
//     overlaps other blocks' GEMM; 48 LIF chains/CU in flight (was 32).
//     8 t-passes of 128; double-buffered cs, one barrier per pass;
//     k-loop itself barrier-free (whole weight slab resident).
//   - Emits 1024-bit masks only (8 MB); no 256 MB current round-trip.
//   - expand_spk8: masks -> i8 spikes for gemm2. expand_spk: masks -> f32.
//   - layer 2 unchanged (round-11 proven): chunked barrier-light gemm_i8 +
//     lif_lds<32>.
//   - LIF recurrence identical arithmetic: u = 0.95*u + c; on spike u = c
//     next step (== 0.95*0 + c exactly), f64 state, f32 inputs.
// Fallback: round-3 proven f16 path if ws too small.
// ---------------------------------------------------------------------------

typedef int i32x4 __attribute__((ext_vector_type(4)));
typedef _Float16 f16x8 __attribute__((ext_vector_type(8)));
typedef _Float16 f16x4 __attribute__((ext_vector_type(4)));
typedef float f32x4 __attribute__((ext_vector_type(4)));

#define GLDS(g, l) __builtin_amdgcn_global_load_lds( \
    (const __attribute__((address_space(1))) void*)(g), \
    (__attribute__((address_space(3))) void*)(l), 16, 0, 0)

#define INV231 4.656612873077392578125e-10   // 2^-31

// ======================= prep =======================

// w (M,K) f32 -> wp [K/64][4][M][64] i8 digit planes; 16-B chunk c of row m
// stored at c ^ ((m>>1)&3)  (round-6/8-proven conflict-free for ds_read_b128).
__global__ __launch_bounds__(256) void prep_w8(const float* __restrict__ A,
                                               signed char* __restrict__ wp,
                                               int M, int K)
{
    long gt = (long)blockIdx.x * 256 + threadIdx.x;
    int kq4 = K >> 2;
    int m = (int)(gt / kq4), kq = (int)(gt % kq4);
    int k0 = kq * 4;
    int kt = k0 >> 6, kin = k0 & 63;
    int cw = ((kin >> 4) ^ (m >> 1)) & 3;
    float4 w = *(const float4*)&A[(long)m * K + k0];
    float wv[4] = {w.x, w.y, w.z, w.w};
    int pack[4] = {0, 0, 0, 0};
#pragma unroll
    for (int e = 0; e < 4; e++) {
        long k64 = (long)rint((double)wv[e] * 2147483648.0);  // * 2^31
#pragma unroll
        for (int j = 0; j < 3; j++) {
            long r = ((k64 + 128) & 255) - 128;   // balanced digit [-128,127]
            pack[j] |= ((int)r & 255) << (e * 8);
            k64 = (k64 - r) >> 8;
        }
        pack[3] |= ((int)k64 & 255) << (e * 8);
    }
#pragma unroll
    for (int p = 0; p < 4; p++)
        *(int*)&wp[(((long)kt * 4 + p) * M + m) * 64 + cw * 16 + (kin & 15)] = pack[p];
}

// x [b][512][1024] f32 -> x8t [b][8][1024][64] i8 (k-tile-major, plain layout
// for direct coalesced frag loads; no swizzle).
__global__ __launch_bounds__(256) void prep_x8(const float* __restrict__ x,
                                               unsigned char* __restrict__ xt)
{
    __shared__ float xs[64][68];
    const int b = blockIdx.z, i0 = blockIdx.y * 64, t0 = blockIdx.x * 64;
    const float* xb = x + ((long)b * 512 + i0) * 1024 + t0;
#pragma unroll
    for (int p = 0; p < 4; p++) {
        int f = threadIdx.x + p * 256;
        int i = f >> 4, t4 = (f & 15) * 4;
        *(float4*)&xs[i][t4] = *(const float4*)&xb[(long)i * 1024 + t4];
    }
    __syncthreads();
    int tt = threadIdx.x >> 2, c = threadIdx.x & 3;
    unsigned char bytes[16];
#pragma unroll
    for (int j = 0; j < 16; j++)
        bytes[j] = (unsigned char)xs[c * 16 + j][tt];
    *(uint4*)&xt[(((long)b * 8 + (i0 >> 6)) * 1024 + t0 + tt) * 64 + c * 16] =
        *(uint4*)bytes;
}

// ======================= fused layer-1 GEMM + LIF =======================
// Block = (16 m, b) x ALL 1024 t. 192 threads: waves 0-1 GEMM (64t x 16m
// each), wave 2 = LIF scanner (lanes 0-15, one chain per m).
// LDS: Ws[8][4][16][64] = 32 KB (whole K=512 slab, staged once) +
//      cs[2][128][17] f32 = 17.4 KB (double-buffered current staging).
// 8 t-passes of 128: pass p GEMM -> cs[p&1]; LIF scans cs[(p-1)&1]
// concurrently; one barrier per pass. 49 KB LDS -> 3 blocks/CU so LIF
// drains overlap other blocks' GEMM.
// Output: 1024-bit spike masks only.
__global__ __launch_bounds__(192, 2) void gemm_lif1(
    const signed char* __restrict__ wp,     // [8][4][2048][64] swizzled
    const unsigned char* __restrict__ act,  // [b][8][1024][64] plain
    const float* __restrict__ bias,         // (2048)
    unsigned* __restrict__ mask_ws)         // [b][32][2048]
{
    __shared__ signed char Ws[8][4][16][64];   // 32 KB
    __shared__ float cs[2][128][17];           // 17.4 KB

    const int m0 = blockIdx.x * 16, b = blockIdx.y;
    const int tid = threadIdx.x, lane = tid & 63, wave = tid >> 6;
    const int lm = lane & 15, lq = lane >> 4;
    const int fro = ((lq ^ (lm >> 1)) & 3) * 16;   // swizzled LDS read offset
    const unsigned char* ab = act + (long)b * 8 * 1024 * 64;

    i32x4 areg[2][4];
    double bv0 = 0.0;

    if (wave < 2) {
        // stage the whole weight slab: 32 slabs of [16][64]=1KB, 16 GLDS/wave
        const int gl_row = lane >> 2, gl_col = (lane & 3) * 16;
#pragma unroll
        for (int j = 0; j < 16; ++j) {
            const int r = wave + 2 * j;          // slab id 0..31
            const int kt = r >> 2, p = r & 3;
            const signed char* g = wp + ((long)r * 2048 + m0 + gl_row) * 64 + gl_col;
            GLDS(g, &Ws[kt][p][0][0]);
        }
        bv0 = (double)bias[m0 + lm];
        // acts (pass 0, kt 0) into parity slot 0
#pragma unroll
        for (int f = 0; f < 4; f++)
            areg[0][f] = *(const i32x4*)
                &ab[((long)(wave * 64 + f * 16 + lm)) * 64 + lq * 16];
    }
    __syncthreads();

    // LIF state (wave 2, lanes < 16: chain for col m0+lane)
    double u = 0.0;
    bool sprev = false;

    for (int p = 0; p < 9; ++p) {
        if (wave < 2 && p < 8) {
            i32x4 acc[4][4];   // [plane][t-frag]
#pragma unroll
            for (int pp = 0; pp < 4; pp++)
#pragma unroll
                for (int f = 0; f < 4; f++) acc[pp][f] = (i32x4)0;

#pragma unroll
            for (int kk = 0; kk < 8; ++kk) {
                // prefetch next virtual iter (pn, kn) -> other parity slot
                {
                    int pn = p, kn = kk + 1;
                    if (kn == 8) { kn = 0; pn = p + 1; if (pn > 7) { pn = 7; kn = 7; } }
                    const long tt = (long)pn * 128 + wave * 64 + lm;
#pragma unroll
                    for (int f = 0; f < 4; f++)
                        areg[(kk + 1) & 1][f] = *(const i32x4*)
                            &ab[((long)kn * 1024 + tt + f * 16) * 64 + lq * 16];
                }
#pragma unroll
                for (int pp = 0; pp < 4; pp++) {
                    i32x4 w0 = *(const i32x4*)&Ws[kk][pp][lm][fro];
#pragma unroll
                    for (int f = 0; f < 4; f++)
                        acc[pp][f] = __builtin_amdgcn_mfma_i32_16x16x64_i8(
                            areg[kk & 1][f], w0, acc[pp][f], 0, 0, 0);
                }
            }
            // Horner -> exact f32 current -> cs[p&1]
            const int tb = wave * 64;
#pragma unroll
            for (int tf = 0; tf < 4; tf++)
#pragma unroll
                for (int r = 0; r < 4; r++) {
                    long T = acc[3][tf][r];
                    T = T * 256 + acc[2][tf][r];
                    T = T * 256 + acc[1][tf][r];
                    T = T * 256 + acc[0][tf][r];
                    cs[p & 1][tb + tf * 16 + lq * 4 + r][lm] =
                        (float)((double)T * INV231 + bv0);
                }
        }
        if (wave == 2 && p >= 1 && lane < 16) {
            const int pq = p - 1, buf = pq & 1;
#pragma unroll 1
            for (int g = 0; g < 4; ++g) {
                unsigned mword = 0;
#pragma unroll
                for (int j = 0; j < 32; ++j) {
                    double c = (double)cs[buf][g * 32 + j][lane];
                    double a = 0.95 * u + c;
                    u = sprev ? c : a;        // spike last step -> v was 0
                    bool s = (u >= 1.0);
                    mword |= (s ? 1u : 0u) << j;
                    sprev = s;
                }
                mask_ws[((long)b * 32 + pq * 4 + g) * 2048 + m0 + lane] = mword;
            }
        }
        __syncthreads();
    }
}

// ======================= mask expanders =======================

// masks [b][32][2048] -> i8 spikes spk8 [b][32 kt][1024 t][64 m]
__global__ __launch_bounds__(256) void expand_spk8(
    const unsigned* __restrict__ mask_ws,
    unsigned char* __restrict__ spk8)
{
    __shared__ unsigned msk[64][33];
    const int b = blockIdx.x, kt = blockIdx.y;
    const int tid = threadIdx.x;
#pragma unroll
    for (int i = 0; i < 8; ++i) {
        int idx = tid + i * 256;            // 0..2047
        int tw = idx >> 6, m = idx & 63;
        msk[m][tw] = mask_ws[((long)b * 32 + tw) * 2048 + kt * 64 + m];
    }
    __syncthreads();
    unsigned char* dst = spk8 + ((long)b * 32 + kt) * 1024 * 64;
#pragma unroll
    for (int i = 0; i < 16; ++i) {
        int off = tid + i * 256;            // 16-B chunk index 0..4095
        int t = off >> 2, mq = off & 3;
        int tw = t >> 5, sh = t & 31;
        unsigned w0 = 0, w1 = 0, w2 = 0, w3 = 0;
#pragma unroll
        for (int j = 0; j < 4; ++j) {
            w0 |= ((msk[mq * 16 + j][tw] >> sh) & 1u) << (8 * j);
            w1 |= ((msk[mq * 16 + 4 + j][tw] >> sh) & 1u) << (8 * j);
            w2 |= ((msk[mq * 16 + 8 + j][tw] >> sh) & 1u) << (8 * j);
            w3 |= ((msk[mq * 16 + 12 + j][tw] >> sh) & 1u) << (8 * j);
        }
        *(uint4*)&dst[(long)off * 16] = (uint4){w0, w1, w2, w3};
    }
}

// masks [b][32][2048] -> f32 spikes [b][2048][1024]
__global__ __launch_bounds__(256) void expand_spk(
    const unsigned* __restrict__ mask_ws,
    float* __restrict__ spk1)
{
    __shared__ unsigned msk[8][32];
    const long rowbase = (long)blockIdx.x * 8;
    const int b = (int)(rowbase >> 11), m0 = (int)(rowbase & 2047);
    const int tid = threadIdx.x;
    {
        int w = tid >> 3, r = tid & 7;
        msk[r][w] = mask_ws[((long)b * 32 + w) * 2048 + m0 + r];
    }
    __syncthreads();
    const int r = tid >> 5, l5 = tid & 31;
    float* dst = spk1 + (rowbase + r) * 1024;
    const int sh = (l5 & 7) * 4;
#pragma unroll
    for (int j = 0; j < 8; j++) {
        const int t = l5 * 4 + j * 128;
        const unsigned w = msk[r][(l5 >> 3) + j * 4];
        float4 o;
        o.x = ((w >> sh) & 1u) ? 1.f : 0.f;
        o.y = ((w >> (sh + 1)) & 1u) ? 1.f : 0.f;
        o.z = ((w >> (sh + 2)) & 1u) ? 1.f : 0.f;
        o.w = ((w >> (sh + 3)) & 1u) ? 1.f : 0.f;
        *(float4*)&dst[t] = o;
    }
}

// ======================= layer-2 GEMM (round-11 proven) =======================
// !TRANS: D[M][t] (weights A, acts B) -> cur2 directly.
// CHUNK k-tiles staged per phase; inner loop barrier-free.
template <bool TRANS, int NITER, int CHUNK>
__global__ __launch_bounds__(256, 2) void gemm_i8(
    const signed char* __restrict__ wp,     // [K/64][4][M][64] swizzled
    const unsigned char* __restrict__ act,  // [b][K/64][1024][64] plain
    const float* __restrict__ bias,         // (M)
    float* __restrict__ C,
    int M)
{
    constexpr int NCHUNK = NITER / CHUNK;
    __shared__ signed char Ws[CHUNK][4][32][64];   // CHUNK * 8 KB

    const int b = blockIdx.y;
    const int m0 = blockIdx.z * 32, t0 = blockIdx.x * 256;
    const int tid = threadIdx.x, lane = tid & 63, wave = tid >> 6;
    const int wt = t0 + wave * 64;            // wave's global t base
    const int lm = lane & 15, lq = lane >> 4;
    const int fro = ((lq ^ (lm >> 1)) & 3) * 16;   // swizzled LDS read offset
    const int gl_row = lane >> 2, gl_col = (lane & 3) * 16;

    const unsigned char* ab = act + (long)b * NITER * 1024 * 64;

    auto stage = [&](int cc) {
#pragma unroll
        for (int j = 0; j < CHUNK; ++j) {
            const int r = wave + 4 * j;          // slab id
            const int kt = r >> 2, p = r & 3;
            const long kg = ((long)(cc * CHUNK + kt) * 4 + p);
            const signed char* g = wp + (kg * M + m0 + gl_row) * 64 + gl_col;
            GLDS(g, &Ws[kt][p][0][0]);
            GLDS(g + 16 * 64, &Ws[kt][p][16][0]);
        }
    };

    i32x4 acc[4][8];
#pragma unroll
    for (int p = 0; p < 4; p++)
#pragma unroll
        for (int q = 0; q < 8; q++) acc[p][q] = (i32x4)0;

    stage(0);
    i32x4 areg[2][4];
#pragma unroll
    for (int f = 0; f < 4; f++)
        areg[0][f] = *(const i32x4*)&ab[((long)(wt + f * 16 + lm)) * 64 + lq * 16];
    __syncthreads();

    for (int c = 0; c < NCHUNK; ++c) {
#pragma unroll
        for (int kk = 0; kk < CHUNK; ++kk) {
            {
                const int itv = c * CHUNK + kk;
                const long nx = (itv + 1 < NITER) ? itv + 1 : itv;
#pragma unroll
                for (int f = 0; f < 4; f++)
                    areg[(kk + 1) & 1][f] = *(const i32x4*)
                        &ab[(nx * 1024 + wt + f * 16 + lm) * 64 + lq * 16];
            }
#pragma unroll
            for (int p = 0; p < 4; p++) {
                i32x4 w0 = *(const i32x4*)&Ws[kk][p][lm][fro];
                i32x4 w1 = *(const i32x4*)&Ws[kk][p][16 + lm][fro];
                if (TRANS) {
#pragma unroll
                    for (int f = 0; f < 4; f++) {
                        acc[p][f * 2 + 0] = __builtin_amdgcn_mfma_i32_16x16x64_i8(
                            areg[kk & 1][f], w0, acc[p][f * 2 + 0], 0, 0, 0);
                        acc[p][f * 2 + 1] = __builtin_amdgcn_mfma_i32_16x16x64_i8(
                            areg[kk & 1][f], w1, acc[p][f * 2 + 1], 0, 0, 0);
                    }
                } else {
#pragma unroll
                    for (int f = 0; f < 4; f++) {
                        acc[p][0 + f] = __builtin_amdgcn_mfma_i32_16x16x64_i8(
                            w0, areg[kk & 1][f], acc[p][0 + f], 0, 0, 0);
                        acc[p][4 + f] = __builtin_amdgcn_mfma_i32_16x16x64_i8(
                            w1, areg[kk & 1][f], acc[p][4 + f], 0, 0, 0);
                    }
                }
            }
        }
        if (c + 1 < NCHUNK) {
            __syncthreads();
            stage(c + 1);
            __syncthreads();
        }
    }

    if (TRANS) {
        double bv[2];
        bv[0] = (double)bias[m0 + lm];
        bv[1] = (double)bias[m0 + 16 + lm];
        float* Cb = C + (long)b * 1024 * M;
#pragma unroll
        for (int tf = 0; tf < 4; tf++)
#pragma unroll
            for (int r = 0; r < 4; r++) {
                const int trow = wt + tf * 16 + lq * 4 + r;
#pragma unroll
                for (int mf = 0; mf < 2; mf++) {
                    long T = acc[3][tf * 2 + mf][r];
                    T = T * 256 + acc[2][tf * 2 + mf][r];
                    T = T * 256 + acc[1][tf * 2 + mf][r];
                    T = T * 256 + acc[0][tf * 2 + mf][r];
                    Cb[(long)trow * M + m0 + mf * 16 + lm] =
                        (float)((double)T * INV231 + bv[mf]);
                }
            }
    } else {
        float* Cb = C + (long)b * M * 1024;
#pragma unroll
        for (int mf = 0; mf < 2; mf++)
#pragma unroll
            for (int r = 0; r < 4; r++) {
                const int mrow = m0 + mf * 16 + lq * 4 + r;
                const double bv = (double)bias[mrow];
#pragma unroll
                for (int tf = 0; tf < 4; tf++) {
                    long T = acc[3][mf * 4 + tf][r];
                    T = T * 256 + acc[2][mf * 4 + tf][r];
                    T = T * 256 + acc[1][mf * 4 + tf][r];
                    T = T * 256 + acc[0][mf * 4 + tf][r];
                    Cb[(long)mrow * 1024 + wt + tf * 16 + lm] =
                        (float)((double)T * INV231 + bv);
                }
            }
    }
}

// LDS-chunked LIF for layer 2 (proven round 4); RPB=32 -> 256 blocks (1/CU)
template <int RPB>
__global__ __launch_bounds__(256) void lif_lds(float* __restrict__ cur)
{
    __shared__ float cs[RPB][36];
    const long rowbase = (long)blockIdx.x * RPB;
    float* base = cur + rowbase * 1024;
    const int tid = threadIdx.x;
    double v = 0.0;
    const int NV = RPB * 32 / 4;
    for (int tc = 0; tc < 1024; tc += 32) {
        for (int f = tid; f < NV; f += 256) {
            int row = f >> 3, t4 = (f & 7) * 4;
            *(float4*)&cs[row][t4] = *(const float4*)&base[(long)row * 1024 + tc + t4];
        }
        __syncthreads();
        if (tid < RPB) {
#pragma unroll
            for (int j = 0; j < 32; j++) {
                v = 0.95 * v + (double)cs[tid][j];
                bool s = v >= 1.0;
                cs[tid][j] = s ? 1.f : 0.f;
                if (s) v = 0.0;
            }
        }
        __syncthreads();
        for (int f = tid; f < NV; f += 256) {
            int row = f >> 3, t4 = (f & 7) * 4;
            *(float4*)&base[(long)row * 1024 + tc + t4] = *(float4*)&cs[row][t4];
        }
        __syncthreads();
    }
}

// ======================= fallback (round 3, proven) =======================

__device__ inline void split3(float w, _Float16& q0, _Float16& q1, _Float16& q2) {
    float p0 = rintf(w * 4096.f) * 2.44140625e-4f;
    float r1 = w - p0;
    float p1s = rintf(r1 * 8388608.f) * 2.44140625e-4f;
    float r2 = r1 - p1s * 4.8828125e-4f;
    float p2s = rintf(r2 * 1.7179869184e10f) * 1.220703125e-4f;
    q0 = (_Float16)p0; q1 = (_Float16)p1s; q2 = (_Float16)p2s;
}

__global__ __launch_bounds__(256) void gemm_f16x3_kernel(
    const float* __restrict__ A, const float* __restrict__ Bmat,
    const float* __restrict__ bias, float* __restrict__ C,
    int M, int N, int K, long sB, long sC)
{
    __shared__ _Float16 As[3][128][40];
    __shared__ _Float16 Bsh[128][40];
    const int batch = blockIdx.z;
    const float* Bp = Bmat + (long)batch * sB;
    float* Cp = C + (long)batch * sC;
    const int m0 = blockIdx.y * 128, n0 = blockIdx.x * 128;
    const int tid = threadIdx.x, lane = tid & 63, wave = tid >> 6;
    const int wrow = (wave >> 1) * 64, wcol = (wave & 1) * 64;
    const int lm = lane & 15, lq = lane >> 4;
    const int a_mo = tid >> 3, a_kc = (tid & 7) * 4;
    const int b_kq = tid >> 5, b_nq = tid & 31;

    f32x4 acc[3][4][4];
#pragma unroll
    for (int p = 0; p < 3; p++)
#pragma unroll
        for (int i = 0; i < 4; i++)
#pragma unroll
            for (int j = 0; j < 4; j++) acc[p][i][j] = (f32x4)0.f;

    for (int k0 = 0; k0 < K; k0 += 32) {
#pragma unroll
        for (int i = 0; i < 4; i++) {
            const int m = i * 32 + a_mo;
            float4 w = *(const float4*)&A[(long)(m0 + m) * K + k0 + a_kc];
            _Float16 a0[4], a1[4], a2[4];
            split3(w.x, a0[0], a1[0], a2[0]);
            split3(w.y, a0[1], a1[1], a2[1]);
            split3(w.z, a0[2], a1[2], a2[2]);
            split3(w.w, a0[3], a1[3], a2[3]);
            *(f16x4*)&As[0][m][a_kc] = (f16x4){a0[0], a0[1], a0[2], a0[3]};
            *(f16x4*)&As[1][m][a_kc] = (f16x4){a1[0], a1[1], a1[2], a1[3]};
            *(f16x4*)&As[2][m][a_kc] = (f16x4){a2[0], a2[1], a2[2], a2[3]};
        }
        {
            float4 r0 = *(const float4*)&Bp[(long)(k0 + b_kq * 4 + 0) * N + n0 + b_nq * 4];
            float4 r1 = *(const float4*)&Bp[(long)(k0 + b_kq * 4 + 1) * N + n0 + b_nq * 4];
            float4 r2 = *(const float4*)&Bp[(long)(k0 + b_kq * 4 + 2) * N + n0 + b_nq * 4];
            float4 r3 = *(const float4*)&Bp[(long)(k0 + b_kq * 4 + 3) * N + n0 + b_nq * 4];
            *(f16x4*)&Bsh[b_nq * 4 + 0][b_kq * 4] =
                (f16x4){(_Float16)r0.x, (_Float16)r1.x, (_Float16)r2.x, (_Float16)r3.x};
            *(f16x4*)&Bsh[b_nq * 4 + 1][b_kq * 4] =
                (f16x4){(_Float16)r0.y, (_Float16)r1.y, (_Float16)r2.y, (_Float16)r3.y};
            *(f16x4*)&Bsh[b_nq * 4 + 2][b_kq * 4] =
                (f16x4){(_Float16)r0.z, (_Float16)r1.z, (_Float16)r2.z, (_Float16)r3.z};
            *(f16x4*)&Bsh[b_nq * 4 + 3][b_kq * 4] =
                (f16x4){(_Float16)r0.w, (_Float16)r1.w, (_Float16)r2.w, (_Float16)r3.w};
        }
        __syncthreads();
        f16x8 bf[4];
#pragma unroll
        for (int j = 0; j < 4; j++)
            bf[j] = *(const f16x8*)&Bsh[wcol + j * 16 + lm][lq * 8];
#pragma unroll
        for (int p = 0; p < 3; p++) {
            f16x8 af[4];
#pragma unroll
            for (int i = 0; i < 4; i++)
                af[i] = *(const f16x8*)&As[p][wrow + i * 16 + lm][lq * 8];
#pragma unroll
            for (int i = 0; i < 4; i++)
#pragma unroll
                for (int j = 0; j < 4; j++)
                    acc[p][i][j] = __builtin_amdgcn_mfma_f32_16x16x32_f16(
                        af[i], bf[j], acc[p][i][j], 0, 0, 0);
        }
        __syncthreads();
    }
#pragma unroll
    for (int i = 0; i < 4; i++)
#pragma unroll
        for (int r = 0; r < 4; r++) {
            const int row = m0 + wrow + i * 16 + lq * 4 + r;
            const double bv = (double)bias[row];
#pragma unroll
            for (int j = 0; j < 4; j++) {
                double s = (double)acc[0][i][j][r]
                         + (double)acc[1][i][j][r] * 4.8828125e-4
                         + (double)acc[2][i][j][r] * 4.76837158203125e-7 + bv;
                Cp[(long)row * N + n0 + wcol + j * 16 + lm] = (float)s;
            }
        }
}

__global__ __launch_bounds__(256) void lif_rows(float* __restrict__ data,
                                                long nrows, int T)
{
    long r = (long)blockIdx.x * blockDim.x + threadIdx.x;
    if (r >= nrows) return;
    float* p = data + r * (long)T;
    double v = 0.0;
    for (int t = 0; t < T; t += 4) {
        float4 c = *(float4*)(p + t);
        float4 s;
        v = 0.95 * v + (double)c.x; s.x = (v >= 1.0) ? 1.f : 0.f; if (v >= 1.0) v = 0.0;
        v = 0.95 * v + (double)c.y; s.y = (v >= 1.0) ? 1.f : 0.f; if (v >= 1.0) v = 0.0;
        v = 0.95 * v + (double)c.z; s.z = (v >= 1.0) ? 1.f : 0.f; if (v >= 1.0) v = 0.0;
        v = 0.95 * v + (double)c.w; s.w = (v >= 1.0) ? 1.f : 0.f; if (v >= 1.0) v = 0.0;
        *(float4*)(p + t) = s;
    }
}

// ======================= launch =======================

extern "C" void kernel_launch(void* const* d_in, const int* in_sizes, int n_in,
                              void* d_out, int out_size, void* d_ws, size_t ws_size,
                              hipStream_t stream)
{
    const float* x  = (const float*)d_in[0];  // (32, 512, 1024)
    const float* w1 = (const float*)d_in[1];  // (2048, 512)
    const float* b1 = (const float*)d_in[2];  // (2048)
    const float* w2 = (const float*)d_in[3];  // (256, 2048)
    const float* b2 = (const float*)d_in[4];  // (256)

    float* out  = (float*)d_out;
    float* spk1 = out;                              // (32, 2048, 1024)
    float* spk2 = out + (long)32 * 2048 * 1024;     // (32, 256, 1024)

    const size_t WP1 = 4194304;        // [8][4][2048][64] i8
    const size_t WP2 = 2097152;        // [32][4][256][64] i8
    const size_t X8T = 16777216;       // [32][8][1024][64] i8
    const size_t SPK = 67108864;       // [32][32][1024][64] i8
    const size_t MSK = 8388608;        // [32][32][2048] u32
    const size_t NEED = WP1 + WP2 + X8T + SPK + MSK;

    if (ws_size >= NEED) {
        char* ws = (char*)d_ws;
        signed char* wp1 = (signed char*)ws;
        signed char* wp2 = (signed char*)(ws + WP1);
        unsigned char* x8t = (unsigned char*)(ws + WP1 + WP2);
        unsigned char* spk8 = (unsigned char*)(ws + WP1 + WP2 + X8T);
        unsigned* mask_ws = (unsigned*)(ws + WP1 + WP2 + X8T + SPK);

        prep_w8<<<1024, 256, 0, stream>>>(w1, wp1, 2048, 512);
        prep_w8<<<512, 256, 0, stream>>>(w2, wp2, 256, 2048);
        prep_x8<<<dim3(16, 8, 32), 256, 0, stream>>>(x, x8t);

        // layer 1: fused GEMM+LIF -> masks only; 16-m blocks, 3/CU
        gemm_lif1<<<dim3(128, 32), 192, 0, stream>>>(wp1, x8t, b1, mask_ws);
        expand_spk8<<<dim3(32, 32), 256, 0, stream>>>(mask_ws, spk8);

        // layer 2: cur2 [b][256][1024] direct -> in-place LIF
        gemm_i8<false, 32, 8><<<dim3(4, 32, 8), 256, 0, stream>>>(
            wp2, spk8, b2, spk2, 256);
        lif_lds<32><<<256, 256, 0, stream>>>(spk2);

        // f32 spike expansion for layer-1 output
        expand_spk<<<8192, 256, 0, stream>>>(mask_ws, spk1);
    } else {
        gemm_f16x3_kernel<<<dim3(8, 16, 32), 256, 0, stream>>>(
            w1, x, b1, spk1, 2048, 1024, 512, (long)512 * 1024, (long)2048 * 1024);
        lif_rows<<<(65536 + 255) / 256, 256, 0, stream>>>(spk1, 65536, 1024);
        gemm_f16x3_kernel<<<dim3(8, 2, 32), 256, 0, stream>>>(
            w2, spk1, b2, spk2, 256, 1024, 2048, (long)2048 * 1024, (long)256 * 1024);
        lif_rows<<<(8192 + 255) / 256, 256, 0, stream>>>(spk2, 8192, 1024);
    }
}

// Round 5
// 647.074 us; speedup vs baseline: 1.1488x; 1.0182x over previous
//
#include <hip/hip_runtime.h>

// ---------------------------------------------------------------------------
// LavaNetwork, bit-exact 4-plane i8 MFMA GEMM (mfma_i32_16x16x64_i8).
//   w ~ k*2^-31 (k = rint(w*2^31), residual <= 2^-32), 4 balanced base-256
//   digits -> exact i8 planes, exact i32 sums, exact i64 Horner + f64 bias.
// Round-14 structure:
//   - gemm_lif1 (fused, round-13 tiling: 192 thr, 2 GEMM waves 64tx16m +
//     1 LIF wave, 49 KB LDS, 3 blocks/CU) with LIF REGISTER PRELOAD:
//     each 32-step group's currents are loaded into registers with 32
//     independent ds_reads (one wait), then the f64 recurrence runs
//     register-only; groups are software-pipelined (load g+1 || chain g).
//     Round-4 PMC showed ~88 cyc/LIF-step == LDS latency inside the
//     dependent chain; this removes it (~15 cyc/step predicted).
//   - lif_lds (layer-2 scan): same preload fix.
//   - everything else unchanged from round 13 (proven, absmax 0).
// Fallback: round-3 proven f16 path if ws too small.
// ---------------------------------------------------------------------------

typedef int i32x4 __attribute__((ext_vector_type(4)));
typedef _Float16 f16x8 __attribute__((ext_vector_type(8)));
typedef _Float16 f16x4 __attribute__((ext_vector_type(4)));
typedef float f32x4 __attribute__((ext_vector_type(4)));

#define GLDS(g, l) __builtin_amdgcn_global_load_lds( \
    (const __attribute__((address_space(1))) void*)(g), \
    (__attribute__((address_space(3))) void*)(l), 16, 0, 0)

#define INV231 4.656612873077392578125e-10   // 2^-31

// ======================= prep =======================

// w (M,K) f32 -> wp [K/64][4][M][64] i8 digit planes; 16-B chunk c of row m
// stored at c ^ ((m>>1)&3)  (round-6/8-proven conflict-free for ds_read_b128).
__global__ __launch_bounds__(256) void prep_w8(const float* __restrict__ A,
                                               signed char* __restrict__ wp,
                                               int M, int K)
{
    long gt = (long)blockIdx.x * 256 + threadIdx.x;
    int kq4 = K >> 2;
    int m = (int)(gt / kq4), kq = (int)(gt % kq4);
    int k0 = kq * 4;
    int kt = k0 >> 6, kin = k0 & 63;
    int cw = ((kin >> 4) ^ (m >> 1)) & 3;
    float4 w = *(const float4*)&A[(long)m * K + k0];
    float wv[4] = {w.x, w.y, w.z, w.w};
    int pack[4] = {0, 0, 0, 0};
#pragma unroll
    for (int e = 0; e < 4; e++) {
        long k64 = (long)rint((double)wv[e] * 2147483648.0);  // * 2^31
#pragma unroll
        for (int j = 0; j < 3; j++) {
            long r = ((k64 + 128) & 255) - 128;   // balanced digit [-128,127]
            pack[j] |= ((int)r & 255) << (e * 8);
            k64 = (k64 - r) >> 8;
        }
        pack[3] |= ((int)k64 & 255) << (e * 8);
    }
#pragma unroll
    for (int p = 0; p < 4; p++)
        *(int*)&wp[(((long)kt * 4 + p) * M + m) * 64 + cw * 16 + (kin & 15)] = pack[p];
}

// x [b][512][1024] f32 -> x8t [b][8][1024][64] i8 (k-tile-major, plain layout
// for direct coalesced frag loads; no swizzle).
__global__ __launch_bounds__(256) void prep_x8(const float* __restrict__ x,
                                               unsigned char* __restrict__ xt)
{
    __shared__ float xs[64][68];
    const int b = blockIdx.z, i0 = blockIdx.y * 64, t0 = blockIdx.x * 64;
    const float* xb = x + ((long)b * 512 + i0) * 1024 + t0;
#pragma unroll
    for (int p = 0; p < 4; p++) {
        int f = threadIdx.x + p * 256;
        int i = f >> 4, t4 = (f & 15) * 4;
        *(float4*)&xs[i][t4] = *(const float4*)&xb[(long)i * 1024 + t4];
    }
    __syncthreads();
    int tt = threadIdx.x >> 2, c = threadIdx.x & 3;
    unsigned char bytes[16];
#pragma unroll
    for (int j = 0; j < 16; j++)
        bytes[j] = (unsigned char)xs[c * 16 + j][tt];
    *(uint4*)&xt[(((long)b * 8 + (i0 >> 6)) * 1024 + t0 + tt) * 64 + c * 16] =
        *(uint4*)bytes;
}

// ======================= fused layer-1 GEMM + LIF =======================
// Block = (16 m, b) x ALL 1024 t. 192 threads: waves 0-1 GEMM (64t x 16m
// each), wave 2 = LIF scanner (lanes 0-15, one chain per m).
// LDS: Ws[8][4][16][64] = 32 KB (whole K=512 slab, staged once) +
//      cs[2][128][17] f32 = 17.4 KB (double-buffered current staging).
// 8 t-passes of 128: pass p GEMM -> cs[p&1]; LIF scans cs[(p-1)&1]
// concurrently; one barrier per pass. LIF uses register-preloaded groups.
// Output: 1024-bit spike masks only.
__global__ __launch_bounds__(192, 2) void gemm_lif1(
    const signed char* __restrict__ wp,     // [8][4][2048][64] swizzled
    const unsigned char* __restrict__ act,  // [b][8][1024][64] plain
    const float* __restrict__ bias,         // (2048)
    unsigned* __restrict__ mask_ws)         // [b][32][2048]
{
    __shared__ signed char Ws[8][4][16][64];   // 32 KB
    __shared__ float cs[2][128][17];           // 17.4 KB

    const int m0 = blockIdx.x * 16, b = blockIdx.y;
    const int tid = threadIdx.x, lane = tid & 63, wave = tid >> 6;
    const int lm = lane & 15, lq = lane >> 4;
    const int fro = ((lq ^ (lm >> 1)) & 3) * 16;   // swizzled LDS read offset
    const unsigned char* ab = act + (long)b * 8 * 1024 * 64;

    i32x4 areg[2][4];
    double bv0 = 0.0;

    if (wave < 2) {
        // stage the whole weight slab: 32 slabs of [16][64]=1KB, 16 GLDS/wave
        const int gl_row = lane >> 2, gl_col = (lane & 3) * 16;
#pragma unroll
        for (int j = 0; j < 16; ++j) {
            const int r = wave + 2 * j;          // slab id 0..31
            const int kt = r >> 2, p = r & 3;
            const signed char* g = wp + ((long)r * 2048 + m0 + gl_row) * 64 + gl_col;
            GLDS(g, &Ws[kt][p][0][0]);
        }
        bv0 = (double)bias[m0 + lm];
        // acts (pass 0, kt 0) into parity slot 0
#pragma unroll
        for (int f = 0; f < 4; f++)
            areg[0][f] = *(const i32x4*)
                &ab[((long)(wave * 64 + f * 16 + lm)) * 64 + lq * 16];
    }
    __syncthreads();

    // LIF state (wave 2, lanes < 16: chain for col m0+lane)
    double u = 0.0;
    bool sprev = false;

    for (int p = 0; p < 9; ++p) {
        if (wave < 2 && p < 8) {
            i32x4 acc[4][4];   // [plane][t-frag]
#pragma unroll
            for (int pp = 0; pp < 4; pp++)
#pragma unroll
                for (int f = 0; f < 4; f++) acc[pp][f] = (i32x4)0;

#pragma unroll
            for (int kk = 0; kk < 8; ++kk) {
                // prefetch next virtual iter (pn, kn) -> other parity slot
                {
                    int pn = p, kn = kk + 1;
                    if (kn == 8) { kn = 0; pn = p + 1; if (pn > 7) { pn = 7; kn = 7; } }
                    const long tt = (long)pn * 128 + wave * 64 + lm;
#pragma unroll
                    for (int f = 0; f < 4; f++)
                        areg[(kk + 1) & 1][f] = *(const i32x4*)
                            &ab[((long)kn * 1024 + tt + f * 16) * 64 + lq * 16];
                }
#pragma unroll
                for (int pp = 0; pp < 4; pp++) {
                    i32x4 w0 = *(const i32x4*)&Ws[kk][pp][lm][fro];
#pragma unroll
                    for (int f = 0; f < 4; f++)
                        acc[pp][f] = __builtin_amdgcn_mfma_i32_16x16x64_i8(
                            areg[kk & 1][f], w0, acc[pp][f], 0, 0, 0);
                }
            }
            // Horner -> exact f32 current -> cs[p&1]
            const int tb = wave * 64;
#pragma unroll
            for (int tf = 0; tf < 4; tf++)
#pragma unroll
                for (int r = 0; r < 4; r++) {
                    long T = acc[3][tf][r];
                    T = T * 256 + acc[2][tf][r];
                    T = T * 256 + acc[1][tf][r];
                    T = T * 256 + acc[0][tf][r];
                    cs[p & 1][tb + tf * 16 + lq * 4 + r][lm] =
                        (float)((double)T * INV231 + bv0);
                }
        }
        if (wave == 2 && p >= 1 && lane < 16) {
            const int pq = p - 1, buf = pq & 1;
            // register-preloaded, software-pipelined scan:
            // load group g+1 while chaining group g (all static indices)
            float cvA[32], cvB[32];
#pragma unroll
            for (int j = 0; j < 32; ++j) cvA[j] = cs[buf][j][lane];
#pragma unroll
            for (int j = 0; j < 32; ++j) cvB[j] = cs[buf][32 + j][lane];
            {   // g = 0 (chain cvA)
                unsigned mword = 0;
#pragma unroll
                for (int j = 0; j < 32; ++j) {
                    double c = (double)cvA[j];
                    double a = 0.95 * u + c;
                    u = sprev ? c : a;
                    bool s = (u >= 1.0);
                    mword |= (s ? 1u : 0u) << j;
                    sprev = s;
                }
                mask_ws[((long)b * 32 + pq * 4 + 0) * 2048 + m0 + lane] = mword;
            }
#pragma unroll
            for (int j = 0; j < 32; ++j) cvA[j] = cs[buf][64 + j][lane];
            {   // g = 1 (chain cvB)
                unsigned mword = 0;
#pragma unroll
                for (int j = 0; j < 32; ++j) {
                    double c = (double)cvB[j];
                    double a = 0.95 * u + c;
                    u = sprev ? c : a;
                    bool s = (u >= 1.0);
                    mword |= (s ? 1u : 0u) << j;
                    sprev = s;
                }
                mask_ws[((long)b * 32 + pq * 4 + 1) * 2048 + m0 + lane] = mword;
            }
#pragma unroll
            for (int j = 0; j < 32; ++j) cvB[j] = cs[buf][96 + j][lane];
            {   // g = 2 (chain cvA)
                unsigned mword = 0;
#pragma unroll
                for (int j = 0; j < 32; ++j) {
                    double c = (double)cvA[j];
                    double a = 0.95 * u + c;
                    u = sprev ? c : a;
                    bool s = (u >= 1.0);
                    mword |= (s ? 1u : 0u) << j;
                    sprev = s;
                }
                mask_ws[((long)b * 32 + pq * 4 + 2) * 2048 + m0 + lane] = mword;
            }
            {   // g = 3 (chain cvB)
                unsigned mword = 0;
#pragma unroll
                for (int j = 0; j < 32; ++j) {
                    double c = (double)cvB[j];
                    double a = 0.95 * u + c;
                    u = sprev ? c : a;
                    bool s = (u >= 1.0);
                    mword |= (s ? 1u : 0u) << j;
                    sprev = s;
                }
                mask_ws[((long)b * 32 + pq * 4 + 3) * 2048 + m0 + lane] = mword;
            }
        }
        __syncthreads();
    }
}

// ======================= mask expanders =======================

// masks [b][32][2048] -> i8 spikes spk8 [b][32 kt][1024 t][64 m]
__global__ __launch_bounds__(256) void expand_spk8(
    const unsigned* __restrict__ mask_ws,
    unsigned char* __restrict__ spk8)
{
    __shared__ unsigned msk[64][33];
    const int b = blockIdx.x, kt = blockIdx.y;
    const int tid = threadIdx.x;
#pragma unroll
    for (int i = 0; i < 8; ++i) {
        int idx = tid + i * 256;            // 0..2047
        int tw = idx >> 6, m = idx & 63;
        msk[m][tw] = mask_ws[((long)b * 32 + tw) * 2048 + kt * 64 + m];
    }
    __syncthreads();
    unsigned char* dst = spk8 + ((long)b * 32 + kt) * 1024 * 64;
#pragma unroll
    for (int i = 0; i < 16; ++i) {
        int off = tid + i * 256;            // 16-B chunk index 0..4095
        int t = off >> 2, mq = off & 3;
        int tw = t >> 5, sh = t & 31;
        unsigned w0 = 0, w1 = 0, w2 = 0, w3 = 0;
#pragma unroll
        for (int j = 0; j < 4; ++j) {
            w0 |= ((msk[mq * 16 + j][tw] >> sh) & 1u) << (8 * j);
            w1 |= ((msk[mq * 16 + 4 + j][tw] >> sh) & 1u) << (8 * j);
            w2 |= ((msk[mq * 16 + 8 + j][tw] >> sh) & 1u) << (8 * j);
            w3 |= ((msk[mq * 16 + 12 + j][tw] >> sh) & 1u) << (8 * j);
        }
        *(uint4*)&dst[(long)off * 16] = (uint4){w0, w1, w2, w3};
    }
}

// masks [b][32][2048] -> f32 spikes [b][2048][1024]
__global__ __launch_bounds__(256) void expand_spk(
    const unsigned* __restrict__ mask_ws,
    float* __restrict__ spk1)
{
    __shared__ unsigned msk[8][32];
    const long rowbase = (long)blockIdx.x * 8;
    const int b = (int)(rowbase >> 11), m0 = (int)(rowbase & 2047);
    const int tid = threadIdx.x;
    {
        int w = tid >> 3, r = tid & 7;
        msk[r][w] = mask_ws[((long)b * 32 + w) * 2048 + m0 + r];
    }
    __syncthreads();
    const int r = tid >> 5, l5 = tid & 31;
    float* dst = spk1 + (rowbase + r) * 1024;
    const int sh = (l5 & 7) * 4;
#pragma unroll
    for (int j = 0; j < 8; j++) {
        const int t = l5 * 4 + j * 128;
        const unsigned w = msk[r][(l5 >> 3) + j * 4];
        float4 o;
        o.x = ((w >> sh) & 1u) ? 1.f : 0.f;
        o.y = ((w >> (sh + 1)) & 1u) ? 1.f : 0.f;
        o.z = ((w >> (sh + 2)) & 1u) ? 1.f : 0.f;
        o.w = ((w >> (sh + 3)) & 1u) ? 1.f : 0.f;
        *(float4*)&dst[t] = o;
    }
}

// ======================= layer-2 GEMM (round-11 proven) =======================
// !TRANS: D[M][t] (weights A, acts B) -> cur2 directly.
// CHUNK k-tiles staged per phase; inner loop barrier-free.
template <bool TRANS, int NITER, int CHUNK>
__global__ __launch_bounds__(256, 2) void gemm_i8(
    const signed char* __restrict__ wp,     // [K/64][4][M][64] swizzled
    const unsigned char* __restrict__ act,  // [b][K/64][1024][64] plain
    const float* __restrict__ bias,         // (M)
    float* __restrict__ C,
    int M)
{
    constexpr int NCHUNK = NITER / CHUNK;
    __shared__ signed char Ws[CHUNK][4][32][64];   // CHUNK * 8 KB

    const int b = blockIdx.y;
    const int m0 = blockIdx.z * 32, t0 = blockIdx.x * 256;
    const int tid = threadIdx.x, lane = tid & 63, wave = tid >> 6;
    const int wt = t0 + wave * 64;            // wave's global t base
    const int lm = lane & 15, lq = lane >> 4;
    const int fro = ((lq ^ (lm >> 1)) & 3) * 16;   // swizzled LDS read offset
    const int gl_row = lane >> 2, gl_col = (lane & 3) * 16;

    const unsigned char* ab = act + (long)b * NITER * 1024 * 64;

    auto stage = [&](int cc) {
#pragma unroll
        for (int j = 0; j < CHUNK; ++j) {
            const int r = wave + 4 * j;          // slab id
            const int kt = r >> 2, p = r & 3;
            const long kg = ((long)(cc * CHUNK + kt) * 4 + p);
            const signed char* g = wp + (kg * M + m0 + gl_row) * 64 + gl_col;
            GLDS(g, &Ws[kt][p][0][0]);
            GLDS(g + 16 * 64, &Ws[kt][p][16][0]);
        }
    };

    i32x4 acc[4][8];
#pragma unroll
    for (int p = 0; p < 4; p++)
#pragma unroll
        for (int q = 0; q < 8; q++) acc[p][q] = (i32x4)0;

    stage(0);
    i32x4 areg[2][4];
#pragma unroll
    for (int f = 0; f < 4; f++)
        areg[0][f] = *(const i32x4*)&ab[((long)(wt + f * 16 + lm)) * 64 + lq * 16];
    __syncthreads();

    for (int c = 0; c < NCHUNK; ++c) {
#pragma unroll
        for (int kk = 0; kk < CHUNK; ++kk) {
            {
                const int itv = c * CHUNK + kk;
                const long nx = (itv + 1 < NITER) ? itv + 1 : itv;
#pragma unroll
                for (int f = 0; f < 4; f++)
                    areg[(kk + 1) & 1][f] = *(const i32x4*)
                        &ab[(nx * 1024 + wt + f * 16 + lm) * 64 + lq * 16];
            }
#pragma unroll
            for (int p = 0; p < 4; p++) {
                i32x4 w0 = *(const i32x4*)&Ws[kk][p][lm][fro];
                i32x4 w1 = *(const i32x4*)&Ws[kk][p][16 + lm][fro];
                if (TRANS) {
#pragma unroll
                    for (int f = 0; f < 4; f++) {
                        acc[p][f * 2 + 0] = __builtin_amdgcn_mfma_i32_16x16x64_i8(
                            areg[kk & 1][f], w0, acc[p][f * 2 + 0], 0, 0, 0);
                        acc[p][f * 2 + 1] = __builtin_amdgcn_mfma_i32_16x16x64_i8(
                            areg[kk & 1][f], w1, acc[p][f * 2 + 1], 0, 0, 0);
                    }
                } else {
#pragma unroll
                    for (int f = 0; f < 4; f++) {
                        acc[p][0 + f] = __builtin_amdgcn_mfma_i32_16x16x64_i8(
                            w0, areg[kk & 1][f], acc[p][0 + f], 0, 0, 0);
                        acc[p][4 + f] = __builtin_amdgcn_mfma_i32_16x16x64_i8(
                            w1, areg[kk & 1][f], acc[p][4 + f], 0, 0, 0);
                    }
                }
            }
        }
        if (c + 1 < NCHUNK) {
            __syncthreads();
            stage(c + 1);
            __syncthreads();
        }
    }

    if (TRANS) {
        double bv[2];
        bv[0] = (double)bias[m0 + lm];
        bv[1] = (double)bias[m0 + 16 + lm];
        float* Cb = C + (long)b * 1024 * M;
#pragma unroll
        for (int tf = 0; tf < 4; tf++)
#pragma unroll
            for (int r = 0; r < 4; r++) {
                const int trow = wt + tf * 16 + lq * 4 + r;
#pragma unroll
                for (int mf = 0; mf < 2; mf++) {
                    long T = acc[3][tf * 2 + mf][r];
                    T = T * 256 + acc[2][tf * 2 + mf][r];
                    T = T * 256 + acc[1][tf * 2 + mf][r];
                    T = T * 256 + acc[0][tf * 2 + mf][r];
                    Cb[(long)trow * M + m0 + mf * 16 + lm] =
                        (float)((double)T * INV231 + bv[mf]);
                }
            }
    } else {
        float* Cb = C + (long)b * M * 1024;
#pragma unroll
        for (int mf = 0; mf < 2; mf++)
#pragma unroll
            for (int r = 0; r < 4; r++) {
                const int mrow = m0 + mf * 16 + lq * 4 + r;
                const double bv = (double)bias[mrow];
#pragma unroll
                for (int tf = 0; tf < 4; tf++) {
                    long T = acc[3][mf * 4 + tf][r];
                    T = T * 256 + acc[2][mf * 4 + tf][r];
                    T = T * 256 + acc[1][mf * 4 + tf][r];
                    T = T * 256 + acc[0][mf * 4 + tf][r];
                    Cb[(long)mrow * 1024 + wt + tf * 16 + lm] =
                        (float)((double)T * INV231 + bv);
                }
            }
    }
}

// LDS-chunked LIF for layer 2 (round 4 + register preload); RPB=32 -> 256
// blocks (1/CU)
template <int RPB>
__global__ __launch_bounds__(256) void lif_lds(float* __restrict__ cur)
{
    __shared__ float cs[RPB][36];
    const long rowbase = (long)blockIdx.x * RPB;
    float* base = cur + rowbase * 1024;
    const int tid = threadIdx.x;
    double v = 0.0;
    const int NV = RPB * 32 / 4;
    for (int tc = 0; tc < 1024; tc += 32) {
        for (int f = tid; f < NV; f += 256) {
            int row = f >> 3, t4 = (f & 7) * 4;
            *(float4*)&cs[row][t4] = *(const float4*)&base[(long)row * 1024 + tc + t4];
        }
        __syncthreads();
        if (tid < RPB) {
            float cv[32];
#pragma unroll
            for (int j = 0; j < 32; j++) cv[j] = cs[tid][j];
#pragma unroll
            for (int j = 0; j < 32; j++) {
                v = 0.95 * v + (double)cv[j];
                bool s = v >= 1.0;
                cs[tid][j] = s ? 1.f : 0.f;
                if (s) v = 0.0;
            }
        }
        __syncthreads();
        for (int f = tid; f < NV; f += 256) {
            int row = f >> 3, t4 = (f & 7) * 4;
            *(float4*)&base[(long)row * 1024 + tc + t4] = *(float4*)&cs[row][t4];
        }
        __syncthreads();
    }
}

// ======================= fallback (round 3, proven) =======================

__device__ inline void split3(float w, _Float16& q0, _Float16& q1, _Float16& q2) {
    float p0 = rintf(w * 4096.f) * 2.44140625e-4f;
    float r1 = w - p0;
    float p1s = rintf(r1 * 8388608.f) * 2.44140625e-4f;
    float r2 = r1 - p1s * 4.8828125e-4f;
    float p2s = rintf(r2 * 1.7179869184e10f) * 1.220703125e-4f;
    q0 = (_Float16)p0; q1 = (_Float16)p1s; q2 = (_Float16)p2s;
}

__global__ __launch_bounds__(256) void gemm_f16x3_kernel(
    const float* __restrict__ A, const float* __restrict__ Bmat,
    const float* __restrict__ bias, float* __restrict__ C,
    int M, int N, int K, long sB, long sC)
{
    __shared__ _Float16 As[3][128][40];
    __shared__ _Float16 Bsh[128][40];
    const int batch = blockIdx.z;
    const float* Bp = Bmat + (long)batch * sB;
    float* Cp = C + (long)batch * sC;
    const int m0 = blockIdx.y * 128, n0 = blockIdx.x * 128;
    const int tid = threadIdx.x, lane = tid & 63, wave = tid >> 6;
    const int wrow = (wave >> 1) * 64, wcol = (wave & 1) * 64;
    const int lm = lane & 15, lq = lane >> 4;
    const int a_mo = tid >> 3, a_kc = (tid & 7) * 4;
    const int b_kq = tid >> 5, b_nq = tid & 31;

    f32x4 acc[3][4][4];
#pragma unroll
    for (int p = 0; p < 3; p++)
#pragma unroll
        for (int i = 0; i < 4; i++)
#pragma unroll
            for (int j = 0; j < 4; j++) acc[p][i][j] = (f32x4)0.f;

    for (int k0 = 0; k0 < K; k0 += 32) {
#pragma unroll
        for (int i = 0; i < 4; i++) {
            const int m = i * 32 + a_mo;
            float4 w = *(const float4*)&A[(long)(m0 + m) * K + k0 + a_kc];
            _Float16 a0[4], a1[4], a2[4];
            split3(w.x, a0[0], a1[0], a2[0]);
            split3(w.y, a0[1], a1[1], a2[1]);
            split3(w.z, a0[2], a1[2], a2[2]);
            split3(w.w, a0[3], a1[3], a2[3]);
            *(f16x4*)&As[0][m][a_kc] = (f16x4){a0[0], a0[1], a0[2], a0[3]};
            *(f16x4*)&As[1][m][a_kc] = (f16x4){a1[0], a1[1], a1[2], a1[3]};
            *(f16x4*)&As[2][m][a_kc] = (f16x4){a2[0], a2[1], a2[2], a2[3]};
        }
        {
            float4 r0 = *(const float4*)&Bp[(long)(k0 + b_kq * 4 + 0) * N + n0 + b_nq * 4];
            float4 r1 = *(const float4*)&Bp[(long)(k0 + b_kq * 4 + 1) * N + n0 + b_nq * 4];
            float4 r2 = *(const float4*)&Bp[(long)(k0 + b_kq * 4 + 2) * N + n0 + b_nq * 4];
            float4 r3 = *(const float4*)&Bp[(long)(k0 + b_kq * 4 + 3) * N + n0 + b_nq * 4];
            *(f16x4*)&Bsh[b_nq * 4 + 0][b_kq * 4] =
                (f16x4){(_Float16)r0.x, (_Float16)r1.x, (_Float16)r2.x, (_Float16)r3.x};
            *(f16x4*)&Bsh[b_nq * 4 + 1][b_kq * 4] =
                (f16x4){(_Float16)r0.y, (_Float16)r1.y, (_Float16)r2.y, (_Float16)r3.y};
            *(f16x4*)&Bsh[b_nq * 4 + 2][b_kq * 4] =
                (f16x4){(_Float16)r0.z, (_Float16)r1.z, (_Float16)r2.z, (_Float16)r3.z};
            *(f16x4*)&Bsh[b_nq * 4 + 3][b_kq * 4] =
                (f16x4){(_Float16)r0.w, (_Float16)r1.w, (_Float16)r2.w, (_Float16)r3.w};
        }
        __syncthreads();
        f16x8 bf[4];
#pragma unroll
        for (int j = 0; j < 4; j++)
            bf[j] = *(const f16x8*)&Bsh[wcol + j * 16 + lm][lq * 8];
#pragma unroll
        for (int p = 0; p < 3; p++) {
            f16x8 af[4];
#pragma unroll
            for (int i = 0; i < 4; i++)
                af[i] = *(const f16x8*)&As[p][wrow + i * 16 + lm][lq * 8];
#pragma unroll
            for (int i = 0; i < 4; i++)
#pragma unroll
                for (int j = 0; j < 4; j++)
                    acc[p][i][j] = __builtin_amdgcn_mfma_f32_16x16x32_f16(
                        af[i], bf[j], acc[p][i][j], 0, 0, 0);
        }
        __syncthreads();
    }
#pragma unroll
    for (int i = 0; i < 4; i++)
#pragma unroll
        for (int r = 0; r < 4; r++) {
            const int row = m0 + wrow + i * 16 + lq * 4 + r;
            const double bv = (double)bias[row];
#pragma unroll
            for (int j = 0; j < 4; j++) {
                double s = (double)acc[0][i][j][r]
                         + (double)acc[1][i][j][r] * 4.8828125e-4
                         + (double)acc[2][i][j][r] * 4.76837158203125e-7 + bv;
                Cp[(long)row * N + n0 + wcol + j * 16 + lm] = (float)s;
            }
        }
}

__global__ __launch_bounds__(256) void lif_rows(float* __restrict__ data,
                                                long nrows, int T)
{
    long r = (long)blockIdx.x * blockDim.x + threadIdx.x;
    if (r >= nrows) return;
    float* p = data + r * (long)T;
    double v = 0.0;
    for (int t = 0; t < T; t += 4) {
        float4 c = *(float4*)(p + t);
        float4 s;
        v = 0.95 * v + (double)c.x; s.x = (v >= 1.0) ? 1.f : 0.f; if (v >= 1.0) v = 0.0;
        v = 0.95 * v + (double)c.y; s.y = (v >= 1.0) ? 1.f : 0.f; if (v >= 1.0) v = 0.0;
        v = 0.95 * v + (double)c.z; s.z = (v >= 1.0) ? 1.f : 0.f; if (v >= 1.0) v = 0.0;
        v = 0.95 * v + (double)c.w; s.w = (v >= 1.0) ? 1.f : 0.f; if (v >= 1.0) v = 0.0;
        *(float4*)(p + t) = s;
    }
}

// ======================= launch =======================

extern "C" void kernel_launch(void* const* d_in, const int* in_sizes, int n_in,
                              void* d_out, int out_size, void* d_ws, size_t ws_size,
                              hipStream_t stream)
{
    const float* x  = (const float*)d_in[0];  // (32, 512, 1024)
    const float* w1 = (const float*)d_in[1];  // (2048, 512)
    const float* b1 = (const float*)d_in[2];  // (2048)
    const float* w2 = (const float*)d_in[3];  // (256, 2048)
    const float* b2 = (const float*)d_in[4];  // (256)

    float* out  = (float*)d_out;
    float* spk1 = out;                              // (32, 2048, 1024)
    float* spk2 = out + (long)32 * 2048 * 1024;     // (32, 256, 1024)

    const size_t WP1 = 4194304;        // [8][4][2048][64] i8
    const size_t WP2 = 2097152;        // [32][4][256][64] i8
    const size_t X8T = 16777216;       // [32][8][1024][64] i8
    const size_t SPK = 67108864;       // [32][32][1024][64] i8
    const size_t MSK = 8388608;        // [32][32][2048] u32
    const size_t NEED = WP1 + WP2 + X8T + SPK + MSK;

    if (ws_size >= NEED) {
        char* ws = (char*)d_ws;
        signed char* wp1 = (signed char*)ws;
        signed char* wp2 = (signed char*)(ws + WP1);
        unsigned char* x8t = (unsigned char*)(ws + WP1 + WP2);
        unsigned char* spk8 = (unsigned char*)(ws + WP1 + WP2 + X8T);
        unsigned* mask_ws = (unsigned*)(ws + WP1 + WP2 + X8T + SPK);

        prep_w8<<<1024, 256, 0, stream>>>(w1, wp1, 2048, 512);
        prep_w8<<<512, 256, 0, stream>>>(w2, wp2, 256, 2048);
        prep_x8<<<dim3(16, 8, 32), 256, 0, stream>>>(x, x8t);

        // layer 1: fused GEMM+LIF -> masks only; 16-m blocks, 3/CU
        gemm_lif1<<<dim3(128, 32), 192, 0, stream>>>(wp1, x8t, b1, mask_ws);
        expand_spk8<<<dim3(32, 32), 256, 0, stream>>>(mask_ws, spk8);

        // layer 2: cur2 [b][256][1024] direct -> in-place LIF
        gemm_i8<false, 32, 8><<<dim3(4, 32, 8), 256, 0, stream>>>(
            wp2, spk8, b2, spk2, 256);
        lif_lds<32><<<256, 256, 0, stream>>>(spk2);

        // f32 spike expansion for layer-1 output
        expand_spk<<<8192, 256, 0, stream>>>(mask_ws, spk1);
    } else {
        gemm_f16x3_kernel<<<dim3(8, 16, 32), 256, 0, stream>>>(
            w1, x, b1, spk1, 2048, 1024, 512, (long)512 * 1024, (long)2048 * 1024);
        lif_rows<<<(65536 + 255) / 256, 256, 0, stream>>>(spk1, 65536, 1024);
        gemm_f16x3_kernel<<<dim3(8, 2, 32), 256, 0, stream>>>(
            w2, spk1, b2, spk2, 256, 1024, 2048, (long)2048 * 1024, (long)256 * 1024);
        lif_rows<<<(8192 + 255) / 256, 256, 0, stream>>>(spk2, 8192, 1024);
    }
}

// Round 6
// 638.390 us; speedup vs baseline: 1.1645x; 1.0136x over previous
//
#include <hip/hip_runtime.h>

// ---------------------------------------------------------------------------
// LavaNetwork, bit-exact 4-plane i8 MFMA GEMM (mfma_i32_16x16x64_i8).
//   w ~ k*2^-31 (k = rint(w*2^31), residual <= 2^-32), 4 balanced base-256
//   digits -> exact i8 planes, exact i32 sums, exact i64 Horner + f64 bias.
// Round-15 structure:
//   - gemm_lif1 rebuilt for 64-LANE LIF (round-5 PMC: VALUBusy ~= LIF issue
//     with only 16/64 lanes active; issue cost is per-instruction, so lane
//     count is the lever). Block = (64 m, b) x all 1024 t, 320 threads:
//     waves 0-3 GEMM (64t x 16m each per pass), wave 4 = LIF with all 64
//     lanes (one chain per m). LDS = Ws[8][4][64][64] (128 KB, whole K=512
//     resident -> barrier-free k-loop) + cs[2][64][64] (32 KB, dbuf)
//     = exactly 160 KB -> 1 block/CU, 4 sequential blocks/CU.
//     16 t-passes of 64; one barrier per pass; GEMM pass p || LIF pass p-1.
//   - Emits 1024-bit masks only (8 MB); expanders / layer 2 unchanged.
//   - LIF recurrence identical arithmetic: u = 0.95*u + c; on spike u = c
//     next step (== 0.95*0 + c exactly), f64 state, f32 inputs.
// Fallback: round-3 proven f16 path if ws too small.
// ---------------------------------------------------------------------------

typedef int i32x4 __attribute__((ext_vector_type(4)));
typedef _Float16 f16x8 __attribute__((ext_vector_type(8)));
typedef _Float16 f16x4 __attribute__((ext_vector_type(4)));
typedef float f32x4 __attribute__((ext_vector_type(4)));

#define GLDS(g, l) __builtin_amdgcn_global_load_lds( \
    (const __attribute__((address_space(1))) void*)(g), \
    (__attribute__((address_space(3))) void*)(l), 16, 0, 0)

#define INV231 4.656612873077392578125e-10   // 2^-31

// ======================= prep =======================

// w (M,K) f32 -> wp [K/64][4][M][64] i8 digit planes; 16-B chunk c of row m
// stored at c ^ ((m>>1)&3)  (round-6/8-proven conflict-free for ds_read_b128).
__global__ __launch_bounds__(256) void prep_w8(const float* __restrict__ A,
                                               signed char* __restrict__ wp,
                                               int M, int K)
{
    long gt = (long)blockIdx.x * 256 + threadIdx.x;
    int kq4 = K >> 2;
    int m = (int)(gt / kq4), kq = (int)(gt % kq4);
    int k0 = kq * 4;
    int kt = k0 >> 6, kin = k0 & 63;
    int cw = ((kin >> 4) ^ (m >> 1)) & 3;
    float4 w = *(const float4*)&A[(long)m * K + k0];
    float wv[4] = {w.x, w.y, w.z, w.w};
    int pack[4] = {0, 0, 0, 0};
#pragma unroll
    for (int e = 0; e < 4; e++) {
        long k64 = (long)rint((double)wv[e] * 2147483648.0);  // * 2^31
#pragma unroll
        for (int j = 0; j < 3; j++) {
            long r = ((k64 + 128) & 255) - 128;   // balanced digit [-128,127]
            pack[j] |= ((int)r & 255) << (e * 8);
            k64 = (k64 - r) >> 8;
        }
        pack[3] |= ((int)k64 & 255) << (e * 8);
    }
#pragma unroll
    for (int p = 0; p < 4; p++)
        *(int*)&wp[(((long)kt * 4 + p) * M + m) * 64 + cw * 16 + (kin & 15)] = pack[p];
}

// x [b][512][1024] f32 -> x8t [b][8][1024][64] i8 (k-tile-major, plain layout
// for direct coalesced frag loads; no swizzle).
__global__ __launch_bounds__(256) void prep_x8(const float* __restrict__ x,
                                               unsigned char* __restrict__ xt)
{
    __shared__ float xs[64][68];
    const int b = blockIdx.z, i0 = blockIdx.y * 64, t0 = blockIdx.x * 64;
    const float* xb = x + ((long)b * 512 + i0) * 1024 + t0;
#pragma unroll
    for (int p = 0; p < 4; p++) {
        int f = threadIdx.x + p * 256;
        int i = f >> 4, t4 = (f & 15) * 4;
        *(float4*)&xs[i][t4] = *(const float4*)&xb[(long)i * 1024 + t4];
    }
    __syncthreads();
    int tt = threadIdx.x >> 2, c = threadIdx.x & 3;
    unsigned char bytes[16];
#pragma unroll
    for (int j = 0; j < 16; j++)
        bytes[j] = (unsigned char)xs[c * 16 + j][tt];
    *(uint4*)&xt[(((long)b * 8 + (i0 >> 6)) * 1024 + t0 + tt) * 64 + c * 16] =
        *(uint4*)bytes;
}

// ======================= fused layer-1 GEMM + LIF =======================
// Block = (64 m, b) x ALL 1024 t. 320 threads: waves 0-3 GEMM (64t x 16m
// each per pass; wave w owns m-slice w*16..w*16+15), wave 4 = LIF with all
// 64 lanes (chain for col m0+lane).
// LDS: Ws[8][4][64][64] = 128 KB (whole K=512 slab, staged once) +
//      cs[2][64][64] f32 = 32 KB (double-buffered currents) = 160 KB exact.
// 16 t-passes of 64: pass p GEMM -> cs[p&1]; LIF scans cs[(p-1)&1]
// concurrently; one barrier per pass; k-loop itself barrier-free.
// Output: 1024-bit spike masks only.
__global__ __launch_bounds__(320, 1) void gemm_lif1(
    const signed char* __restrict__ wp,     // [8][4][2048][64] swizzled
    const unsigned char* __restrict__ act,  // [b][8][1024][64] plain
    const float* __restrict__ bias,         // (2048)
    unsigned* __restrict__ mask_ws)         // [b][32][2048]
{
    __shared__ signed char Ws[8][4][64][64];   // 128 KB
    __shared__ float cs[2][64][64];            // 32 KB

    const int m0 = blockIdx.x * 64, b = blockIdx.y;
    const int tid = threadIdx.x, lane = tid & 63, wave = tid >> 6;
    const int lm = lane & 15, lq = lane >> 4;
    const int fro = ((lq ^ (lm >> 1)) & 3) * 16;   // swizzled LDS read offset
    const unsigned char* ab = act + (long)b * 8 * 1024 * 64;

    i32x4 areg[2][4];
    double bv = 0.0;

    if (wave < 4) {
        // stage the whole weight slab: 32 slabs of [64][64]=4KB,
        // 8 slabs/wave x 4 GLDS each
        const int gl_row = lane >> 2, gl_col = (lane & 3) * 16;
#pragma unroll
        for (int j = 0; j < 8; ++j) {
            const int r = wave + 4 * j;          // slab id 0..31
            const int kt = r >> 2, pl = r & 3;
            const signed char* g = wp + ((long)r * 2048 + m0 + gl_row) * 64 + gl_col;
#pragma unroll
            for (int q = 0; q < 4; ++q)
                GLDS(g + q * 16 * 64, &Ws[kt][pl][q * 16][0]);
        }
        bv = (double)bias[m0 + wave * 16 + lm];
        // acts (pass 0, kt 0) into parity slot 0
#pragma unroll
        for (int f = 0; f < 4; f++)
            areg[0][f] = *(const i32x4*)
                &ab[((long)(f * 16 + lm)) * 64 + lq * 16];
    }
    __syncthreads();

    // LIF state (wave 4, all 64 lanes: chain for col m0+lane)
    double u = 0.0;
    bool sprev = false;

    for (int p = 0; p < 17; ++p) {
        if (wave < 4 && p < 16) {
            i32x4 acc[4][4];   // [plane][t-frag]
#pragma unroll
            for (int pp = 0; pp < 4; pp++)
#pragma unroll
                for (int f = 0; f < 4; f++) acc[pp][f] = (i32x4)0;

#pragma unroll
            for (int kk = 0; kk < 8; ++kk) {
                // prefetch next virtual iter (pn, kn) -> other parity slot
                {
                    int pn = p, kn = kk + 1;
                    if (kn == 8) { kn = 0; pn = p + 1; if (pn > 15) { pn = 15; kn = 7; } }
                    const long tt = (long)pn * 64 + lm;
#pragma unroll
                    for (int f = 0; f < 4; f++)
                        areg[(kk + 1) & 1][f] = *(const i32x4*)
                            &ab[((long)kn * 1024 + tt + f * 16) * 64 + lq * 16];
                }
#pragma unroll
                for (int pl = 0; pl < 4; pl++) {
                    i32x4 w0 = *(const i32x4*)&Ws[kk][pl][wave * 16 + lm][fro];
#pragma unroll
                    for (int f = 0; f < 4; f++)
                        acc[pl][f] = __builtin_amdgcn_mfma_i32_16x16x64_i8(
                            areg[kk & 1][f], w0, acc[pl][f], 0, 0, 0);
                }
            }
            // Horner -> exact f32 current -> cs[p&1]
#pragma unroll
            for (int tf = 0; tf < 4; tf++)
#pragma unroll
                for (int r = 0; r < 4; r++) {
                    long T = acc[3][tf][r];
                    T = T * 256 + acc[2][tf][r];
                    T = T * 256 + acc[1][tf][r];
                    T = T * 256 + acc[0][tf][r];
                    cs[p & 1][tf * 16 + lq * 4 + r][wave * 16 + lm] =
                        (float)((double)T * INV231 + bv);
                }
        }
        if (wave == 4 && p >= 1) {
            const int pq = p - 1, buf = pq & 1;
            // register preload (64 independent ds_reads), then register-only
            // f64 chains; all static indices
            float cvA[32], cvB[32];
#pragma unroll
            for (int j = 0; j < 32; ++j) cvA[j] = cs[buf][j][lane];
#pragma unroll
            for (int j = 0; j < 32; ++j) cvB[j] = cs[buf][32 + j][lane];
            {   // t-word pq*2
                unsigned mword = 0;
#pragma unroll
                for (int j = 0; j < 32; ++j) {
                    double c = (double)cvA[j];
                    double a = 0.95 * u + c;
                    u = sprev ? c : a;
                    bool s = (u >= 1.0);
                    mword |= (s ? 1u : 0u) << j;
                    sprev = s;
                }
                mask_ws[((long)b * 32 + pq * 2 + 0) * 2048 + m0 + lane] = mword;
            }
            {   // t-word pq*2+1
                unsigned mword = 0;
#pragma unroll
                for (int j = 0; j < 32; ++j) {
                    double c = (double)cvB[j];
                    double a = 0.95 * u + c;
                    u = sprev ? c : a;
                    bool s = (u >= 1.0);
                    mword |= (s ? 1u : 0u) << j;
                    sprev = s;
                }
                mask_ws[((long)b * 32 + pq * 2 + 1) * 2048 + m0 + lane] = mword;
            }
        }
        __syncthreads();
    }
}

// ======================= mask expanders =======================

// masks [b][32][2048] -> i8 spikes spk8 [b][32 kt][1024 t][64 m]
__global__ __launch_bounds__(256) void expand_spk8(
    const unsigned* __restrict__ mask_ws,
    unsigned char* __restrict__ spk8)
{
    __shared__ unsigned msk[64][33];
    const int b = blockIdx.x, kt = blockIdx.y;
    const int tid = threadIdx.x;
#pragma unroll
    for (int i = 0; i < 8; ++i) {
        int idx = tid + i * 256;            // 0..2047
        int tw = idx >> 6, m = idx & 63;
        msk[m][tw] = mask_ws[((long)b * 32 + tw) * 2048 + kt * 64 + m];
    }
    __syncthreads();
    unsigned char* dst = spk8 + ((long)b * 32 + kt) * 1024 * 64;
#pragma unroll
    for (int i = 0; i < 16; ++i) {
        int off = tid + i * 256;            // 16-B chunk index 0..4095
        int t = off >> 2, mq = off & 3;
        int tw = t >> 5, sh = t & 31;
        unsigned w0 = 0, w1 = 0, w2 = 0, w3 = 0;
#pragma unroll
        for (int j = 0; j < 4; ++j) {
            w0 |= ((msk[mq * 16 + j][tw] >> sh) & 1u) << (8 * j);
            w1 |= ((msk[mq * 16 + 4 + j][tw] >> sh) & 1u) << (8 * j);
            w2 |= ((msk[mq * 16 + 8 + j][tw] >> sh) & 1u) << (8 * j);
            w3 |= ((msk[mq * 16 + 12 + j][tw] >> sh) & 1u) << (8 * j);
        }
        *(uint4*)&dst[(long)off * 16] = (uint4){w0, w1, w2, w3};
    }
}

// masks [b][32][2048] -> f32 spikes [b][2048][1024]
__global__ __launch_bounds__(256) void expand_spk(
    const unsigned* __restrict__ mask_ws,
    float* __restrict__ spk1)
{
    __shared__ unsigned msk[8][32];
    const long rowbase = (long)blockIdx.x * 8;
    const int b = (int)(rowbase >> 11), m0 = (int)(rowbase & 2047);
    const int tid = threadIdx.x;
    {
        int w = tid >> 3, r = tid & 7;
        msk[r][w] = mask_ws[((long)b * 32 + w) * 2048 + m0 + r];
    }
    __syncthreads();
    const int r = tid >> 5, l5 = tid & 31;
    float* dst = spk1 + (rowbase + r) * 1024;
    const int sh = (l5 & 7) * 4;
#pragma unroll
    for (int j = 0; j < 8; j++) {
        const int t = l5 * 4 + j * 128;
        const unsigned w = msk[r][(l5 >> 3) + j * 4];
        float4 o;
        o.x = ((w >> sh) & 1u) ? 1.f : 0.f;
        o.y = ((w >> (sh + 1)) & 1u) ? 1.f : 0.f;
        o.z = ((w >> (sh + 2)) & 1u) ? 1.f : 0.f;
        o.w = ((w >> (sh + 3)) & 1u) ? 1.f : 0.f;
        *(float4*)&dst[t] = o;
    }
}

// ======================= layer-2 GEMM (round-11 proven) =======================
// !TRANS: D[M][t] (weights A, acts B) -> cur2 directly.
// CHUNK k-tiles staged per phase; inner loop barrier-free.
template <bool TRANS, int NITER, int CHUNK>
__global__ __launch_bounds__(256, 2) void gemm_i8(
    const signed char* __restrict__ wp,     // [K/64][4][M][64] swizzled
    const unsigned char* __restrict__ act,  // [b][K/64][1024][64] plain
    const float* __restrict__ bias,         // (M)
    float* __restrict__ C,
    int M)
{
    constexpr int NCHUNK = NITER / CHUNK;
    __shared__ signed char Ws[CHUNK][4][32][64];   // CHUNK * 8 KB

    const int b = blockIdx.y;
    const int m0 = blockIdx.z * 32, t0 = blockIdx.x * 256;
    const int tid = threadIdx.x, lane = tid & 63, wave = tid >> 6;
    const int wt = t0 + wave * 64;            // wave's global t base
    const int lm = lane & 15, lq = lane >> 4;
    const int fro = ((lq ^ (lm >> 1)) & 3) * 16;   // swizzled LDS read offset
    const int gl_row = lane >> 2, gl_col = (lane & 3) * 16;

    const unsigned char* ab = act + (long)b * NITER * 1024 * 64;

    auto stage = [&](int cc) {
#pragma unroll
        for (int j = 0; j < CHUNK; ++j) {
            const int r = wave + 4 * j;          // slab id
            const int kt = r >> 2, p = r & 3;
            const long kg = ((long)(cc * CHUNK + kt) * 4 + p);
            const signed char* g = wp + (kg * M + m0 + gl_row) * 64 + gl_col;
            GLDS(g, &Ws[kt][p][0][0]);
            GLDS(g + 16 * 64, &Ws[kt][p][16][0]);
        }
    };

    i32x4 acc[4][8];
#pragma unroll
    for (int p = 0; p < 4; p++)
#pragma unroll
        for (int q = 0; q < 8; q++) acc[p][q] = (i32x4)0;

    stage(0);
    i32x4 areg[2][4];
#pragma unroll
    for (int f = 0; f < 4; f++)
        areg[0][f] = *(const i32x4*)&ab[((long)(wt + f * 16 + lm)) * 64 + lq * 16];
    __syncthreads();

    for (int c = 0; c < NCHUNK; ++c) {
#pragma unroll
        for (int kk = 0; kk < CHUNK; ++kk) {
            {
                const int itv = c * CHUNK + kk;
                const long nx = (itv + 1 < NITER) ? itv + 1 : itv;
#pragma unroll
                for (int f = 0; f < 4; f++)
                    areg[(kk + 1) & 1][f] = *(const i32x4*)
                        &ab[(nx * 1024 + wt + f * 16 + lm) * 64 + lq * 16];
            }
#pragma unroll
            for (int p = 0; p < 4; p++) {
                i32x4 w0 = *(const i32x4*)&Ws[kk][p][lm][fro];
                i32x4 w1 = *(const i32x4*)&Ws[kk][p][16 + lm][fro];
                if (TRANS) {
#pragma unroll
                    for (int f = 0; f < 4; f++) {
                        acc[p][f * 2 + 0] = __builtin_amdgcn_mfma_i32_16x16x64_i8(
                            areg[kk & 1][f], w0, acc[p][f * 2 + 0], 0, 0, 0);
                        acc[p][f * 2 + 1] = __builtin_amdgcn_mfma_i32_16x16x64_i8(
                            areg[kk & 1][f], w1, acc[p][f * 2 + 1], 0, 0, 0);
                    }
                } else {
#pragma unroll
                    for (int f = 0; f < 4; f++) {
                        acc[p][0 + f] = __builtin_amdgcn_mfma_i32_16x16x64_i8(
                            w0, areg[kk & 1][f], acc[p][0 + f], 0, 0, 0);
                        acc[p][4 + f] = __builtin_amdgcn_mfma_i32_16x16x64_i8(
                            w1, areg[kk & 1][f], acc[p][4 + f], 0, 0, 0);
                    }
                }
            }
        }
        if (c + 1 < NCHUNK) {
            __syncthreads();
            stage(c + 1);
            __syncthreads();
        }
    }

    if (TRANS) {
        double bv[2];
        bv[0] = (double)bias[m0 + lm];
        bv[1] = (double)bias[m0 + 16 + lm];
        float* Cb = C + (long)b * 1024 * M;
#pragma unroll
        for (int tf = 0; tf < 4; tf++)
#pragma unroll
            for (int r = 0; r < 4; r++) {
                const int trow = wt + tf * 16 + lq * 4 + r;
#pragma unroll
                for (int mf = 0; mf < 2; mf++) {
                    long T = acc[3][tf * 2 + mf][r];
                    T = T * 256 + acc[2][tf * 2 + mf][r];
                    T = T * 256 + acc[1][tf * 2 + mf][r];
                    T = T * 256 + acc[0][tf * 2 + mf][r];
                    Cb[(long)trow * M + m0 + mf * 16 + lm] =
                        (float)((double)T * INV231 + bv[mf]);
                }
            }
    } else {
        float* Cb = C + (long)b * M * 1024;
#pragma unroll
        for (int mf = 0; mf < 2; mf++)
#pragma unroll
            for (int r = 0; r < 4; r++) {
                const int mrow = m0 + mf * 16 + lq * 4 + r;
                const double bv = (double)bias[mrow];
#pragma unroll
                for (int tf = 0; tf < 4; tf++) {
                    long T = acc[3][mf * 4 + tf][r];
                    T = T * 256 + acc[2][mf * 4 + tf][r];
                    T = T * 256 + acc[1][mf * 4 + tf][r];
                    T = T * 256 + acc[0][mf * 4 + tf][r];
                    Cb[(long)mrow * 1024 + wt + tf * 16 + lm] =
                        (float)((double)T * INV231 + bv);
                }
            }
    }
}

// LDS-chunked LIF for layer 2 (round 4 + register preload); RPB=32 -> 256
// blocks (1/CU)
template <int RPB>
__global__ __launch_bounds__(256) void lif_lds(float* __restrict__ cur)
{
    __shared__ float cs[RPB][36];
    const long rowbase = (long)blockIdx.x * RPB;
    float* base = cur + rowbase * 1024;
    const int tid = threadIdx.x;
    double v = 0.0;
    const int NV = RPB * 32 / 4;
    for (int tc = 0; tc < 1024; tc += 32) {
        for (int f = tid; f < NV; f += 256) {
            int row = f >> 3, t4 = (f & 7) * 4;
            *(float4*)&cs[row][t4] = *(const float4*)&base[(long)row * 1024 + tc + t4];
        }
        __syncthreads();
        if (tid < RPB) {
            float cv[32];
#pragma unroll
            for (int j = 0; j < 32; j++) cv[j] = cs[tid][j];
#pragma unroll
            for (int j = 0; j < 32; j++) {
                v = 0.95 * v + (double)cv[j];
                bool s = v >= 1.0;
                cs[tid][j] = s ? 1.f : 0.f;
                if (s) v = 0.0;
            }
        }
        __syncthreads();
        for (int f = tid; f < NV; f += 256) {
            int row = f >> 3, t4 = (f & 7) * 4;
            *(float4*)&base[(long)row * 1024 + tc + t4] = *(float4*)&cs[row][t4];
        }
        __syncthreads();
    }
}

// ======================= fallback (round 3, proven) =======================

__device__ inline void split3(float w, _Float16& q0, _Float16& q1, _Float16& q2) {
    float p0 = rintf(w * 4096.f) * 2.44140625e-4f;
    float r1 = w - p0;
    float p1s = rintf(r1 * 8388608.f) * 2.44140625e-4f;
    float r2 = r1 - p1s * 4.8828125e-4f;
    float p2s = rintf(r2 * 1.7179869184e10f) * 1.220703125e-4f;
    q0 = (_Float16)p0; q1 = (_Float16)p1s; q2 = (_Float16)p2s;
}

__global__ __launch_bounds__(256) void gemm_f16x3_kernel(
    const float* __restrict__ A, const float* __restrict__ Bmat,
    const float* __restrict__ bias, float* __restrict__ C,
    int M, int N, int K, long sB, long sC)
{
    __shared__ _Float16 As[3][128][40];
    __shared__ _Float16 Bsh[128][40];
    const int batch = blockIdx.z;
    const float* Bp = Bmat + (long)batch * sB;
    float* Cp = C + (long)batch * sC;
    const int m0 = blockIdx.y * 128, n0 = blockIdx.x * 128;
    const int tid = threadIdx.x, lane = tid & 63, wave = tid >> 6;
    const int wrow = (wave >> 1) * 64, wcol = (wave & 1) * 64;
    const int lm = lane & 15, lq = lane >> 4;
    const int a_mo = tid >> 3, a_kc = (tid & 7) * 4;
    const int b_kq = tid >> 5, b_nq = tid & 31;

    f32x4 acc[3][4][4];
#pragma unroll
    for (int p = 0; p < 3; p++)
#pragma unroll
        for (int i = 0; i < 4; i++)
#pragma unroll
            for (int j = 0; j < 4; j++) acc[p][i][j] = (f32x4)0.f;

    for (int k0 = 0; k0 < K; k0 += 32) {
#pragma unroll
        for (int i = 0; i < 4; i++) {
            const int m = i * 32 + a_mo;
            float4 w = *(const float4*)&A[(long)(m0 + m) * K + k0 + a_kc];
            _Float16 a0[4], a1[4], a2[4];
            split3(w.x, a0[0], a1[0], a2[0]);
            split3(w.y, a0[1], a1[1], a2[1]);
            split3(w.z, a0[2], a1[2], a2[2]);
            split3(w.w, a0[3], a1[3], a2[3]);
            *(f16x4*)&As[0][m][a_kc] = (f16x4){a0[0], a0[1], a0[2], a0[3]};
            *(f16x4*)&As[1][m][a_kc] = (f16x4){a1[0], a1[1], a1[2], a1[3]};
            *(f16x4*)&As[2][m][a_kc] = (f16x4){a2[0], a2[1], a2[2], a2[3]};
        }
        {
            float4 r0 = *(const float4*)&Bp[(long)(k0 + b_kq * 4 + 0) * N + n0 + b_nq * 4];
            float4 r1 = *(const float4*)&Bp[(long)(k0 + b_kq * 4 + 1) * N + n0 + b_nq * 4];
            float4 r2 = *(const float4*)&Bp[(long)(k0 + b_kq * 4 + 2) * N + n0 + b_nq * 4];
            float4 r3 = *(const float4*)&Bp[(long)(k0 + b_kq * 4 + 3) * N + n0 + b_nq * 4];
            *(f16x4*)&Bsh[b_nq * 4 + 0][b_kq * 4] =
                (f16x4){(_Float16)r0.x, (_Float16)r1.x, (_Float16)r2.x, (_Float16)r3.x};
            *(f16x4*)&Bsh[b_nq * 4 + 1][b_kq * 4] =
                (f16x4){(_Float16)r0.y, (_Float16)r1.y, (_Float16)r2.y, (_Float16)r3.y};
            *(f16x4*)&Bsh[b_nq * 4 + 2][b_kq * 4] =
                (f16x4){(_Float16)r0.z, (_Float16)r1.z, (_Float16)r2.z, (_Float16)r3.z};
            *(f16x4*)&Bsh[b_nq * 4 + 3][b_kq * 4] =
                (f16x4){(_Float16)r0.w, (_Float16)r1.w, (_Float16)r2.w, (_Float16)r3.w};
        }
        __syncthreads();
        f16x8 bf[4];
#pragma unroll
        for (int j = 0; j < 4; j++)
            bf[j] = *(const f16x8*)&Bsh[wcol + j * 16 + lm][lq * 8];
#pragma unroll
        for (int p = 0; p < 3; p++) {
            f16x8 af[4];
#pragma unroll
            for (int i = 0; i < 4; i++)
                af[i] = *(const f16x8*)&As[p][wrow + i * 16 + lm][lq * 8];
#pragma unroll
            for (int i = 0; i < 4; i++)
#pragma unroll
                for (int j = 0; j < 4; j++)
                    acc[p][i][j] = __builtin_amdgcn_mfma_f32_16x16x32_f16(
                        af[i], bf[j], acc[p][i][j], 0, 0, 0);
        }
        __syncthreads();
    }
#pragma unroll
    for (int i = 0; i < 4; i++)
#pragma unroll
        for (int r = 0; r < 4; r++) {
            const int row = m0 + wrow + i * 16 + lq * 4 + r;
            const double bv = (double)bias[row];
#pragma unroll
            for (int j = 0; j < 4; j++) {
                double s = (double)acc[0][i][j][r]
                         + (double)acc[1][i][j][r] * 4.8828125e-4
                         + (double)acc[2][i][j][r] * 4.76837158203125e-7 + bv;
                Cp[(long)row * N + n0 + wcol + j * 16 + lm] = (float)s;
            }
        }
}

__global__ __launch_bounds__(256) void lif_rows(float* __restrict__ data,
                                                long nrows, int T)
{
    long r = (long)blockIdx.x * blockDim.x + threadIdx.x;
    if (r >= nrows) return;
    float* p = data + r * (long)T;
    double v = 0.0;
    for (int t = 0; t < T; t += 4) {
        float4 c = *(float4*)(p + t);
        float4 s;
        v = 0.95 * v + (double)c.x; s.x = (v >= 1.0) ? 1.f : 0.f; if (v >= 1.0) v = 0.0;
        v = 0.95 * v + (double)c.y; s.y = (v >= 1.0) ? 1.f : 0.f; if (v >= 1.0) v = 0.0;
        v = 0.95 * v + (double)c.z; s.z = (v >= 1.0) ? 1.f : 0.f; if (v >= 1.0) v = 0.0;
        v = 0.95 * v + (double)c.w; s.w = (v >= 1.0) ? 1.f : 0.f; if (v >= 1.0) v = 0.0;
        *(float4*)(p + t) = s;
    }
}

// ======================= launch =======================

extern "C" void kernel_launch(void* const* d_in, const int* in_sizes, int n_in,
                              void* d_out, int out_size, void* d_ws, size_t ws_size,
                              hipStream_t stream)
{
    const float* x  = (const float*)d_in[0];  // (32, 512, 1024)
    const float* w1 = (const float*)d_in[1];  // (2048, 512)
    const float* b1 = (const float*)d_in[2];  // (2048)
    const float* w2 = (const float*)d_in[3];  // (256, 2048)
    const float* b2 = (const float*)d_in[4];  // (256)

    float* out  = (float*)d_out;
    float* spk1 = out;                              // (32, 2048, 1024)
    float* spk2 = out + (long)32 * 2048 * 1024;     // (32, 256, 1024)

    const size_t WP1 = 4194304;        // [8][4][2048][64] i8
    const size_t WP2 = 2097152;        // [32][4][256][64] i8
    const size_t X8T = 16777216;       // [32][8][1024][64] i8
    const size_t SPK = 67108864;       // [32][32][1024][64] i8
    const size_t MSK = 8388608;        // [32][32][2048] u32
    const size_t NEED = WP1 + WP2 + X8T + SPK + MSK;

    if (ws_size >= NEED) {
        char* ws = (char*)d_ws;
        signed char* wp1 = (signed char*)ws;
        signed char* wp2 = (signed char*)(ws + WP1);
        unsigned char* x8t = (unsigned char*)(ws + WP1 + WP2);
        unsigned char* spk8 = (unsigned char*)(ws + WP1 + WP2 + X8T);
        unsigned* mask_ws = (unsigned*)(ws + WP1 + WP2 + X8T + SPK);

        prep_w8<<<1024, 256, 0, stream>>>(w1, wp1, 2048, 512);
        prep_w8<<<512, 256, 0, stream>>>(w2, wp2, 256, 2048);
        prep_x8<<<dim3(16, 8, 32), 256, 0, stream>>>(x, x8t);

        // layer 1: fused GEMM+LIF -> masks only; 64-m blocks, 64-lane LIF
        gemm_lif1<<<dim3(32, 32), 320, 0, stream>>>(wp1, x8t, b1, mask_ws);
        expand_spk8<<<dim3(32, 32), 256, 0, stream>>>(mask_ws, spk8);

        // layer 2: cur2 [b][256][1024] direct -> in-place LIF
        gemm_i8<false, 32, 8><<<dim3(4, 32, 8), 256, 0, stream>>>(
            wp2, spk8, b2, spk2, 256);
        lif_lds<32><<<256, 256, 0, stream>>>(spk2);

        // f32 spike expansion for layer-1 output
        expand_spk<<<8192, 256, 0, stream>>>(mask_ws, spk1);
    } else {
        gemm_f16x3_kernel<<<dim3(8, 16, 32), 256, 0, stream>>>(
            w1, x, b1, spk1, 2048, 1024, 512, (long)512 * 1024, (long)2048 * 1024);
        lif_rows<<<(65536 + 255) / 256, 256, 0, stream>>>(spk1, 65536, 1024);
        gemm_f16x3_kernel<<<dim3(8, 2, 32), 256, 0, stream>>>(
            w2, spk1, b2, spk2, 256, 1024, 2048, (long)2048 * 1024, (long)256 * 1024);
        lif_rows<<<(8192 + 255) / 256, 256, 0, stream>>>(spk2, 8192, 1024);
    }
}

// Round 7
// 623.705 us; speedup vs baseline: 1.1919x; 1.0235x over previous
//
#include <hip/hip_runtime.h>

// ---------------------------------------------------------------------------
// LavaNetwork, bit-exact 4-plane i8 MFMA GEMM (mfma_i32_16x16x64_i8).
//   w ~ k*2^-31 (k = rint(w*2^31), residual <= 2^-32), 4 balanced base-256
//   digits -> exact i8 planes, exact i32 sums, exact i64 Horner + f64 bias.
// Round-16 structure (round-15 + stall removal in gemm_lif1):
//   - gemm_lif1: 64-m block, 320 thr (4 GEMM waves 64t x 16m + 64-lane LIF
//     wave), Ws[8][4][64][64]=128K whole-K resident + cs[2][64][64]=32K.
//     NEW: (1) 4-slot ring act prefetch (distance 2, ~660 cyc cover);
//     (2) raw per-pass barriers (manual lgkmcnt(0) + s_barrier +
//     sched_barrier(0)) -- NO vmcnt(0) drain, so act prefetch survives
//     pass boundaries. Only LDS (cs) crosses these barriers -> lgkmcnt-only
//     is sufficient; initial staging barrier stays __syncthreads (GLDS).
//     (3) s_setprio(1) around MFMA cluster (wave role diversity: T5 prereq).
//   - Emits 1024-bit masks only; expanders / layer 2 / preps unchanged.
//   - LIF recurrence identical arithmetic: u = 0.95*u + c; on spike u = c
//     next step (== 0.95*0 + c exactly), f64 state, f32 inputs.
// Fallback: round-3 proven f16 path if ws too small.
// ---------------------------------------------------------------------------

typedef int i32x4 __attribute__((ext_vector_type(4)));
typedef _Float16 f16x8 __attribute__((ext_vector_type(8)));
typedef _Float16 f16x4 __attribute__((ext_vector_type(4)));
typedef float f32x4 __attribute__((ext_vector_type(4)));

#define GLDS(g, l) __builtin_amdgcn_global_load_lds( \
    (const __attribute__((address_space(1))) void*)(g), \
    (__attribute__((address_space(3))) void*)(l), 16, 0, 0)

#define INV231 4.656612873077392578125e-10   // 2^-31

// ======================= prep =======================

// w (M,K) f32 -> wp [K/64][4][M][64] i8 digit planes; 16-B chunk c of row m
// stored at c ^ ((m>>1)&3)  (round-6/8-proven conflict-free for ds_read_b128).
__global__ __launch_bounds__(256) void prep_w8(const float* __restrict__ A,
                                               signed char* __restrict__ wp,
                                               int M, int K)
{
    long gt = (long)blockIdx.x * 256 + threadIdx.x;
    int kq4 = K >> 2;
    int m = (int)(gt / kq4), kq = (int)(gt % kq4);
    int k0 = kq * 4;
    int kt = k0 >> 6, kin = k0 & 63;
    int cw = ((kin >> 4) ^ (m >> 1)) & 3;
    float4 w = *(const float4*)&A[(long)m * K + k0];
    float wv[4] = {w.x, w.y, w.z, w.w};
    int pack[4] = {0, 0, 0, 0};
#pragma unroll
    for (int e = 0; e < 4; e++) {
        long k64 = (long)rint((double)wv[e] * 2147483648.0);  // * 2^31
#pragma unroll
        for (int j = 0; j < 3; j++) {
            long r = ((k64 + 128) & 255) - 128;   // balanced digit [-128,127]
            pack[j] |= ((int)r & 255) << (e * 8);
            k64 = (k64 - r) >> 8;
        }
        pack[3] |= ((int)k64 & 255) << (e * 8);
    }
#pragma unroll
    for (int p = 0; p < 4; p++)
        *(int*)&wp[(((long)kt * 4 + p) * M + m) * 64 + cw * 16 + (kin & 15)] = pack[p];
}

// x [b][512][1024] f32 -> x8t [b][8][1024][64] i8 (k-tile-major, plain layout
// for direct coalesced frag loads; no swizzle).
__global__ __launch_bounds__(256) void prep_x8(const float* __restrict__ x,
                                               unsigned char* __restrict__ xt)
{
    __shared__ float xs[64][68];
    const int b = blockIdx.z, i0 = blockIdx.y * 64, t0 = blockIdx.x * 64;
    const float* xb = x + ((long)b * 512 + i0) * 1024 + t0;
#pragma unroll
    for (int p = 0; p < 4; p++) {
        int f = threadIdx.x + p * 256;
        int i = f >> 4, t4 = (f & 15) * 4;
        *(float4*)&xs[i][t4] = *(const float4*)&xb[(long)i * 1024 + t4];
    }
    __syncthreads();
    int tt = threadIdx.x >> 2, c = threadIdx.x & 3;
    unsigned char bytes[16];
#pragma unroll
    for (int j = 0; j < 16; j++)
        bytes[j] = (unsigned char)xs[c * 16 + j][tt];
    *(uint4*)&xt[(((long)b * 8 + (i0 >> 6)) * 1024 + t0 + tt) * 64 + c * 16] =
        *(uint4*)bytes;
}

// ======================= fused layer-1 GEMM + LIF =======================
// Block = (64 m, b) x ALL 1024 t. 320 threads: waves 0-3 GEMM (64t x 16m
// each per pass; wave w owns m-slice w*16..w*16+15), wave 4 = LIF with all
// 64 lanes (chain for col m0+lane).
// LDS: Ws[8][4][64][64] = 128 KB (whole K=512 slab, staged once) +
//      cs[2][64][64] f32 = 32 KB (double-buffered currents) = 160 KB exact.
// 16 t-passes of 64: pass p GEMM -> cs[p&1]; LIF scans cs[(p-1)&1]
// concurrently. Raw lgkmcnt-only barriers per pass (act prefetch survives);
// 4-slot ring prefetch distance 2; setprio around MFMA.
// Output: 1024-bit spike masks only.
__global__ __launch_bounds__(320, 1) void gemm_lif1(
    const signed char* __restrict__ wp,     // [8][4][2048][64] swizzled
    const unsigned char* __restrict__ act,  // [b][8][1024][64] plain
    const float* __restrict__ bias,         // (2048)
    unsigned* __restrict__ mask_ws)         // [b][32][2048]
{
    __shared__ signed char Ws[8][4][64][64];   // 128 KB
    __shared__ float cs[2][64][64];            // 32 KB

    const int m0 = blockIdx.x * 64, b = blockIdx.y;
    const int tid = threadIdx.x, lane = tid & 63, wave = tid >> 6;
    const int lm = lane & 15, lq = lane >> 4;
    const int fro = ((lq ^ (lm >> 1)) & 3) * 16;   // swizzled LDS read offset
    const unsigned char* ab = act + (long)b * 8 * 1024 * 64;

    i32x4 areg[4][4];   // 4-slot ring, prefetch distance 2
    double bv = 0.0;

    if (wave < 4) {
        // stage the whole weight slab: 32 slabs of [64][64]=4KB,
        // 8 slabs/wave x 4 GLDS each
        const int gl_row = lane >> 2, gl_col = (lane & 3) * 16;
#pragma unroll
        for (int j = 0; j < 8; ++j) {
            const int r = wave + 4 * j;          // slab id 0..31
            const int kt = r >> 2, pl = r & 3;
            const signed char* g = wp + ((long)r * 2048 + m0 + gl_row) * 64 + gl_col;
#pragma unroll
            for (int q = 0; q < 4; ++q)
                GLDS(g + q * 16 * 64, &Ws[kt][pl][q * 16][0]);
        }
        bv = (double)bias[m0 + wave * 16 + lm];
        // ring prologue: virtual iters v=0 (slot 0) and v=1 (slot 1)
#pragma unroll
        for (int f = 0; f < 4; f++)
            areg[0][f] = *(const i32x4*)
                &ab[((long)(f * 16 + lm)) * 64 + lq * 16];                // kt 0, t lm
#pragma unroll
        for (int f = 0; f < 4; f++)
            areg[1][f] = *(const i32x4*)
                &ab[((long)1 * 1024 + f * 16 + lm) * 64 + lq * 16];      // kt 1, t lm
    }
    __syncthreads();   // full drain: GLDS weights must be resident

    // LIF state (wave 4, all 64 lanes: chain for col m0+lane)
    double u = 0.0;
    bool sprev = false;

    for (int p = 0; p < 17; ++p) {
        if (wave < 4 && p < 16) {
            i32x4 acc[4][4];   // [plane][t-frag]
#pragma unroll
            for (int pp = 0; pp < 4; pp++)
#pragma unroll
                for (int f = 0; f < 4; f++) acc[pp][f] = (i32x4)0;

#pragma unroll
            for (int kk = 0; kk < 8; ++kk) {
                // prefetch virtual iter v+2 into slot (kk+2)&3
                {
                    int vn = p * 8 + kk + 2;
                    if (vn > 127) vn = 127;      // redundant reload, same addr
                    const int pn = vn >> 3, kn = vn & 7;
                    const long tt = (long)pn * 64 + lm;
#pragma unroll
                    for (int f = 0; f < 4; f++)
                        areg[(kk + 2) & 3][f] = *(const i32x4*)
                            &ab[((long)kn * 1024 + tt + f * 16) * 64 + lq * 16];
                }
                __builtin_amdgcn_s_setprio(1);
#pragma unroll
                for (int pl = 0; pl < 4; pl++) {
                    i32x4 w0 = *(const i32x4*)&Ws[kk][pl][wave * 16 + lm][fro];
#pragma unroll
                    for (int f = 0; f < 4; f++)
                        acc[pl][f] = __builtin_amdgcn_mfma_i32_16x16x64_i8(
                            areg[kk & 3][f], w0, acc[pl][f], 0, 0, 0);
                }
                __builtin_amdgcn_s_setprio(0);
            }
            // Horner -> exact f32 current -> cs[p&1]
#pragma unroll
            for (int tf = 0; tf < 4; tf++)
#pragma unroll
                for (int r = 0; r < 4; r++) {
                    long T = acc[3][tf][r];
                    T = T * 256 + acc[2][tf][r];
                    T = T * 256 + acc[1][tf][r];
                    T = T * 256 + acc[0][tf][r];
                    cs[p & 1][tf * 16 + lq * 4 + r][wave * 16 + lm] =
                        (float)((double)T * INV231 + bv);
                }
        }
        if (wave == 4 && p >= 1) {
            const int pq = p - 1, buf = pq & 1;
            // register preload (64 independent ds_reads), then register-only
            // f64 chains; all static indices
            float cvA[32], cvB[32];
#pragma unroll
            for (int j = 0; j < 32; ++j) cvA[j] = cs[buf][j][lane];
#pragma unroll
            for (int j = 0; j < 32; ++j) cvB[j] = cs[buf][32 + j][lane];
            {   // t-word pq*2
                unsigned mword = 0;
#pragma unroll
                for (int j = 0; j < 32; ++j) {
                    double c = (double)cvA[j];
                    double a = 0.95 * u + c;
                    u = sprev ? c : a;
                    bool s = (u >= 1.0);
                    mword |= (s ? 1u : 0u) << j;
                    sprev = s;
                }
                mask_ws[((long)b * 32 + pq * 2 + 0) * 2048 + m0 + lane] = mword;
            }
            {   // t-word pq*2+1
                unsigned mword = 0;
#pragma unroll
                for (int j = 0; j < 32; ++j) {
                    double c = (double)cvB[j];
                    double a = 0.95 * u + c;
                    u = sprev ? c : a;
                    bool s = (u >= 1.0);
                    mword |= (s ? 1u : 0u) << j;
                    sprev = s;
                }
                mask_ws[((long)b * 32 + pq * 2 + 1) * 2048 + m0 + lane] = mword;
            }
        }
        // raw pass barrier: only LDS (cs) crosses it -> lgkmcnt(0) suffices;
        // in-flight GLOBAL act prefetches intentionally survive (no vmcnt
        // drain -- the round-6 structural stall).
        asm volatile("s_waitcnt lgkmcnt(0)" ::: "memory");
        __builtin_amdgcn_s_barrier();
        __builtin_amdgcn_sched_barrier(0);
    }
}

// ======================= mask expanders =======================

// masks [b][32][2048] -> i8 spikes spk8 [b][32 kt][1024 t][64 m]
__global__ __launch_bounds__(256) void expand_spk8(
    const unsigned* __restrict__ mask_ws,
    unsigned char* __restrict__ spk8)
{
    __shared__ unsigned msk[64][33];
    const int b = blockIdx.x, kt = blockIdx.y;
    const int tid = threadIdx.x;
#pragma unroll
    for (int i = 0; i < 8; ++i) {
        int idx = tid + i * 256;            // 0..2047
        int tw = idx >> 6, m = idx & 63;
        msk[m][tw] = mask_ws[((long)b * 32 + tw) * 2048 + kt * 64 + m];
    }
    __syncthreads();
    unsigned char* dst = spk8 + ((long)b * 32 + kt) * 1024 * 64;
#pragma unroll
    for (int i = 0; i < 16; ++i) {
        int off = tid + i * 256;            // 16-B chunk index 0..4095
        int t = off >> 2, mq = off & 3;
        int tw = t >> 5, sh = t & 31;
        unsigned w0 = 0, w1 = 0, w2 = 0, w3 = 0;
#pragma unroll
        for (int j = 0; j < 4; ++j) {
            w0 |= ((msk[mq * 16 + j][tw] >> sh) & 1u) << (8 * j);
            w1 |= ((msk[mq * 16 + 4 + j][tw] >> sh) & 1u) << (8 * j);
            w2 |= ((msk[mq * 16 + 8 + j][tw] >> sh) & 1u) << (8 * j);
            w3 |= ((msk[mq * 16 + 12 + j][tw] >> sh) & 1u) << (8 * j);
        }
        *(uint4*)&dst[(long)off * 16] = (uint4){w0, w1, w2, w3};
    }
}

// masks [b][32][2048] -> f32 spikes [b][2048][1024]
__global__ __launch_bounds__(256) void expand_spk(
    const unsigned* __restrict__ mask_ws,
    float* __restrict__ spk1)
{
    __shared__ unsigned msk[8][32];
    const long rowbase = (long)blockIdx.x * 8;
    const int b = (int)(rowbase >> 11), m0 = (int)(rowbase & 2047);
    const int tid = threadIdx.x;
    {
        int w = tid >> 3, r = tid & 7;
        msk[r][w] = mask_ws[((long)b * 32 + w) * 2048 + m0 + r];
    }
    __syncthreads();
    const int r = tid >> 5, l5 = tid & 31;
    float* dst = spk1 + (rowbase + r) * 1024;
    const int sh = (l5 & 7) * 4;
#pragma unroll
    for (int j = 0; j < 8; j++) {
        const int t = l5 * 4 + j * 128;
        const unsigned w = msk[r][(l5 >> 3) + j * 4];
        float4 o;
        o.x = ((w >> sh) & 1u) ? 1.f : 0.f;
        o.y = ((w >> (sh + 1)) & 1u) ? 1.f : 0.f;
        o.z = ((w >> (sh + 2)) & 1u) ? 1.f : 0.f;
        o.w = ((w >> (sh + 3)) & 1u) ? 1.f : 0.f;
        *(float4*)&dst[t] = o;
    }
}

// ======================= layer-2 GEMM (round-11 proven) =======================
// !TRANS: D[M][t] (weights A, acts B) -> cur2 directly.
// CHUNK k-tiles staged per phase; inner loop barrier-free.
template <bool TRANS, int NITER, int CHUNK>
__global__ __launch_bounds__(256, 2) void gemm_i8(
    const signed char* __restrict__ wp,     // [K/64][4][M][64] swizzled
    const unsigned char* __restrict__ act,  // [b][K/64][1024][64] plain
    const float* __restrict__ bias,         // (M)
    float* __restrict__ C,
    int M)
{
    constexpr int NCHUNK = NITER / CHUNK;
    __shared__ signed char Ws[CHUNK][4][32][64];   // CHUNK * 8 KB

    const int b = blockIdx.y;
    const int m0 = blockIdx.z * 32, t0 = blockIdx.x * 256;
    const int tid = threadIdx.x, lane = tid & 63, wave = tid >> 6;
    const int wt = t0 + wave * 64;            // wave's global t base
    const int lm = lane & 15, lq = lane >> 4;
    const int fro = ((lq ^ (lm >> 1)) & 3) * 16;   // swizzled LDS read offset
    const int gl_row = lane >> 2, gl_col = (lane & 3) * 16;

    const unsigned char* ab = act + (long)b * NITER * 1024 * 64;

    auto stage = [&](int cc) {
#pragma unroll
        for (int j = 0; j < CHUNK; ++j) {
            const int r = wave + 4 * j;          // slab id
            const int kt = r >> 2, p = r & 3;
            const long kg = ((long)(cc * CHUNK + kt) * 4 + p);
            const signed char* g = wp + (kg * M + m0 + gl_row) * 64 + gl_col;
            GLDS(g, &Ws[kt][p][0][0]);
            GLDS(g + 16 * 64, &Ws[kt][p][16][0]);
        }
    };

    i32x4 acc[4][8];
#pragma unroll
    for (int p = 0; p < 4; p++)
#pragma unroll
        for (int q = 0; q < 8; q++) acc[p][q] = (i32x4)0;

    stage(0);
    i32x4 areg[2][4];
#pragma unroll
    for (int f = 0; f < 4; f++)
        areg[0][f] = *(const i32x4*)&ab[((long)(wt + f * 16 + lm)) * 64 + lq * 16];
    __syncthreads();

    for (int c = 0; c < NCHUNK; ++c) {
#pragma unroll
        for (int kk = 0; kk < CHUNK; ++kk) {
            {
                const int itv = c * CHUNK + kk;
                const long nx = (itv + 1 < NITER) ? itv + 1 : itv;
#pragma unroll
                for (int f = 0; f < 4; f++)
                    areg[(kk + 1) & 1][f] = *(const i32x4*)
                        &ab[(nx * 1024 + wt + f * 16 + lm) * 64 + lq * 16];
            }
#pragma unroll
            for (int p = 0; p < 4; p++) {
                i32x4 w0 = *(const i32x4*)&Ws[kk][p][lm][fro];
                i32x4 w1 = *(const i32x4*)&Ws[kk][p][16 + lm][fro];
                if (TRANS) {
#pragma unroll
                    for (int f = 0; f < 4; f++) {
                        acc[p][f * 2 + 0] = __builtin_amdgcn_mfma_i32_16x16x64_i8(
                            areg[kk & 1][f], w0, acc[p][f * 2 + 0], 0, 0, 0);
                        acc[p][f * 2 + 1] = __builtin_amdgcn_mfma_i32_16x16x64_i8(
                            areg[kk & 1][f], w1, acc[p][f * 2 + 1], 0, 0, 0);
                    }
                } else {
#pragma unroll
                    for (int f = 0; f < 4; f++) {
                        acc[p][0 + f] = __builtin_amdgcn_mfma_i32_16x16x64_i8(
                            w0, areg[kk & 1][f], acc[p][0 + f], 0, 0, 0);
                        acc[p][4 + f] = __builtin_amdgcn_mfma_i32_16x16x64_i8(
                            w1, areg[kk & 1][f], acc[p][4 + f], 0, 0, 0);
                    }
                }
            }
        }
        if (c + 1 < NCHUNK) {
            __syncthreads();
            stage(c + 1);
            __syncthreads();
        }
    }

    if (TRANS) {
        double bv[2];
        bv[0] = (double)bias[m0 + lm];
        bv[1] = (double)bias[m0 + 16 + lm];
        float* Cb = C + (long)b * 1024 * M;
#pragma unroll
        for (int tf = 0; tf < 4; tf++)
#pragma unroll
            for (int r = 0; r < 4; r++) {
                const int trow = wt + tf * 16 + lq * 4 + r;
#pragma unroll
                for (int mf = 0; mf < 2; mf++) {
                    long T = acc[3][tf * 2 + mf][r];
                    T = T * 256 + acc[2][tf * 2 + mf][r];
                    T = T * 256 + acc[1][tf * 2 + mf][r];
                    T = T * 256 + acc[0][tf * 2 + mf][r];
                    Cb[(long)trow * M + m0 + mf * 16 + lm] =
                        (float)((double)T * INV231 + bv[mf]);
                }
            }
    } else {
        float* Cb = C + (long)b * M * 1024;
#pragma unroll
        for (int mf = 0; mf < 2; mf++)
#pragma unroll
            for (int r = 0; r < 4; r++) {
                const int mrow = m0 + mf * 16 + lq * 4 + r;
                const double bv = (double)bias[mrow];
#pragma unroll
                for (int tf = 0; tf < 4; tf++) {
                    long T = acc[3][mf * 4 + tf][r];
                    T = T * 256 + acc[2][mf * 4 + tf][r];
                    T = T * 256 + acc[1][mf * 4 + tf][r];
                    T = T * 256 + acc[0][mf * 4 + tf][r];
                    Cb[(long)mrow * 1024 + wt + tf * 16 + lm] =
                        (float)((double)T * INV231 + bv);
                }
            }
    }
}

// LDS-chunked LIF for layer 2 (round 4 + register preload); RPB=32 -> 256
// blocks (1/CU)
template <int RPB>
__global__ __launch_bounds__(256) void lif_lds(float* __restrict__ cur)
{
    __shared__ float cs[RPB][36];
    const long rowbase = (long)blockIdx.x * RPB;
    float* base = cur + rowbase * 1024;
    const int tid = threadIdx.x;
    double v = 0.0;
    const int NV = RPB * 32 / 4;
    for (int tc = 0; tc < 1024; tc += 32) {
        for (int f = tid; f < NV; f += 256) {
            int row = f >> 3, t4 = (f & 7) * 4;
            *(float4*)&cs[row][t4] = *(const float4*)&base[(long)row * 1024 + tc + t4];
        }
        __syncthreads();
        if (tid < RPB) {
            float cv[32];
#pragma unroll
            for (int j = 0; j < 32; j++) cv[j] = cs[tid][j];
#pragma unroll
            for (int j = 0; j < 32; j++) {
                v = 0.95 * v + (double)cv[j];
                bool s = v >= 1.0;
                cs[tid][j] = s ? 1.f : 0.f;
                if (s) v = 0.0;
            }
        }
        __syncthreads();
        for (int f = tid; f < NV; f += 256) {
            int row = f >> 3, t4 = (f & 7) * 4;
            *(float4*)&base[(long)row * 1024 + tc + t4] = *(float4*)&cs[row][t4];
        }
        __syncthreads();
    }
}

// ======================= fallback (round 3, proven) =======================

__device__ inline void split3(float w, _Float16& q0, _Float16& q1, _Float16& q2) {
    float p0 = rintf(w * 4096.f) * 2.44140625e-4f;
    float r1 = w - p0;
    float p1s = rintf(r1 * 8388608.f) * 2.44140625e-4f;
    float r2 = r1 - p1s * 4.8828125e-4f;
    float p2s = rintf(r2 * 1.7179869184e10f) * 1.220703125e-4f;
    q0 = (_Float16)p0; q1 = (_Float16)p1s; q2 = (_Float16)p2s;
}

__global__ __launch_bounds__(256) void gemm_f16x3_kernel(
    const float* __restrict__ A, const float* __restrict__ Bmat,
    const float* __restrict__ bias, float* __restrict__ C,
    int M, int N, int K, long sB, long sC)
{
    __shared__ _Float16 As[3][128][40];
    __shared__ _Float16 Bsh[128][40];
    const int batch = blockIdx.z;
    const float* Bp = Bmat + (long)batch * sB;
    float* Cp = C + (long)batch * sC;
    const int m0 = blockIdx.y * 128, n0 = blockIdx.x * 128;
    const int tid = threadIdx.x, lane = tid & 63, wave = tid >> 6;
    const int wrow = (wave >> 1) * 64, wcol = (wave & 1) * 64;
    const int lm = lane & 15, lq = lane >> 4;
    const int a_mo = tid >> 3, a_kc = (tid & 7) * 4;
    const int b_kq = tid >> 5, b_nq = tid & 31;

    f32x4 acc[3][4][4];
#pragma unroll
    for (int p = 0; p < 3; p++)
#pragma unroll
        for (int i = 0; i < 4; i++)
#pragma unroll
            for (int j = 0; j < 4; j++) acc[p][i][j] = (f32x4)0.f;

    for (int k0 = 0; k0 < K; k0 += 32) {
#pragma unroll
        for (int i = 0; i < 4; i++) {
            const int m = i * 32 + a_mo;
            float4 w = *(const float4*)&A[(long)(m0 + m) * K + k0 + a_kc];
            _Float16 a0[4], a1[4], a2[4];
            split3(w.x, a0[0], a1[0], a2[0]);
            split3(w.y, a0[1], a1[1], a2[1]);
            split3(w.z, a0[2], a1[2], a2[2]);
            split3(w.w, a0[3], a1[3], a2[3]);
            *(f16x4*)&As[0][m][a_kc] = (f16x4){a0[0], a0[1], a0[2], a0[3]};
            *(f16x4*)&As[1][m][a_kc] = (f16x4){a1[0], a1[1], a1[2], a1[3]};
            *(f16x4*)&As[2][m][a_kc] = (f16x4){a2[0], a2[1], a2[2], a2[3]};
        }
        {
            float4 r0 = *(const float4*)&Bp[(long)(k0 + b_kq * 4 + 0) * N + n0 + b_nq * 4];
            float4 r1 = *(const float4*)&Bp[(long)(k0 + b_kq * 4 + 1) * N + n0 + b_nq * 4];
            float4 r2 = *(const float4*)&Bp[(long)(k0 + b_kq * 4 + 2) * N + n0 + b_nq * 4];
            float4 r3 = *(const float4*)&Bp[(long)(k0 + b_kq * 4 + 3) * N + n0 + b_nq * 4];
            *(f16x4*)&Bsh[b_nq * 4 + 0][b_kq * 4] =
                (f16x4){(_Float16)r0.x, (_Float16)r1.x, (_Float16)r2.x, (_Float16)r3.x};
            *(f16x4*)&Bsh[b_nq * 4 + 1][b_kq * 4] =
                (f16x4){(_Float16)r0.y, (_Float16)r1.y, (_Float16)r2.y, (_Float16)r3.y};
            *(f16x4*)&Bsh[b_nq * 4 + 2][b_kq * 4] =
                (f16x4){(_Float16)r0.z, (_Float16)r1.z, (_Float16)r2.z, (_Float16)r3.z};
            *(f16x4*)&Bsh[b_nq * 4 + 3][b_kq * 4] =
                (f16x4){(_Float16)r0.w, (_Float16)r1.w, (_Float16)r2.w, (_Float16)r3.w};
        }
        __syncthreads();
        f16x8 bf[4];
#pragma unroll
        for (int j = 0; j < 4; j++)
            bf[j] = *(const f16x8*)&Bsh[wcol + j * 16 + lm][lq * 8];
#pragma unroll
        for (int p = 0; p < 3; p++) {
            f16x8 af[4];
#pragma unroll
            for (int i = 0; i < 4; i++)
                af[i] = *(const f16x8*)&As[p][wrow + i * 16 + lm][lq * 8];
#pragma unroll
            for (int i = 0; i < 4; i++)
#pragma unroll
                for (int j = 0; j < 4; j++)
                    acc[p][i][j] = __builtin_amdgcn_mfma_f32_16x16x32_f16(
                        af[i], bf[j], acc[p][i][j], 0, 0, 0);
        }
        __syncthreads();
    }
#pragma unroll
    for (int i = 0; i < 4; i++)
#pragma unroll
        for (int r = 0; r < 4; r++) {
            const int row = m0 + wrow + i * 16 + lq * 4 + r;
            const double bv = (double)bias[row];
#pragma unroll
            for (int j = 0; j < 4; j++) {
                double s = (double)acc[0][i][j][r]
                         + (double)acc[1][i][j][r] * 4.8828125e-4
                         + (double)acc[2][i][j][r] * 4.76837158203125e-7 + bv;
                Cp[(long)row * N + n0 + wcol + j * 16 + lm] = (float)s;
            }
        }
}

__global__ __launch_bounds__(256) void lif_rows(float* __restrict__ data,
                                                long nrows, int T)
{
    long r = (long)blockIdx.x * blockDim.x + threadIdx.x;
    if (r >= nrows) return;
    float* p = data + r * (long)T;
    double v = 0.0;
    for (int t = 0; t < T; t += 4) {
        float4 c = *(float4*)(p + t);
        float4 s;
        v = 0.95 * v + (double)c.x; s.x = (v >= 1.0) ? 1.f : 0.f; if (v >= 1.0) v = 0.0;
        v = 0.95 * v + (double)c.y; s.y = (v >= 1.0) ? 1.f : 0.f; if (v >= 1.0) v = 0.0;
        v = 0.95 * v + (double)c.z; s.z = (v >= 1.0) ? 1.f : 0.f; if (v >= 1.0) v = 0.0;
        v = 0.95 * v + (double)c.w; s.w = (v >= 1.0) ? 1.f : 0.f; if (v >= 1.0) v = 0.0;
        *(float4*)(p + t) = s;
    }
}

// ======================= launch =======================

extern "C" void kernel_launch(void* const* d_in, const int* in_sizes, int n_in,
                              void* d_out, int out_size, void* d_ws, size_t ws_size,
                              hipStream_t stream)
{
    const float* x  = (const float*)d_in[0];  // (32, 512, 1024)
    const float* w1 = (const float*)d_in[1];  // (2048, 512)
    const float* b1 = (const float*)d_in[2];  // (2048)
    const float* w2 = (const float*)d_in[3];  // (256, 2048)
    const float* b2 = (const float*)d_in[4];  // (256)

    float* out  = (float*)d_out;
    float* spk1 = out;                              // (32, 2048, 1024)
    float* spk2 = out + (long)32 * 2048 * 1024;     // (32, 256, 1024)

    const size_t WP1 = 4194304;        // [8][4][2048][64] i8
    const size_t WP2 = 2097152;        // [32][4][256][64] i8
    const size_t X8T = 16777216;       // [32][8][1024][64] i8
    const size_t SPK = 67108864;       // [32][32][1024][64] i8
    const size_t MSK = 8388608;        // [32][32][2048] u32
    const size_t NEED = WP1 + WP2 + X8T + SPK + MSK;

    if (ws_size >= NEED) {
        char* ws = (char*)d_ws;
        signed char* wp1 = (signed char*)ws;
        signed char* wp2 = (signed char*)(ws + WP1);
        unsigned char* x8t = (unsigned char*)(ws + WP1 + WP2);
        unsigned char* spk8 = (unsigned char*)(ws + WP1 + WP2 + X8T);
        unsigned* mask_ws = (unsigned*)(ws + WP1 + WP2 + X8T + SPK);

        prep_w8<<<1024, 256, 0, stream>>>(w1, wp1, 2048, 512);
        prep_w8<<<512, 256, 0, stream>>>(w2, wp2, 256, 2048);
        prep_x8<<<dim3(16, 8, 32), 256, 0, stream>>>(x, x8t);

        // layer 1: fused GEMM+LIF -> masks only; 64-m blocks, 64-lane LIF
        gemm_lif1<<<dim3(32, 32), 320, 0, stream>>>(wp1, x8t, b1, mask_ws);
        expand_spk8<<<dim3(32, 32), 256, 0, stream>>>(mask_ws, spk8);

        // layer 2: cur2 [b][256][1024] direct -> in-place LIF
        gemm_i8<false, 32, 8><<<dim3(4, 32, 8), 256, 0, stream>>>(
            wp2, spk8, b2, spk2, 256);
        lif_lds<32><<<256, 256, 0, stream>>>(spk2);

        // f32 spike expansion for layer-1 output
        expand_spk<<<8192, 256, 0, stream>>>(mask_ws, spk1);
    } else {
        gemm_f16x3_kernel<<<dim3(8, 16, 32), 256, 0, stream>>>(
            w1, x, b1, spk1, 2048, 1024, 512, (long)512 * 1024, (long)2048 * 1024);
        lif_rows<<<(65536 + 255) / 256, 256, 0, stream>>>(spk1, 65536, 1024);
        gemm_f16x3_kernel<<<dim3(8, 2, 32), 256, 0, stream>>>(
            w2, spk1, b2, spk2, 256, 1024, 2048, (long)2048 * 1024, (long)256 * 1024);
        lif_rows<<<(8192 + 255) / 256, 256, 0, stream>>>(spk2, 8192, 1024);
    }
}